// Round 1
// baseline (6723.512 us; speedup 1.0000x reference)
//
#include <hip/hip_runtime.h>
#include <cstdint>
#include <cmath>

typedef unsigned int u32;
typedef unsigned long long u64;

#define NN 32768
#define NE 131072
#define FIN 1025
#define HTS 262144
#define HTM (HTS - 1)

// ---------------- workspace layout (byte offsets, 256-aligned) ----------------
#define WS_A_D    0ul          // double[NN]
#define WS_B_D    262144ul     // double[NN]
#define WS_EMAX   524288ul     // u32[NN]
#define WS_SSUM   655360ul     // double[NN]
#define WS_EXD    917504ul     // double[NE]  (e, then ex)
#define WS_SCORE  1966080ul    // float[NE]
#define WS_KEY    2490368ul    // u64[NE]
#define WS_BEST   3538944ul    // u64[NN]
#define WS_USED   3801088ul    // u32[NN]
#define WS_ESTAT  3932160ul    // int[NE] 0=active 1=sel 2=dead
#define WS_CLUST  4456448ul    // int[NN]
#define WS_OTHER  4587520ul    // int[NN]
#define WS_NSC    4718592ul    // float[NN]
#define WS_HT     4849664ul    // u32[HTS]
#define WS_CEU    5898240ul    // int[NE]
#define WS_CEV    6422528ul    // int[NE]
#define WS_DEG    6946816ul    // u32[NN]
#define WS_DIS    7077888ul    // float[NN]
#define WS_MISC   7208960ul    // int[64] : [0]=coarse edge count
#define WS_GMAX   7209216ul    // u32[8*512]
#define WS_GSUM   7225600ul    // float[8*512]
#define WS_GCNT   7241984ul    // float[64]
#define WS_P0     7242240ul    // float[NN*512]
#define WS_P1     74351104ul   // float[NN*512]
#define WS_H      141459968ul  // float[NN*512]

__device__ __forceinline__ u32 enc_f(float f) {
    u32 b = __float_as_uint(f);
    return (b & 0x80000000u) ? ~b : (b | 0x80000000u);
}
__device__ __forceinline__ float dec_f(u32 m) {
    return (m & 0x80000000u) ? __uint_as_float(m ^ 0x80000000u) : __uint_as_float(~m);
}
__device__ __forceinline__ double wave_sum(double v) {
    #pragma unroll
    for (int off = 32; off > 0; off >>= 1) v += __shfl_down(v, off, 64);
    return v;
}

// ---------------- init scratch that must start zeroed / sentinel ----------------
__global__ void init_misc(u32* ht, u32* emax, double* ssum, u32* deg,
                          int* misc, u32* gmaxb, float* gsum, float* gcnt) {
    int i = blockIdx.x * 256 + threadIdx.x;
    if (i < HTS) ht[i] = 0xFFFFFFFFu;
    if (i < NN) { emax[i] = 0u; ssum[i] = 0.0; deg[i] = 0u; }
    if (i < 4096) { gmaxb[i] = 0u; gsum[i] = 0.0f; }
    if (i < 64) { misc[i] = 0; gcnt[i] = 0.0f; }
}

// ---------------- per-node dots with pool_w halves (double accum) ----------------
__global__ void node_dots(const float* __restrict__ x, const float* __restrict__ pw,
                          double* a_d, double* b_d) {
    int wave = (blockIdx.x * blockDim.x + threadIdx.x) >> 6;
    int lane = threadIdx.x & 63;
    if (wave >= NN) return;
    const float* xr = x + (size_t)wave * FIN;
    double s0 = 0.0, s1 = 0.0;
    for (int f = lane; f < FIN; f += 64) {
        double xv = (double)xr[f];
        s0 += xv * (double)pw[f];
        s1 += xv * (double)pw[FIN + f];
    }
    s0 = wave_sum(s0); s1 = wave_sum(s1);
    if (lane == 0) { a_d[wave] = s0; b_d[wave] = s1; }
}

// ---------------- edge score pipeline ----------------
__global__ void edge_p1(const int* __restrict__ ei, const double* __restrict__ a_d,
                        const double* __restrict__ b_d, const float* __restrict__ pb,
                        double* e_d, u32* emax) {
    int k = blockIdx.x * 256 + threadIdx.x;
    if (k >= NE) return;
    int u = ei[k], v = ei[NE + k];
    double e = a_d[u] + b_d[v] + (double)pb[0];
    e_d[k] = e;
    atomicMax(&emax[v], enc_f((float)e));
}
__global__ void edge_p2(const int* __restrict__ ei, double* e_d,
                        const u32* __restrict__ emax, double* ssum) {
    int k = blockIdx.x * 256 + threadIdx.x;
    if (k >= NE) return;
    int v = ei[NE + k];
    float mf = dec_f(emax[v]);
    double ex = exp(e_d[k] - (double)mf);
    e_d[k] = ex;
    unsafeAtomicAdd(&ssum[v], ex);
}
__global__ void edge_p3(const int* __restrict__ ei, const double* __restrict__ e_d,
                        const double* __restrict__ ssum, float* score, u64* key) {
    int k = blockIdx.x * 256 + threadIdx.x;
    if (k >= NE) return;
    int v = ei[NE + k];
    float sc = (float)(e_d[k] / ssum[v] + 0.5);
    score[k] = sc;
    u32 m = enc_f(sc);               // ascending order
    key[k] = ((u64)(m ^ 0xFFFFFFFFu) << 32) | (u32)k;  // low key = high score, tie: low idx
}

// ---------------- greedy matching == locally-dominant fixed point ----------------
__global__ void __launch_bounds__(1024) match_kernel(
        const u64* __restrict__ key, const int* __restrict__ ei,
        int* estat, u64* best, u32* used) {
    int tid = threadIdx.x;
    const int* eu = ei; const int* ev = ei + NE;
    for (int n = tid; n < NN; n += 1024) { best[n] = ~0ull; used[n] = 0u; }
    for (int e = tid; e < NE; e += 1024) estat[e] = 0;
    __shared__ int s_active;
    __syncthreads();
    for (int round = 0; round < 4096; ++round) {
        if (tid == 0) s_active = 0;
        __syncthreads();
        for (int e = tid; e < NE; e += 1024)
            if (estat[e] == 0) {
                u64 k = key[e];
                atomicMin(&best[eu[e]], k);
                atomicMin(&best[ev[e]], k);
            }
        __syncthreads();
        for (int e = tid; e < NE; e += 1024)
            if (estat[e] == 0) {
                u64 k = key[e];
                int a = eu[e], b = ev[e];
                if (best[a] == k && best[b] == k) {
                    estat[e] = 1; used[a] = 1u; used[b] = 1u;
                }
            }
        __syncthreads();
        int my = 0;
        for (int e = tid; e < NE; e += 1024)
            if (estat[e] == 0) {
                if (used[eu[e]] | used[ev[e]]) estat[e] = 2;
                else ++my;
            }
        for (int n = tid; n < NN; n += 1024) best[n] = ~0ull;
        if (my) atomicAdd(&s_active, my);
        __syncthreads();
        if (s_active == 0) break;
    }
}

__global__ void cluster_init(int* cluster, int* other, float* nscore) {
    int n = blockIdx.x * 256 + threadIdx.x;
    if (n >= NN) return;
    cluster[n] = n; other[n] = -1; nscore[n] = 1.0f;
}
__global__ void apply_sel(const int* __restrict__ ei, const int* __restrict__ estat,
                          const float* __restrict__ score,
                          int* cluster, int* other, float* nscore) {
    int e = blockIdx.x * 256 + threadIdx.x;
    if (e >= NE) return;
    if (estat[e] != 1) return;
    int u = ei[e], v = ei[NE + e];
    int rep = min(u, v);
    cluster[u] = rep; cluster[v] = rep;
    if (u != v) other[rep] = u + v - rep;
    nscore[rep] = score[e];
}

// ---------------- coarse graph: dedup (cu,cv) pairs via hash set ----------------
__global__ void coarse_build(const int* __restrict__ ei, const int* __restrict__ cluster,
                             u32* ht, int* misc, int* ce_u, int* ce_v, u32* deg) {
    int e = blockIdx.x * 256 + threadIdx.x;
    if (e >= NE) return;
    int cu = cluster[ei[e]], cv = cluster[ei[NE + e]];
    if (cu == cv) return;
    u32 k = (u32)cu * 32768u + (u32)cv;
    u32 h = ((k * 2654435761u) >> 12) & HTM;
    while (true) {
        u32 old = atomicCAS(&ht[h], 0xFFFFFFFFu, k);
        if (old == 0xFFFFFFFFu) {
            int idx = atomicAdd(&misc[0], 1);
            ce_u[idx] = cu; ce_v[idx] = cv;
            atomicAdd(&deg[cu], 1u);
            break;
        }
        if (old == k) break;
        h = (h + 1) & HTM;
    }
}
__global__ void dis_kernel(const u32* __restrict__ deg, float* dis) {
    int n = blockIdx.x * 256 + threadIdx.x;
    if (n >= NN) return;
    u32 d = deg[n];
    dis[n] = d ? (float)(1.0 / sqrt((double)d)) : 0.0f;
}

// ---------------- dual-B fp32 GEMM, 64x64x16 tile, optional fused px gather ----------------
template <bool FUSED>
__global__ void __launch_bounds__(256) gemm_dual(
        const float* __restrict__ A, const float* __restrict__ B0,
        const float* __restrict__ B1, float* __restrict__ C0, float* __restrict__ C1,
        int K, const int* __restrict__ cluster, const int* __restrict__ other,
        const float* __restrict__ nscore) {
    __shared__ __align__(16) float As[16][68];
    __shared__ __align__(16) float Bs0[16][64];
    __shared__ __align__(16) float Bs1[16][64];
    int tid = threadIdx.x;
    int bm = blockIdx.y * 64, bn = blockIdx.x * 64;
    int tx = tid & 15, ty = tid >> 4;
    int la_m = tid >> 4, la_k = tid & 15;   // A loader base
    int lb_n = tid & 63, lb_k = tid >> 6;   // B loader base
    float acc0[4][4] = {{0}}, acc1[4][4] = {{0}};
    int KT = (K + 15) >> 4;
    for (int kt = 0; kt < KT; ++kt) {
        int k0 = kt << 4;
        #pragma unroll
        for (int i = 0; i < 4; ++i) {
            int m = la_m + (i << 4);
            int gk = k0 + la_k;
            int r = bm + m;
            float v = 0.0f;
            if (gk < K) {
                if (FUSED) {
                    if (cluster[r] == r) {
                        float xv = A[(size_t)r * FIN + gk];
                        int o = other[r];
                        if (o >= 0) xv += A[(size_t)o * FIN + gk];
                        v = nscore[r] * xv;
                    }
                } else {
                    v = A[(size_t)r * 512 + gk];
                }
            }
            As[la_k][m] = v;
        }
        #pragma unroll
        for (int i = 0; i < 4; ++i) {
            int kk = lb_k + (i << 2);
            int gk = k0 + kk;
            float v0 = 0.0f, v1 = 0.0f;
            if (gk < K) {
                v0 = B0[(size_t)gk * 512 + bn + lb_n];
                v1 = B1[(size_t)gk * 512 + bn + lb_n];
            }
            Bs0[kk][lb_n] = v0; Bs1[kk][lb_n] = v1;
        }
        __syncthreads();
        #pragma unroll
        for (int kk = 0; kk < 16; ++kk) {
            float4 a4 = *(const float4*)&As[kk][ty << 2];
            float4 b04 = *(const float4*)&Bs0[kk][tx << 2];
            float4 b14 = *(const float4*)&Bs1[kk][tx << 2];
            float av[4] = {a4.x, a4.y, a4.z, a4.w};
            float b0v[4] = {b04.x, b04.y, b04.z, b04.w};
            float b1v[4] = {b14.x, b14.y, b14.z, b14.w};
            #pragma unroll
            for (int i = 0; i < 4; ++i)
                #pragma unroll
                for (int j = 0; j < 4; ++j) {
                    acc0[i][j] += av[i] * b0v[j];
                    acc1[i][j] += av[i] * b1v[j];
                }
        }
        __syncthreads();
    }
    #pragma unroll
    for (int i = 0; i < 4; ++i) {
        size_t r = (size_t)(bm + (ty << 2) + i);
        float4 o0 = make_float4(acc0[i][0], acc0[i][1], acc0[i][2], acc0[i][3]);
        float4 o1 = make_float4(acc1[i][0], acc1[i][1], acc1[i][2], acc1[i][3]);
        *(float4*)&C0[r * 512 + bn + (tx << 2)] = o0;
        *(float4*)&C1[r * 512 + bn + (tx << 2)] = o1;
    }
}

// ---------------- sparse accumulate: P0[b,:] += -dis[a]*dis[b] * P1[a,:] ----------------
__global__ void spmm_add(const float* __restrict__ P1, float* __restrict__ P0,
                         const int* __restrict__ ce_u, const int* __restrict__ ce_v,
                         const float* __restrict__ dis, const int* __restrict__ misc) {
    int idx = blockIdx.x * 256 + threadIdx.x;
    int e = idx >> 7;
    if (e >= misc[0]) return;
    int c = (idx & 127) << 2;
    int a = ce_u[e], b = ce_v[e];
    float coef = -dis[a] * dis[b];
    float4 p = *(const float4*)&P1[(size_t)a * 512 + c];
    float* dst = &P0[(size_t)b * 512 + c];
    unsafeAtomicAdd(dst + 0, coef * p.x);
    unsafeAtomicAdd(dst + 1, coef * p.y);
    unsafeAtomicAdd(dst + 2, coef * p.z);
    unsafeAtomicAdd(dst + 3, coef * p.w);
}

// ---------------- h = relu(BN(P0 + bias)) ----------------
__global__ void act_bn(const float* __restrict__ P0, const float* __restrict__ bias,
                       const float* __restrict__ bn, float* __restrict__ H) {
    int idx = blockIdx.x * 256 + threadIdx.x;
    if (idx >= NN * 128) return;
    int j4 = (idx & 127) << 2;
    float4 t = *(const float4*)&P0[(size_t)idx << 2];
    float o[4] = {t.x, t.y, t.z, t.w};
    #pragma unroll
    for (int c = 0; c < 4; ++c) {
        int j = j4 + c;
        float ga = bn[j], be = bn[512 + j], mn = bn[1024 + j], vr = bn[1536 + j];
        float sc = (float)(1.0 / sqrt((double)vr + 1e-5));
        float v = (o[c] + bias[j] - mn) * sc * ga + be;
        o[c] = v > 0.0f ? v : 0.0f;
    }
    *(float4*)&H[(size_t)idx << 2] = make_float4(o[0], o[1], o[2], o[3]);
}

// ---------------- global max+mean pool over valid nodes per graph ----------------
__global__ void __launch_bounds__(256) pool_kernel(
        const float* __restrict__ H, const int* __restrict__ cluster,
        const int* __restrict__ batch, u32* gmaxb, float* gsum, float* gcnt) {
    int t = threadIdx.x;
    int n0 = blockIdx.x * 64;
    float m0 = 0.0f, m1 = 0.0f, s0 = 0.0f, s1 = 0.0f;
    int cntl = 0;
    int cur = batch[n0];
    for (int i = 0; i < 64; ++i) {
        int n = n0 + i;
        int bt = batch[n];
        if (bt != cur) {
            atomicMax(&gmaxb[cur * 512 + t], __float_as_uint(m0));
            atomicMax(&gmaxb[cur * 512 + t + 256], __float_as_uint(m1));
            unsafeAtomicAdd(&gsum[cur * 512 + t], s0);
            unsafeAtomicAdd(&gsum[cur * 512 + t + 256], s1);
            if (t == 0) unsafeAtomicAdd(&gcnt[cur], (float)cntl);
            m0 = m1 = s0 = s1 = 0.0f; cntl = 0; cur = bt;
        }
        if (cluster[n] == n) {
            float h0 = H[(size_t)n * 512 + t];
            float h1 = H[(size_t)n * 512 + t + 256];
            m0 = fmaxf(m0, h0); m1 = fmaxf(m1, h1);
            s0 += h0; s1 += h1;
            ++cntl;
        }
    }
    atomicMax(&gmaxb[cur * 512 + t], __float_as_uint(m0));
    atomicMax(&gmaxb[cur * 512 + t + 256], __float_as_uint(m1));
    unsafeAtomicAdd(&gsum[cur * 512 + t], s0);
    unsafeAtomicAdd(&gsum[cur * 512 + t + 256], s1);
    if (t == 0) unsafeAtomicAdd(&gcnt[cur], (float)cntl);
}

// ---------------- readout MLP + log_softmax (tiny, one block) ----------------
__global__ void __launch_bounds__(512) readout(
        const u32* __restrict__ gmaxb, const float* __restrict__ gsum,
        const float* __restrict__ gcnt,
        const float* __restrict__ l1w, const float* __restrict__ l1b,
        const float* __restrict__ bn3,
        const float* __restrict__ l2w, const float* __restrict__ l2b,
        const float* __restrict__ bn4,
        const float* __restrict__ l3w, const float* __restrict__ l3b,
        float* __restrict__ out) {
    __shared__ float G[8 * 1024];
    __shared__ float G1[8 * 512];
    __shared__ float G2[8 * 256];
    int t = threadIdx.x;
    for (int idx = t; idx < 8192; idx += 512) {
        int b = idx >> 10, j = idx & 1023;
        float v;
        if (j < 512) v = __uint_as_float(gmaxb[b * 512 + j]);
        else v = gsum[b * 512 + (j - 512)] / fmaxf(gcnt[b], 1.0f);
        G[idx] = v;
    }
    __syncthreads();
    {   // layer 1: o = t (0..511), all 8 graphs
        int o = t;
        float acc[8];
        #pragma unroll
        for (int b = 0; b < 8; ++b) acc[b] = l1b[o];
        for (int k = 0; k < 1024; ++k) {
            float w = l1w[k * 512 + o];
            #pragma unroll
            for (int b = 0; b < 8; ++b) acc[b] += G[b * 1024 + k] * w;
        }
        float ga = bn3[o], be = bn3[512 + o], mn = bn3[1024 + o], vr = bn3[1536 + o];
        float sc = (float)(1.0 / sqrt((double)vr + 1e-5));
        #pragma unroll
        for (int b = 0; b < 8; ++b) {
            float v = (acc[b] - mn) * sc * ga + be;
            G1[b * 512 + o] = v > 0.0f ? v : 0.0f;
        }
    }
    __syncthreads();
    if (t < 256) {   // layer 2 + feature output
        int o = t;
        float acc[8];
        #pragma unroll
        for (int b = 0; b < 8; ++b) acc[b] = l2b[o];
        for (int k = 0; k < 512; ++k) {
            float w = l2w[k * 256 + o];
            #pragma unroll
            for (int b = 0; b < 8; ++b) acc[b] += G1[b * 512 + k] * w;
        }
        float ga = bn4[o], be = bn4[256 + o], mn = bn4[512 + o], vr = bn4[768 + o];
        float sc = (float)(1.0 / sqrt((double)vr + 1e-5));
        #pragma unroll
        for (int b = 0; b < 8; ++b) {
            float v = (acc[b] - mn) * sc * ga + be;
            v = v > 0.0f ? v : 0.0f;
            G2[b * 256 + o] = v;
            out[32 + b * 256 + o] = v;
        }
    }
    __syncthreads();
    if (t < 8) {   // layer 3 + log_softmax
        int b = t;
        float r[4];
        #pragma unroll
        for (int c = 0; c < 4; ++c) {
            float acc = l3b[c];
            for (int k = 0; k < 256; ++k) acc += G2[b * 256 + k] * l3w[k * 4 + c];
            r[c] = acc > 0.0f ? acc : 0.0f;
        }
        float mx = fmaxf(fmaxf(r[0], r[1]), fmaxf(r[2], r[3]));
        float s = 0.0f;
        #pragma unroll
        for (int c = 0; c < 4; ++c) s += expf(r[c] - mx);
        float lse = mx + logf(s);
        #pragma unroll
        for (int c = 0; c < 4; ++c) out[b * 4 + c] = r[c] - lse;
    }
}

extern "C" void kernel_launch(void* const* d_in, const int* in_sizes, int n_in,
                              void* d_out, int out_size, void* d_ws, size_t ws_size,
                              hipStream_t stream) {
    const float* x      = (const float*)d_in[0];
    const int*   ei     = (const int*)d_in[1];
    const int*   batch  = (const int*)d_in[2];
    const float* pool_w = (const float*)d_in[3];
    const float* pool_b = (const float*)d_in[4];
    const float* c1_w0  = (const float*)d_in[5];
    const float* c1_w1  = (const float*)d_in[6];
    const float* c1_b   = (const float*)d_in[7];
    const float* c2_w0  = (const float*)d_in[8];
    const float* c2_w1  = (const float*)d_in[9];
    const float* c2_b   = (const float*)d_in[10];
    const float* bn1    = (const float*)d_in[11];
    const float* bn2    = (const float*)d_in[12];
    const float* bn3    = (const float*)d_in[13];
    const float* bn4    = (const float*)d_in[14];
    const float* l1w    = (const float*)d_in[15];
    const float* l1b    = (const float*)d_in[16];
    const float* l2w    = (const float*)d_in[17];
    const float* l2b    = (const float*)d_in[18];
    const float* l3w    = (const float*)d_in[19];
    const float* l3b    = (const float*)d_in[20];
    float* out = (float*)d_out;
    char* ws = (char*)d_ws;

    double* a_d   = (double*)(ws + WS_A_D);
    double* b_d   = (double*)(ws + WS_B_D);
    u32*    emax  = (u32*)(ws + WS_EMAX);
    double* ssum  = (double*)(ws + WS_SSUM);
    double* exd   = (double*)(ws + WS_EXD);
    float*  score = (float*)(ws + WS_SCORE);
    u64*    key   = (u64*)(ws + WS_KEY);
    u64*    best  = (u64*)(ws + WS_BEST);
    u32*    used  = (u32*)(ws + WS_USED);
    int*    estat = (int*)(ws + WS_ESTAT);
    int*    clus  = (int*)(ws + WS_CLUST);
    int*    other = (int*)(ws + WS_OTHER);
    float*  nsc   = (float*)(ws + WS_NSC);
    u32*    ht    = (u32*)(ws + WS_HT);
    int*    ce_u  = (int*)(ws + WS_CEU);
    int*    ce_v  = (int*)(ws + WS_CEV);
    u32*    deg   = (u32*)(ws + WS_DEG);
    float*  dis   = (float*)(ws + WS_DIS);
    int*    misc  = (int*)(ws + WS_MISC);
    u32*    gmaxb = (u32*)(ws + WS_GMAX);
    float*  gsum  = (float*)(ws + WS_GSUM);
    float*  gcnt  = (float*)(ws + WS_GCNT);
    float*  P0    = (float*)(ws + WS_P0);
    float*  P1    = (float*)(ws + WS_P1);
    float*  H     = (float*)(ws + WS_H);

    init_misc<<<HTS / 256, 256, 0, stream>>>(ht, emax, ssum, deg, misc, gmaxb, gsum, gcnt);
    node_dots<<<NN / 4, 256, 0, stream>>>(x, pool_w, a_d, b_d);
    edge_p1<<<NE / 256, 256, 0, stream>>>(ei, a_d, b_d, pool_b, exd, emax);
    edge_p2<<<NE / 256, 256, 0, stream>>>(ei, exd, emax, ssum);
    edge_p3<<<NE / 256, 256, 0, stream>>>(ei, exd, ssum, score, key);
    match_kernel<<<1, 1024, 0, stream>>>(key, ei, estat, best, used);
    cluster_init<<<NN / 256, 256, 0, stream>>>(clus, other, nsc);
    apply_sel<<<NE / 256, 256, 0, stream>>>(ei, estat, score, clus, other, nsc);
    coarse_build<<<NE / 256, 256, 0, stream>>>(ei, clus, ht, misc, ce_u, ce_v, deg);
    dis_kernel<<<NN / 256, 256, 0, stream>>>(deg, dis);

    dim3 gg(512 / 64, NN / 64);
    gemm_dual<true><<<gg, 256, 0, stream>>>(x, c1_w0, c1_w1, P0, P1, FIN, clus, other, nsc);
    spmm_add<<<(NE * 128) / 256, 256, 0, stream>>>(P1, P0, ce_u, ce_v, dis, misc);
    act_bn<<<(NN * 128) / 256, 256, 0, stream>>>(P0, c1_b, bn1, H);

    gemm_dual<false><<<gg, 256, 0, stream>>>(H, c2_w0, c2_w1, P0, P1, 512, clus, other, nsc);
    spmm_add<<<(NE * 128) / 256, 256, 0, stream>>>(P1, P0, ce_u, ce_v, dis, misc);
    act_bn<<<(NN * 128) / 256, 256, 0, stream>>>(P0, c2_b, bn2, H);

    pool_kernel<<<NN / 64, 256, 0, stream>>>(H, clus, batch, gmaxb, gsum, gcnt);
    readout<<<1, 512, 0, stream>>>(gmaxb, gsum, gcnt, l1w, l1b, bn3,
                                   l2w, l2b, bn4, l3w, l3b, out);
}

// Round 2
// 4621.907 us; speedup vs baseline: 1.4547x; 1.4547x over previous
//
#include <hip/hip_runtime.h>
#include <hip/hip_bf16.h>
#include <cstdint>
#include <cmath>

typedef unsigned int u32;
typedef unsigned long long u64;
typedef float f32x4 __attribute__((ext_vector_type(4)));
typedef __bf16 bf16x8 __attribute__((ext_vector_type(8)));
typedef unsigned short us8 __attribute__((ext_vector_type(8)));

#define NN 32768
#define NE 131072
#define FIN 1025
#define HTS 262144
#define HTM (HTS - 1)

// ---------------- workspace layout (byte offsets) ----------------
// Phase A (scores+matching) scratch [0, 4456448) is overlaid in phase B by Bt.
#define WS_A_D    0ul          // double[NN]
#define WS_B_D    262144ul     // double[NN]
#define WS_EMAX   524288ul     // u32[NN]
#define WS_SSUM   655360ul     // double[NN]
#define WS_EXD    917504ul     // double[NE]
#define WS_KEY    1966080ul    // u64[NE]
#define WS_BEST   3014656ul    // u64[NN]
#define WS_USED   3276800ul    // u32[NN]
#define WS_ACT0   3407872ul    // int[NE]
#define WS_ACT1   3932160ul    // int[NE]   (zone ends 4456448)
#define WS_BTHI   0ul          // ushort[1024*1056] = 2162688 B   (phase B)
#define WS_BTLO   2162688ul    // ushort[1024*1056]               (phase B)
#define WS_HT     1966080ul    // u32[HTS] overlays KEY (key dead before coarse_build)
// persistent across phases:
#define WS_SCORE  4456448ul    // float[NE]
#define WS_SEL    4980736ul    // int[NE]
#define WS_CLUST  5505024ul    // int[NN]
#define WS_OTHER  5636096ul    // int[NN]
#define WS_NSC    5767168ul    // float[NN]
#define WS_CEU    5898240ul    // int[NE]
#define WS_CEV    6422528ul    // int[NE]
#define WS_DEG    6946816ul    // u32[NN]
#define WS_DIS    7077888ul    // float[NN]
#define WS_MISC   7208960ul    // int[64]
#define WS_GMAX   7209216ul    // u32[8*512]
#define WS_GSUM   7225600ul    // float[8*512]
#define WS_GCNT   7241984ul    // float[64]
#define WS_P      7242240ul    // float[NN*1024]  (C0 | C1 combined)
#define WS_H      141459968ul  // float[NN*512]   -> ends 208568832 (same as r1)

__device__ __forceinline__ u32 enc_f(float f) {
    u32 b = __float_as_uint(f);
    return (b & 0x80000000u) ? ~b : (b | 0x80000000u);
}
__device__ __forceinline__ float dec_f(u32 m) {
    return (m & 0x80000000u) ? __uint_as_float(m ^ 0x80000000u) : __uint_as_float(~m);
}
__device__ __forceinline__ double wave_sum(double v) {
    #pragma unroll
    for (int off = 32; off > 0; off >>= 1) v += __shfl_down(v, off, 64);
    return v;
}
__device__ __forceinline__ unsigned short f2bf(float v) {   // RNE truncate f32->bf16
    u32 b = __float_as_uint(v);
    u32 r = b + 0x7FFFu + ((b >> 16) & 1u);
    return (unsigned short)(r >> 16);
}
__device__ __forceinline__ float bf2f(unsigned short h) {
    return __uint_as_float(((u32)h) << 16);
}
__device__ __forceinline__ bf16x8 ld_frag(const unsigned short* p) {
    union { us8 u; bf16x8 b; } t;
    t.u = *(const us8*)p;
    return t.b;
}

// ---------------- init ----------------
__global__ void init_misc(u32* emax, double* ssum, u32* deg,
                          int* misc, u32* gmaxb, float* gsum, float* gcnt) {
    int i = blockIdx.x * 256 + threadIdx.x;
    if (i < NN) { emax[i] = 0u; ssum[i] = 0.0; deg[i] = 0u; }
    if (i < 4096) { gmaxb[i] = 0u; gsum[i] = 0.0f; }
    if (i < 64) { misc[i] = 0; gcnt[i] = 0.0f; }
}
__global__ void init_ht(u32* ht) {
    int i = blockIdx.x * 256 + threadIdx.x;
    if (i < HTS) ht[i] = 0xFFFFFFFFu;
}

// ---------------- per-node dots with pool_w halves (double accum) ----------------
__global__ void node_dots(const float* __restrict__ x, const float* __restrict__ pw,
                          double* a_d, double* b_d) {
    int wave = (blockIdx.x * blockDim.x + threadIdx.x) >> 6;
    int lane = threadIdx.x & 63;
    if (wave >= NN) return;
    const float* xr = x + (size_t)wave * FIN;
    double s0 = 0.0, s1 = 0.0;
    for (int f = lane; f < FIN; f += 64) {
        double xv = (double)xr[f];
        s0 += xv * (double)pw[f];
        s1 += xv * (double)pw[FIN + f];
    }
    s0 = wave_sum(s0); s1 = wave_sum(s1);
    if (lane == 0) { a_d[wave] = s0; b_d[wave] = s1; }
}

// ---------------- edge score pipeline ----------------
__global__ void edge_p1(const int* __restrict__ ei, const double* __restrict__ a_d,
                        const double* __restrict__ b_d, const float* __restrict__ pb,
                        double* e_d, u32* emax) {
    int k = blockIdx.x * 256 + threadIdx.x;
    if (k >= NE) return;
    int u = ei[k], v = ei[NE + k];
    double e = a_d[u] + b_d[v] + (double)pb[0];
    e_d[k] = e;
    atomicMax(&emax[v], enc_f((float)e));
}
__global__ void edge_p2(const int* __restrict__ ei, double* e_d,
                        const u32* __restrict__ emax, double* ssum) {
    int k = blockIdx.x * 256 + threadIdx.x;
    if (k >= NE) return;
    int v = ei[NE + k];
    float mf = dec_f(emax[v]);
    double ex = exp(e_d[k] - (double)mf);
    e_d[k] = ex;
    unsafeAtomicAdd(&ssum[v], ex);
}
__global__ void edge_p3(const int* __restrict__ ei, const double* __restrict__ e_d,
                        const double* __restrict__ ssum, float* score, u64* key) {
    int k = blockIdx.x * 256 + threadIdx.x;
    if (k >= NE) return;
    int v = ei[NE + k];
    float sc = (float)(e_d[k] / ssum[v] + 0.5);
    score[k] = sc;
    u32 m = enc_f(sc);
    key[k] = ((u64)(m ^ 0xFFFFFFFFu) << 32) | (u32)k;  // low = high score, tie: low idx
}

// ---------------- greedy matching, worklist-compacted dominant-edge peeling ----------------
__global__ void __launch_bounds__(1024) match_kernel(
        const u64* __restrict__ key, const int* __restrict__ ei,
        int* __restrict__ sel, u64* __restrict__ best, u32* __restrict__ used,
        int* __restrict__ act0, int* __restrict__ act1) {
    int tid = threadIdx.x;
    const int* eu = ei; const int* ev = ei + NE;
    for (int n = tid; n < NN; n += 1024) { best[n] = ~0ull; used[n] = 0u; }
    for (int e = tid; e < NE; e += 1024) { sel[e] = 0; act0[e] = e; }
    __shared__ int s_n;
    int cnt = NE;
    int* cur = act0; int* nxt = act1;
    __syncthreads();
    for (int round = 0; round < 4096 && cnt > 0; ++round) {
        for (int i = tid; i < cnt; i += 1024) {
            int e = cur[i]; u64 k = key[e];
            atomicMin(&best[eu[e]], k);
            atomicMin(&best[ev[e]], k);
        }
        __syncthreads();
        for (int i = tid; i < cnt; i += 1024) {
            int e = cur[i]; u64 k = key[e];
            int a = eu[e], b = ev[e];
            if (best[a] == k && best[b] == k) { sel[e] = 1; used[a] = 1u; used[b] = 1u; }
        }
        if (tid == 0) s_n = 0;
        __syncthreads();
        for (int i = tid; i < cnt; i += 1024) {
            int e = cur[i];
            int a = eu[e], b = ev[e];
            best[a] = ~0ull; best[b] = ~0ull;
            if (!sel[e] && !(used[a] | used[b])) {
                int idx = atomicAdd(&s_n, 1);
                nxt[idx] = e;
            }
        }
        __syncthreads();
        cnt = s_n;
        int* t = cur; cur = nxt; nxt = t;
    }
}

__global__ void cluster_init(int* cluster, int* other, float* nscore) {
    int n = blockIdx.x * 256 + threadIdx.x;
    if (n >= NN) return;
    cluster[n] = n; other[n] = -1; nscore[n] = 1.0f;
}
__global__ void apply_sel(const int* __restrict__ ei, const int* __restrict__ sel,
                          const float* __restrict__ score,
                          int* cluster, int* other, float* nscore) {
    int e = blockIdx.x * 256 + threadIdx.x;
    if (e >= NE) return;
    if (sel[e] != 1) return;
    int u = ei[e], v = ei[NE + e];
    int rep = min(u, v);
    cluster[u] = rep; cluster[v] = rep;
    if (u != v) other[rep] = u + v - rep;
    nscore[rep] = score[e];
}

// ---------------- coarse graph: dedup (cu,cv) pairs via hash set ----------------
__global__ void coarse_build(const int* __restrict__ ei, const int* __restrict__ cluster,
                             u32* ht, int* misc, int* ce_u, int* ce_v, u32* deg) {
    int e = blockIdx.x * 256 + threadIdx.x;
    if (e >= NE) return;
    int cu = cluster[ei[e]], cv = cluster[ei[NE + e]];
    if (cu == cv) return;
    u32 k = (u32)cu * 32768u + (u32)cv;
    u32 h = ((k * 2654435761u) >> 12) & HTM;
    while (true) {
        u32 old = atomicCAS(&ht[h], 0xFFFFFFFFu, k);
        if (old == 0xFFFFFFFFu) {
            int idx = atomicAdd(&misc[0], 1);
            ce_u[idx] = cu; ce_v[idx] = cv;
            atomicAdd(&deg[cu], 1u);
            break;
        }
        if (old == k) break;
        h = (h + 1) & HTM;
    }
}
__global__ void dis_kernel(const u32* __restrict__ deg, float* dis) {
    int n = blockIdx.x * 256 + threadIdx.x;
    if (n >= NN) return;
    u32 d = deg[n];
    dis[n] = d ? (float)(1.0 / sqrt((double)d)) : 0.0f;
}

// ---------------- weight transpose + bf16 hi/lo split: Bt[n][k], n=0..1023 ----------------
__global__ void conv_b(const float* __restrict__ B0, const float* __restrict__ B1,
                       unsigned short* __restrict__ Bhi, unsigned short* __restrict__ Blo,
                       int K, int KP) {
    int n = blockIdx.x * 256 + threadIdx.x;   // grid.x = 4 -> n in [0,1024)
    int k0 = blockIdx.y * 8;
    unsigned short h[8], l[8];
    #pragma unroll
    for (int j = 0; j < 8; ++j) {
        int k = k0 + j;
        float v = 0.0f;
        if (k < K) v = (n < 512) ? B0[(size_t)k * 512 + n] : B1[(size_t)k * 512 + (n - 512)];
        h[j] = f2bf(v);
        l[j] = f2bf(v - bf2f(h[j]));
    }
    *(us8*)&Bhi[(size_t)n * KP + k0] = *(const us8*)h;
    *(us8*)&Blo[(size_t)n * KP + k0] = *(const us8*)l;
}

// ---------------- split-bf16 MFMA GEMM: P[M x 1024] = A[M x K] @ Bt^T ----------------
// 128x128 tile, BK=32, 4 waves (each 64x64), mfma_f32_16x16x32_bf16, hi/lo split (3 mfma).
template <bool FUSED>
__global__ void __launch_bounds__(256) gemm_mfma(
        const float* __restrict__ A, const unsigned short* __restrict__ Bhi,
        const unsigned short* __restrict__ Blo, float* __restrict__ P,
        int K, int KP, int astride,
        const int* __restrict__ clus, const int* __restrict__ other,
        const float* __restrict__ nsc) {
    __shared__ unsigned short Ah[128 * 40];   // row stride 40 (pad) -> 2-way banks (free)
    __shared__ unsigned short Al[128 * 40];
    __shared__ unsigned short Bh[128 * 40];
    __shared__ unsigned short Bl[128 * 40];
    int tid = threadIdx.x;
    int bn = blockIdx.x * 128;
    int bm = blockIdx.y * 128;
    int wave = tid >> 6, lane = tid & 63, quad = lane >> 4, l16 = lane & 15;
    int moff = (wave >> 1) * 64, noff = (wave & 1) * 64;
    int kq = tid & 3;        // which 8-k chunk
    int rr = tid >> 2;       // 0..63 base row
    f32x4 acc[4][4];
    #pragma unroll
    for (int i = 0; i < 4; ++i)
        #pragma unroll
        for (int j = 0; j < 4; ++j) acc[i][j] = (f32x4){0.f, 0.f, 0.f, 0.f};

    // hoisted per-row gather metadata (FUSED only)
    bool va[2]; float sca[2]; int oa[2]; int ra[2];
    #pragma unroll
    for (int p = 0; p < 2; ++p) {
        int r = bm + rr + p * 64;
        ra[p] = r;
        if (FUSED) {
            va[p] = (clus[r] == r);
            sca[p] = nsc[r];
            oa[p] = other[r];
        }
    }

    for (int k0 = 0; k0 < KP; k0 += 32) {
        // ---- stage A (fp32 -> bf16 hi/lo) ----
        #pragma unroll
        for (int p = 0; p < 2; ++p) {
            int m = rr + p * 64;
            int r = ra[p];
            float v[8];
            if (FUSED) {
                #pragma unroll
                for (int j = 0; j < 8; ++j) {
                    int gk = k0 + kq * 8 + j;
                    float xv = 0.0f;
                    if (va[p] && gk < K) {
                        xv = A[(size_t)r * astride + gk];
                        if (oa[p] >= 0) xv += A[(size_t)oa[p] * astride + gk];
                        xv *= sca[p];
                    }
                    v[j] = xv;
                }
            } else {
                int gk = k0 + kq * 8;
                if (gk + 7 < K) {
                    float4 t0 = *(const float4*)&A[(size_t)r * astride + gk];
                    float4 t1 = *(const float4*)&A[(size_t)r * astride + gk + 4];
                    v[0] = t0.x; v[1] = t0.y; v[2] = t0.z; v[3] = t0.w;
                    v[4] = t1.x; v[5] = t1.y; v[6] = t1.z; v[7] = t1.w;
                } else {
                    #pragma unroll
                    for (int j = 0; j < 8; ++j)
                        v[j] = (gk + j < K) ? A[(size_t)r * astride + gk + j] : 0.0f;
                }
            }
            unsigned short hi[8], lo[8];
            #pragma unroll
            for (int j = 0; j < 8; ++j) {
                hi[j] = f2bf(v[j]);
                lo[j] = f2bf(v[j] - bf2f(hi[j]));
            }
            *(us8*)&Ah[m * 40 + kq * 8] = *(const us8*)hi;
            *(us8*)&Al[m * 40 + kq * 8] = *(const us8*)lo;
        }
        // ---- stage B (pre-split bf16, contiguous k) ----
        #pragma unroll
        for (int p = 0; p < 2; ++p) {
            int n = rr + p * 64;
            size_t ga = (size_t)(bn + n) * KP + k0 + kq * 8;
            *(us8*)&Bh[n * 40 + kq * 8] = *(const us8*)&Bhi[ga];
            *(us8*)&Bl[n * 40 + kq * 8] = *(const us8*)&Blo[ga];
        }
        __syncthreads();
        // ---- fragments + mfma ----
        bf16x8 ah[4], al4[4], bh[4], bl4[4];
        #pragma unroll
        for (int i = 0; i < 4; ++i) {
            int arow = (moff + i * 16 + l16) * 40 + quad * 8;
            int brow = (noff + i * 16 + l16) * 40 + quad * 8;
            ah[i] = ld_frag(&Ah[arow]);
            al4[i] = ld_frag(&Al[arow]);
            bh[i] = ld_frag(&Bh[brow]);
            bl4[i] = ld_frag(&Bl[brow]);
        }
        #pragma unroll
        for (int mi = 0; mi < 4; ++mi)
            #pragma unroll
            for (int ni = 0; ni < 4; ++ni) {
                acc[mi][ni] = __builtin_amdgcn_mfma_f32_16x16x32_bf16(ah[mi], bh[ni], acc[mi][ni], 0, 0, 0);
                acc[mi][ni] = __builtin_amdgcn_mfma_f32_16x16x32_bf16(ah[mi], bl4[ni], acc[mi][ni], 0, 0, 0);
                acc[mi][ni] = __builtin_amdgcn_mfma_f32_16x16x32_bf16(al4[mi], bh[ni], acc[mi][ni], 0, 0, 0);
            }
        __syncthreads();
    }
    // ---- epilogue: C/D layout row=quad*4+r, col=l16 ----
    #pragma unroll
    for (int mi = 0; mi < 4; ++mi)
        #pragma unroll
        for (int ni = 0; ni < 4; ++ni) {
            int col = bn + noff + ni * 16 + l16;
            #pragma unroll
            for (int r2 = 0; r2 < 4; ++r2) {
                int row = bm + moff + mi * 16 + quad * 4 + r2;
                P[(size_t)row * 1024 + col] = acc[mi][ni][r2];
            }
        }
}

// ---------------- sparse accumulate: P[b][c] += -dis[a]*dis[b] * P[a][512+c] ----------------
__global__ void spmm_add(float* __restrict__ P,
                         const int* __restrict__ ce_u, const int* __restrict__ ce_v,
                         const float* __restrict__ dis, const int* __restrict__ misc) {
    int idx = blockIdx.x * 256 + threadIdx.x;
    int e = idx >> 7;
    if (e >= misc[0]) return;
    int c = (idx & 127) << 2;
    int a = ce_u[e], b = ce_v[e];
    float coef = -dis[a] * dis[b];
    float4 p = *(const float4*)&P[(size_t)a * 1024 + 512 + c];
    float* dst = &P[(size_t)b * 1024 + c];
    unsafeAtomicAdd(dst + 0, coef * p.x);
    unsafeAtomicAdd(dst + 1, coef * p.y);
    unsafeAtomicAdd(dst + 2, coef * p.z);
    unsafeAtomicAdd(dst + 3, coef * p.w);
}

// ---------------- h = relu(BN(P[:, :512] + bias)) ----------------
__global__ void act_bn(const float* __restrict__ P, const float* __restrict__ bias,
                       const float* __restrict__ bn, float* __restrict__ H) {
    int idx = blockIdx.x * 256 + threadIdx.x;
    if (idx >= NN * 128) return;
    int r = idx >> 7;
    int j4 = (idx & 127) << 2;
    float4 t = *(const float4*)&P[(size_t)r * 1024 + j4];
    float o[4] = {t.x, t.y, t.z, t.w};
    #pragma unroll
    for (int c = 0; c < 4; ++c) {
        int j = j4 + c;
        float ga = bn[j], be = bn[512 + j], mn = bn[1024 + j], vr = bn[1536 + j];
        float sc = (float)(1.0 / sqrt((double)vr + 1e-5));
        float v = (o[c] + bias[j] - mn) * sc * ga + be;
        o[c] = v > 0.0f ? v : 0.0f;
    }
    *(float4*)&H[(size_t)idx << 2] = make_float4(o[0], o[1], o[2], o[3]);
}

// ---------------- global max+mean pool over valid nodes per graph ----------------
__global__ void __launch_bounds__(256) pool_kernel(
        const float* __restrict__ H, const int* __restrict__ cluster,
        const int* __restrict__ batch, u32* gmaxb, float* gsum, float* gcnt) {
    int t = threadIdx.x;
    int n0 = blockIdx.x * 64;
    float m0 = 0.0f, m1 = 0.0f, s0 = 0.0f, s1 = 0.0f;
    int cntl = 0;
    int cur = batch[n0];
    for (int i = 0; i < 64; ++i) {
        int n = n0 + i;
        int bt = batch[n];
        if (bt != cur) {
            atomicMax(&gmaxb[cur * 512 + t], __float_as_uint(m0));
            atomicMax(&gmaxb[cur * 512 + t + 256], __float_as_uint(m1));
            unsafeAtomicAdd(&gsum[cur * 512 + t], s0);
            unsafeAtomicAdd(&gsum[cur * 512 + t + 256], s1);
            if (t == 0) unsafeAtomicAdd(&gcnt[cur], (float)cntl);
            m0 = m1 = s0 = s1 = 0.0f; cntl = 0; cur = bt;
        }
        if (cluster[n] == n) {
            float h0 = H[(size_t)n * 512 + t];
            float h1 = H[(size_t)n * 512 + t + 256];
            m0 = fmaxf(m0, h0); m1 = fmaxf(m1, h1);
            s0 += h0; s1 += h1;
            ++cntl;
        }
    }
    atomicMax(&gmaxb[cur * 512 + t], __float_as_uint(m0));
    atomicMax(&gmaxb[cur * 512 + t + 256], __float_as_uint(m1));
    unsafeAtomicAdd(&gsum[cur * 512 + t], s0);
    unsafeAtomicAdd(&gsum[cur * 512 + t + 256], s1);
    if (t == 0) unsafeAtomicAdd(&gcnt[cur], (float)cntl);
}

// ---------------- readout MLP + log_softmax (tiny, one block) ----------------
__global__ void __launch_bounds__(512) readout(
        const u32* __restrict__ gmaxb, const float* __restrict__ gsum,
        const float* __restrict__ gcnt,
        const float* __restrict__ l1w, const float* __restrict__ l1b,
        const float* __restrict__ bn3,
        const float* __restrict__ l2w, const float* __restrict__ l2b,
        const float* __restrict__ bn4,
        const float* __restrict__ l3w, const float* __restrict__ l3b,
        float* __restrict__ out) {
    __shared__ float G[8 * 1024];
    __shared__ float G1[8 * 512];
    __shared__ float G2[8 * 256];
    int t = threadIdx.x;
    for (int idx = t; idx < 8192; idx += 512) {
        int b = idx >> 10, j = idx & 1023;
        float v;
        if (j < 512) v = __uint_as_float(gmaxb[b * 512 + j]);
        else v = gsum[b * 512 + (j - 512)] / fmaxf(gcnt[b], 1.0f);
        G[idx] = v;
    }
    __syncthreads();
    {
        int o = t;
        float acc[8];
        #pragma unroll
        for (int b = 0; b < 8; ++b) acc[b] = l1b[o];
        for (int k = 0; k < 1024; ++k) {
            float w = l1w[k * 512 + o];
            #pragma unroll
            for (int b = 0; b < 8; ++b) acc[b] += G[b * 1024 + k] * w;
        }
        float ga = bn3[o], be = bn3[512 + o], mn = bn3[1024 + o], vr = bn3[1536 + o];
        float sc = (float)(1.0 / sqrt((double)vr + 1e-5));
        #pragma unroll
        for (int b = 0; b < 8; ++b) {
            float v = (acc[b] - mn) * sc * ga + be;
            G1[b * 512 + o] = v > 0.0f ? v : 0.0f;
        }
    }
    __syncthreads();
    if (t < 256) {
        int o = t;
        float acc[8];
        #pragma unroll
        for (int b = 0; b < 8; ++b) acc[b] = l2b[o];
        for (int k = 0; k < 512; ++k) {
            float w = l2w[k * 256 + o];
            #pragma unroll
            for (int b = 0; b < 8; ++b) acc[b] += G1[b * 512 + k] * w;
        }
        float ga = bn4[o], be = bn4[256 + o], mn = bn4[512 + o], vr = bn4[768 + o];
        float sc = (float)(1.0 / sqrt((double)vr + 1e-5));
        #pragma unroll
        for (int b = 0; b < 8; ++b) {
            float v = (acc[b] - mn) * sc * ga + be;
            v = v > 0.0f ? v : 0.0f;
            G2[b * 256 + o] = v;
            out[32 + b * 256 + o] = v;
        }
    }
    __syncthreads();
    if (t < 8) {
        int b = t;
        float r[4];
        #pragma unroll
        for (int c = 0; c < 4; ++c) {
            float acc = l3b[c];
            for (int k = 0; k < 256; ++k) acc += G2[b * 256 + k] * l3w[k * 4 + c];
            r[c] = acc > 0.0f ? acc : 0.0f;
        }
        float mx = fmaxf(fmaxf(r[0], r[1]), fmaxf(r[2], r[3]));
        float s = 0.0f;
        #pragma unroll
        for (int c = 0; c < 4; ++c) s += expf(r[c] - mx);
        float lse = mx + logf(s);
        #pragma unroll
        for (int c = 0; c < 4; ++c) out[b * 4 + c] = r[c] - lse;
    }
}

extern "C" void kernel_launch(void* const* d_in, const int* in_sizes, int n_in,
                              void* d_out, int out_size, void* d_ws, size_t ws_size,
                              hipStream_t stream) {
    const float* x      = (const float*)d_in[0];
    const int*   ei     = (const int*)d_in[1];
    const int*   batch  = (const int*)d_in[2];
    const float* pool_w = (const float*)d_in[3];
    const float* pool_b = (const float*)d_in[4];
    const float* c1_w0  = (const float*)d_in[5];
    const float* c1_w1  = (const float*)d_in[6];
    const float* c1_b   = (const float*)d_in[7];
    const float* c2_w0  = (const float*)d_in[8];
    const float* c2_w1  = (const float*)d_in[9];
    const float* c2_b   = (const float*)d_in[10];
    const float* bn1    = (const float*)d_in[11];
    const float* bn2    = (const float*)d_in[12];
    const float* bn3    = (const float*)d_in[13];
    const float* bn4    = (const float*)d_in[14];
    const float* l1w    = (const float*)d_in[15];
    const float* l1b    = (const float*)d_in[16];
    const float* l2w    = (const float*)d_in[17];
    const float* l2b    = (const float*)d_in[18];
    const float* l3w    = (const float*)d_in[19];
    const float* l3b    = (const float*)d_in[20];
    float* out = (float*)d_out;
    char* ws = (char*)d_ws;

    double* a_d   = (double*)(ws + WS_A_D);
    double* b_d   = (double*)(ws + WS_B_D);
    u32*    emax  = (u32*)(ws + WS_EMAX);
    double* ssum  = (double*)(ws + WS_SSUM);
    double* exd   = (double*)(ws + WS_EXD);
    u64*    key   = (u64*)(ws + WS_KEY);
    u64*    best  = (u64*)(ws + WS_BEST);
    u32*    used  = (u32*)(ws + WS_USED);
    int*    act0  = (int*)(ws + WS_ACT0);
    int*    act1  = (int*)(ws + WS_ACT1);
    unsigned short* bthi = (unsigned short*)(ws + WS_BTHI);
    unsigned short* btlo = (unsigned short*)(ws + WS_BTLO);
    u32*    ht    = (u32*)(ws + WS_HT);
    float*  score = (float*)(ws + WS_SCORE);
    int*    sel   = (int*)(ws + WS_SEL);
    int*    clus  = (int*)(ws + WS_CLUST);
    int*    other = (int*)(ws + WS_OTHER);
    float*  nsc   = (float*)(ws + WS_NSC);
    int*    ce_u  = (int*)(ws + WS_CEU);
    int*    ce_v  = (int*)(ws + WS_CEV);
    u32*    deg   = (u32*)(ws + WS_DEG);
    float*  dis   = (float*)(ws + WS_DIS);
    int*    misc  = (int*)(ws + WS_MISC);
    u32*    gmaxb = (u32*)(ws + WS_GMAX);
    float*  gsum  = (float*)(ws + WS_GSUM);
    float*  gcnt  = (float*)(ws + WS_GCNT);
    float*  P     = (float*)(ws + WS_P);
    float*  H     = (float*)(ws + WS_H);

    // ---- phase A: scores, matching, coarse graph ----
    init_misc<<<NN / 256, 256, 0, stream>>>(emax, ssum, deg, misc, gmaxb, gsum, gcnt);
    node_dots<<<NN / 4, 256, 0, stream>>>(x, pool_w, a_d, b_d);
    edge_p1<<<NE / 256, 256, 0, stream>>>(ei, a_d, b_d, pool_b, exd, emax);
    edge_p2<<<NE / 256, 256, 0, stream>>>(ei, exd, emax, ssum);
    edge_p3<<<NE / 256, 256, 0, stream>>>(ei, exd, ssum, score, key);
    match_kernel<<<1, 1024, 0, stream>>>(key, ei, sel, best, used, act0, act1);
    cluster_init<<<NN / 256, 256, 0, stream>>>(clus, other, nsc);
    apply_sel<<<NE / 256, 256, 0, stream>>>(ei, sel, score, clus, other, nsc);
    init_ht<<<HTS / 256, 256, 0, stream>>>(ht);
    coarse_build<<<NE / 256, 256, 0, stream>>>(ei, clus, ht, misc, ce_u, ce_v, deg);
    dis_kernel<<<NN / 256, 256, 0, stream>>>(deg, dis);

    // ---- phase B: ChebConv layers (MFMA), pooling, readout ----
    dim3 gg(8, 256);   // n-tiles fast -> A-tile L2 reuse across the 8 n-blocks
    conv_b<<<dim3(4, 132), 256, 0, stream>>>(c1_w0, c1_w1, bthi, btlo, FIN, 1056);
    gemm_mfma<true><<<gg, 256, 0, stream>>>(x, bthi, btlo, P, FIN, 1056, FIN, clus, other, nsc);
    spmm_add<<<(NE * 128) / 256, 256, 0, stream>>>(P, ce_u, ce_v, dis, misc);
    act_bn<<<(NN * 128) / 256, 256, 0, stream>>>(P, c1_b, bn1, H);

    conv_b<<<dim3(4, 64), 256, 0, stream>>>(c2_w0, c2_w1, bthi, btlo, 512, 512);
    gemm_mfma<false><<<gg, 256, 0, stream>>>(H, bthi, btlo, P, 512, 512, 512, clus, other, nsc);
    spmm_add<<<(NE * 128) / 256, 256, 0, stream>>>(P, ce_u, ce_v, dis, misc);
    act_bn<<<(NN * 128) / 256, 256, 0, stream>>>(P, c2_b, bn2, H);

    pool_kernel<<<NN / 64, 256, 0, stream>>>(H, clus, batch, gmaxb, gsum, gcnt);
    readout<<<1, 512, 0, stream>>>(gmaxb, gsum, gcnt, l1w, l1b, bn3,
                                   l2w, l2b, bn4, l3w, l3b, out);
}

// Round 3
// 3172.636 us; speedup vs baseline: 2.1192x; 1.4568x over previous
//
#include <hip/hip_runtime.h>
#include <hip/hip_bf16.h>
#include <cstdint>
#include <cmath>

typedef unsigned int u32;
typedef unsigned long long u64;
typedef float f32x4 __attribute__((ext_vector_type(4)));
typedef __bf16 bf16x8 __attribute__((ext_vector_type(8)));
typedef unsigned short us8 __attribute__((ext_vector_type(8)));

#define NN 32768
#define NE 131072
#define FIN 1025
#define HTS 262144
#define HTM (HTS - 1)

// ---------------- workspace layout (byte offsets) ----------------
// Phase A (scores+matching) scratch [0, 4456448) is overlaid in phase B by Bt.
#define WS_A_D    0ul          // double[NN]
#define WS_B_D    262144ul     // double[NN]
#define WS_EMAX   524288ul     // u32[NN]
#define WS_SSUM   655360ul     // double[NN]
#define WS_EXD    917504ul     // double[NE]
#define WS_KEY    1966080ul    // u64[NE]
#define WS_BEST   3014656ul    // u64[NN]
#define WS_USED   3276800ul    // u32[NN]
#define WS_ACT0   3407872ul    // int[NE]
#define WS_ACT1   3932160ul    // int[NE]   (zone ends 4456448)
#define WS_BTHI   0ul          // ushort[1024*1056] = 2162688 B   (phase B)
#define WS_BTLO   2162688ul    // ushort[1024*1056]               (phase B)
#define WS_HT     1966080ul    // u32[HTS] overlays KEY (key dead before coarse_build)
// persistent across phases:
#define WS_SCORE  4456448ul    // float[NE]
#define WS_SEL    4980736ul    // int[NE]
#define WS_CLUST  5505024ul    // int[NN]
#define WS_OTHER  5636096ul    // int[NN]
#define WS_NSC    5767168ul    // float[NN]
#define WS_CEU    5898240ul    // int[NE]
#define WS_CEV    6422528ul    // int[NE]
#define WS_DEG    6946816ul    // u32[NN]
#define WS_DIS    7077888ul    // float[NN]
#define WS_MISC   7208960ul    // int[64]  [0]=coarse cnt, [1]=listA cnt, [2]=listB cnt
#define WS_GMAX   7209216ul    // u32[8*512]
#define WS_GSUM   7225600ul    // float[8*512]
#define WS_GCNT   7241984ul    // float[64]
#define WS_P      7242240ul    // float[NN*1024]  (C0 | C1 combined)
#define WS_H      141459968ul  // float[NN*512]   -> ends 208568832

__device__ __forceinline__ u32 enc_f(float f) {
    u32 b = __float_as_uint(f);
    return (b & 0x80000000u) ? ~b : (b | 0x80000000u);
}
__device__ __forceinline__ float dec_f(u32 m) {
    return (m & 0x80000000u) ? __uint_as_float(m ^ 0x80000000u) : __uint_as_float(~m);
}
__device__ __forceinline__ double wave_sum(double v) {
    #pragma unroll
    for (int off = 32; off > 0; off >>= 1) v += __shfl_down(v, off, 64);
    return v;
}
__device__ __forceinline__ unsigned short f2bf(float v) {   // RNE f32->bf16
    u32 b = __float_as_uint(v);
    u32 r = b + 0x7FFFu + ((b >> 16) & 1u);
    return (unsigned short)(r >> 16);
}
__device__ __forceinline__ float bf2f(unsigned short h) {
    return __uint_as_float(((u32)h) << 16);
}
__device__ __forceinline__ bf16x8 ld_frag(const unsigned short* p) {
    union { us8 u; bf16x8 b; } t;
    t.u = *(const us8*)p;
    return t.b;
}

// ---------------- init ----------------
__global__ void init_misc(u32* emax, double* ssum, u32* deg,
                          int* misc, u32* gmaxb, float* gsum, float* gcnt,
                          u64* best, u32* used) {
    int i = blockIdx.x * 256 + threadIdx.x;
    if (i < NN) { emax[i] = 0u; ssum[i] = 0.0; deg[i] = 0u; best[i] = ~0ull; used[i] = 0u; }
    if (i < 4096) { gmaxb[i] = 0u; gsum[i] = 0.0f; }
    if (i < 64) { misc[i] = (i == 1) ? NE : 0; gcnt[i] = 0.0f; }
}
__global__ void init_ht(u32* ht) {
    int i = blockIdx.x * 256 + threadIdx.x;
    if (i < HTS) ht[i] = 0xFFFFFFFFu;
}

// ---------------- per-node dots with pool_w halves (double accum) ----------------
__global__ void node_dots(const float* __restrict__ x, const float* __restrict__ pw,
                          double* a_d, double* b_d) {
    int wave = (blockIdx.x * blockDim.x + threadIdx.x) >> 6;
    int lane = threadIdx.x & 63;
    if (wave >= NN) return;
    const float* xr = x + (size_t)wave * FIN;
    double s0 = 0.0, s1 = 0.0;
    for (int f = lane; f < FIN; f += 64) {
        double xv = (double)xr[f];
        s0 += xv * (double)pw[f];
        s1 += xv * (double)pw[FIN + f];
    }
    s0 = wave_sum(s0); s1 = wave_sum(s1);
    if (lane == 0) { a_d[wave] = s0; b_d[wave] = s1; }
}

// ---------------- edge score pipeline ----------------
__global__ void edge_p1(const int* __restrict__ ei, const double* __restrict__ a_d,
                        const double* __restrict__ b_d, const float* __restrict__ pb,
                        double* e_d, u32* emax) {
    int k = blockIdx.x * 256 + threadIdx.x;
    if (k >= NE) return;
    int u = ei[k], v = ei[NE + k];
    double e = a_d[u] + b_d[v] + (double)pb[0];
    e_d[k] = e;
    atomicMax(&emax[v], enc_f((float)e));
}
__global__ void edge_p2(const int* __restrict__ ei, double* e_d,
                        const u32* __restrict__ emax, double* ssum) {
    int k = blockIdx.x * 256 + threadIdx.x;
    if (k >= NE) return;
    int v = ei[NE + k];
    float mf = dec_f(emax[v]);
    double ex = exp(e_d[k] - (double)mf);
    e_d[k] = ex;
    unsafeAtomicAdd(&ssum[v], ex);
}
// also: worklist init + round-0 min pass
__global__ void edge_p3(const int* __restrict__ ei, const double* __restrict__ e_d,
                        const double* __restrict__ ssum, float* score, u64* key,
                        int* sel, int* act0, u64* best) {
    int k = blockIdx.x * 256 + threadIdx.x;
    if (k >= NE) return;
    int u = ei[k], v = ei[NE + k];
    float sc = (float)(e_d[k] / ssum[v] + 0.5);
    score[k] = sc;
    u32 m = enc_f(sc);
    u64 kk = ((u64)(m ^ 0xFFFFFFFFu) << 32) | (u32)k;  // low = high score, tie: low idx
    key[k] = kk;
    sel[k] = 0;
    act0[k] = k;
    atomicMin(&best[u], kk);
    atomicMin(&best[v], kk);
}

// ---------------- flattened dominant-edge peeling rounds ----------------
__global__ void mk_sel(const u64* __restrict__ key, const int* __restrict__ ei,
                       const int* __restrict__ act, const int* __restrict__ cntp,
                       int* ncntp, const u64* __restrict__ best,
                       u32* used, int* sel) {
    int cnt = cntp[0];
    int stride = gridDim.x * blockDim.x;
    int gid = blockIdx.x * blockDim.x + threadIdx.x;
    if (gid == 0) ncntp[0] = 0;
    for (int i = gid; i < cnt; i += stride) {
        int e = act[i];
        u64 k = key[e];
        int a = ei[e], b = ei[NE + e];
        if (best[a] == k && best[b] == k) { sel[e] = 1; used[a] = 1u; used[b] = 1u; }
    }
}
__global__ void mk_compact(const int* __restrict__ ei, const int* __restrict__ act,
                           const int* __restrict__ cntp, int* nxt, int* ncntp,
                           u64* best, const u32* __restrict__ used) {
    int cnt = cntp[0];
    int stride = gridDim.x * blockDim.x;
    for (int i = blockIdx.x * blockDim.x + threadIdx.x; i < cnt; i += stride) {
        int e = act[i];
        int a = ei[e], b = ei[NE + e];
        best[a] = ~0ull; best[b] = ~0ull;
        bool live = !(used[a] | used[b]);
        u64 mask = __ballot(live);
        if (mask) {
            int lane = threadIdx.x & 63;
            int leader = __ffsll((unsigned long long)mask) - 1;
            int base = 0;
            if (lane == leader) base = atomicAdd(ncntp, __popcll(mask));
            base = __shfl(base, leader, 64);
            if (live) nxt[base + __popcll(mask & ((1ull << lane) - 1ull))] = e;
        }
    }
}
__global__ void mk_min(const u64* __restrict__ key, const int* __restrict__ ei,
                       const int* __restrict__ act, const int* __restrict__ cntp,
                       u64* best) {
    int cnt = cntp[0];
    int stride = gridDim.x * blockDim.x;
    for (int i = blockIdx.x * blockDim.x + threadIdx.x; i < cnt; i += stride) {
        int e = act[i];
        u64 k = key[e];
        atomicMin(&best[ei[e]], k);
        atomicMin(&best[ei[NE + e]], k);
    }
}
// single-block finisher for the tiny tail (loops to completion)
__global__ void __launch_bounds__(1024) match_fin(
        const u64* __restrict__ key, const int* __restrict__ ei,
        int* sel, u64* best, u32* used,
        int* listA, int* listB, const int* __restrict__ cntp) {
    int tid = threadIdx.x;
    int cnt = cntp[0];
    int* cur = listA; int* nxt = listB;
    __shared__ int s_n;
    for (int round = 0; round < 4096 && cnt > 0; ++round) {
        for (int i = tid; i < cnt; i += 1024) {
            int e = cur[i]; u64 k = key[e];
            atomicMin(&best[ei[e]], k);
            atomicMin(&best[ei[NE + e]], k);
        }
        __syncthreads();
        for (int i = tid; i < cnt; i += 1024) {
            int e = cur[i]; u64 k = key[e];
            int a = ei[e], b = ei[NE + e];
            if (best[a] == k && best[b] == k) { sel[e] = 1; used[a] = 1u; used[b] = 1u; }
        }
        if (tid == 0) s_n = 0;
        __syncthreads();
        for (int i = tid; i < cnt; i += 1024) {
            int e = cur[i];
            int a = ei[e], b = ei[NE + e];
            best[a] = ~0ull; best[b] = ~0ull;
            if (!(used[a] | used[b])) {
                int idx = atomicAdd(&s_n, 1);
                nxt[idx] = e;
            }
        }
        __syncthreads();
        cnt = s_n;
        int* t = cur; cur = nxt; nxt = t;
        __syncthreads();
    }
}

__global__ void cluster_init(int* cluster, int* other, float* nscore) {
    int n = blockIdx.x * 256 + threadIdx.x;
    if (n >= NN) return;
    cluster[n] = n; other[n] = -1; nscore[n] = 1.0f;
}
__global__ void apply_sel(const int* __restrict__ ei, const int* __restrict__ sel,
                          const float* __restrict__ score,
                          int* cluster, int* other, float* nscore) {
    int e = blockIdx.x * 256 + threadIdx.x;
    if (e >= NE) return;
    if (sel[e] != 1) return;
    int u = ei[e], v = ei[NE + e];
    int rep = min(u, v);
    cluster[u] = rep; cluster[v] = rep;
    if (u != v) other[rep] = u + v - rep;
    nscore[rep] = score[e];
}

// ---------------- coarse graph: dedup (cu,cv) pairs via hash set ----------------
__global__ void coarse_build(const int* __restrict__ ei, const int* __restrict__ cluster,
                             u32* ht, int* misc, int* ce_u, int* ce_v, u32* deg) {
    int e = blockIdx.x * 256 + threadIdx.x;
    if (e >= NE) return;
    int cu = cluster[ei[e]], cv = cluster[ei[NE + e]];
    if (cu == cv) return;
    u32 k = (u32)cu * 32768u + (u32)cv;
    u32 h = ((k * 2654435761u) >> 12) & HTM;
    while (true) {
        u32 old = atomicCAS(&ht[h], 0xFFFFFFFFu, k);
        if (old == 0xFFFFFFFFu) {
            int idx = atomicAdd(&misc[0], 1);
            ce_u[idx] = cu; ce_v[idx] = cv;
            atomicAdd(&deg[cu], 1u);
            break;
        }
        if (old == k) break;
        h = (h + 1) & HTM;
    }
}
__global__ void dis_kernel(const u32* __restrict__ deg, float* dis) {
    int n = blockIdx.x * 256 + threadIdx.x;
    if (n >= NN) return;
    u32 d = deg[n];
    dis[n] = d ? (float)(1.0 / sqrt((double)d)) : 0.0f;
}

// ---------------- weight transpose + bf16 hi/lo split: Bt[n][k] ----------------
__global__ void conv_b(const float* __restrict__ B0, const float* __restrict__ B1,
                       unsigned short* __restrict__ Bhi, unsigned short* __restrict__ Blo,
                       int K, int KP) {
    int n = blockIdx.x * 256 + threadIdx.x;
    int k0 = blockIdx.y * 8;
    unsigned short h[8], l[8];
    #pragma unroll
    for (int j = 0; j < 8; ++j) {
        int k = k0 + j;
        float v = 0.0f;
        if (k < K) v = (n < 512) ? B0[(size_t)k * 512 + n] : B1[(size_t)k * 512 + (n - 512)];
        h[j] = f2bf(v);
        l[j] = f2bf(v - bf2f(h[j]));
    }
    *(us8*)&Bhi[(size_t)n * KP + k0] = *(const us8*)h;
    *(us8*)&Blo[(size_t)n * KP + k0] = *(const us8*)l;
}

// ---------------- split-bf16 MFMA GEMM: P[M x 1024] = A[M x K] @ Bt^T ----------------
template <bool FUSED>
__global__ void __launch_bounds__(256) gemm_mfma(
        const float* __restrict__ A, const unsigned short* __restrict__ Bhi,
        const unsigned short* __restrict__ Blo, float* __restrict__ P,
        int K, int KP, int astride,
        const int* __restrict__ clus, const int* __restrict__ other,
        const float* __restrict__ nsc) {
    __shared__ unsigned short Ah[128 * 40];
    __shared__ unsigned short Al[128 * 40];
    __shared__ unsigned short Bh[128 * 40];
    __shared__ unsigned short Bl[128 * 40];
    int tid = threadIdx.x;
    int bn = blockIdx.x * 128;
    int bm = blockIdx.y * 128;
    int wave = tid >> 6, lane = tid & 63, quad = lane >> 4, l16 = lane & 15;
    int moff = (wave >> 1) * 64, noff = (wave & 1) * 64;
    int kq = tid & 3;
    int rr = tid >> 2;
    f32x4 acc[4][4];
    #pragma unroll
    for (int i = 0; i < 4; ++i)
        #pragma unroll
        for (int j = 0; j < 4; ++j) acc[i][j] = (f32x4){0.f, 0.f, 0.f, 0.f};

    bool va[2]; float sca[2]; int oa[2]; int ra[2];
    #pragma unroll
    for (int p = 0; p < 2; ++p) {
        int r = bm + rr + p * 64;
        ra[p] = r;
        if (FUSED) {
            va[p] = (clus[r] == r);
            sca[p] = nsc[r];
            oa[p] = other[r];
        }
    }

    for (int k0 = 0; k0 < KP; k0 += 32) {
        #pragma unroll
        for (int p = 0; p < 2; ++p) {
            int m = rr + p * 64;
            int r = ra[p];
            float v[8];
            if (FUSED) {
                #pragma unroll
                for (int j = 0; j < 8; ++j) {
                    int gk = k0 + kq * 8 + j;
                    float xv = 0.0f;
                    if (va[p] && gk < K) {
                        xv = A[(size_t)r * astride + gk];
                        if (oa[p] >= 0) xv += A[(size_t)oa[p] * astride + gk];
                        xv *= sca[p];
                    }
                    v[j] = xv;
                }
            } else {
                int gk = k0 + kq * 8;
                if (gk + 7 < K) {
                    float4 t0 = *(const float4*)&A[(size_t)r * astride + gk];
                    float4 t1 = *(const float4*)&A[(size_t)r * astride + gk + 4];
                    v[0] = t0.x; v[1] = t0.y; v[2] = t0.z; v[3] = t0.w;
                    v[4] = t1.x; v[5] = t1.y; v[6] = t1.z; v[7] = t1.w;
                } else {
                    #pragma unroll
                    for (int j = 0; j < 8; ++j)
                        v[j] = (gk + j < K) ? A[(size_t)r * astride + gk + j] : 0.0f;
                }
            }
            unsigned short hi[8], lo[8];
            #pragma unroll
            for (int j = 0; j < 8; ++j) {
                hi[j] = f2bf(v[j]);
                lo[j] = f2bf(v[j] - bf2f(hi[j]));
            }
            *(us8*)&Ah[m * 40 + kq * 8] = *(const us8*)hi;
            *(us8*)&Al[m * 40 + kq * 8] = *(const us8*)lo;
        }
        #pragma unroll
        for (int p = 0; p < 2; ++p) {
            int n = rr + p * 64;
            size_t ga = (size_t)(bn + n) * KP + k0 + kq * 8;
            *(us8*)&Bh[n * 40 + kq * 8] = *(const us8*)&Bhi[ga];
            *(us8*)&Bl[n * 40 + kq * 8] = *(const us8*)&Blo[ga];
        }
        __syncthreads();
        bf16x8 ah[4], al4[4], bh[4], bl4[4];
        #pragma unroll
        for (int i = 0; i < 4; ++i) {
            int arow = (moff + i * 16 + l16) * 40 + quad * 8;
            int brow = (noff + i * 16 + l16) * 40 + quad * 8;
            ah[i] = ld_frag(&Ah[arow]);
            al4[i] = ld_frag(&Al[arow]);
            bh[i] = ld_frag(&Bh[brow]);
            bl4[i] = ld_frag(&Bl[brow]);
        }
        #pragma unroll
        for (int mi = 0; mi < 4; ++mi)
            #pragma unroll
            for (int ni = 0; ni < 4; ++ni) {
                acc[mi][ni] = __builtin_amdgcn_mfma_f32_16x16x32_bf16(ah[mi], bh[ni], acc[mi][ni], 0, 0, 0);
                acc[mi][ni] = __builtin_amdgcn_mfma_f32_16x16x32_bf16(ah[mi], bl4[ni], acc[mi][ni], 0, 0, 0);
                acc[mi][ni] = __builtin_amdgcn_mfma_f32_16x16x32_bf16(al4[mi], bh[ni], acc[mi][ni], 0, 0, 0);
            }
        __syncthreads();
    }
    #pragma unroll
    for (int mi = 0; mi < 4; ++mi)
        #pragma unroll
        for (int ni = 0; ni < 4; ++ni) {
            int col = bn + noff + ni * 16 + l16;
            #pragma unroll
            for (int r2 = 0; r2 < 4; ++r2) {
                int row = bm + moff + mi * 16 + quad * 4 + r2;
                P[(size_t)row * 1024 + col] = acc[mi][ni][r2];
            }
        }
}

// ---------------- sparse accumulate: P[b][c] += -dis[a]*dis[b] * P[a][512+c] ----------------
__global__ void spmm_add(float* __restrict__ P,
                         const int* __restrict__ ce_u, const int* __restrict__ ce_v,
                         const float* __restrict__ dis, const int* __restrict__ misc) {
    int idx = blockIdx.x * 256 + threadIdx.x;
    int e = idx >> 7;
    if (e >= misc[0]) return;
    int c = (idx & 127) << 2;
    int a = ce_u[e], b = ce_v[e];
    float coef = -dis[a] * dis[b];
    float4 p = *(const float4*)&P[(size_t)a * 1024 + 512 + c];
    float* dst = &P[(size_t)b * 1024 + c];
    unsafeAtomicAdd(dst + 0, coef * p.x);
    unsafeAtomicAdd(dst + 1, coef * p.y);
    unsafeAtomicAdd(dst + 2, coef * p.z);
    unsafeAtomicAdd(dst + 3, coef * p.w);
}

// ---------------- h = relu(BN(P[:, :512] + bias)) ----------------
__global__ void act_bn(const float* __restrict__ P, const float* __restrict__ bias,
                       const float* __restrict__ bn, float* __restrict__ H) {
    int idx = blockIdx.x * 256 + threadIdx.x;
    if (idx >= NN * 128) return;
    int r = idx >> 7;
    int j4 = (idx & 127) << 2;
    float4 t = *(const float4*)&P[(size_t)r * 1024 + j4];
    float o[4] = {t.x, t.y, t.z, t.w};
    #pragma unroll
    for (int c = 0; c < 4; ++c) {
        int j = j4 + c;
        float ga = bn[j], be = bn[512 + j], mn = bn[1024 + j], vr = bn[1536 + j];
        float sc = (float)(1.0 / sqrt((double)vr + 1e-5));
        float v = (o[c] + bias[j] - mn) * sc * ga + be;
        o[c] = v > 0.0f ? v : 0.0f;
    }
    *(float4*)&H[(size_t)idx << 2] = make_float4(o[0], o[1], o[2], o[3]);
}

// ---------------- global max+mean pool over valid nodes per graph ----------------
__global__ void __launch_bounds__(256) pool_kernel(
        const float* __restrict__ H, const int* __restrict__ cluster,
        const int* __restrict__ batch, u32* gmaxb, float* gsum, float* gcnt) {
    int t = threadIdx.x;
    int n0 = blockIdx.x * 64;
    float m0 = 0.0f, m1 = 0.0f, s0 = 0.0f, s1 = 0.0f;
    int cntl = 0;
    int cur = batch[n0];
    for (int i = 0; i < 64; ++i) {
        int n = n0 + i;
        int bt = batch[n];
        if (bt != cur) {
            atomicMax(&gmaxb[cur * 512 + t], __float_as_uint(m0));
            atomicMax(&gmaxb[cur * 512 + t + 256], __float_as_uint(m1));
            unsafeAtomicAdd(&gsum[cur * 512 + t], s0);
            unsafeAtomicAdd(&gsum[cur * 512 + t + 256], s1);
            if (t == 0) unsafeAtomicAdd(&gcnt[cur], (float)cntl);
            m0 = m1 = s0 = s1 = 0.0f; cntl = 0; cur = bt;
        }
        if (cluster[n] == n) {
            float h0 = H[(size_t)n * 512 + t];
            float h1 = H[(size_t)n * 512 + t + 256];
            m0 = fmaxf(m0, h0); m1 = fmaxf(m1, h1);
            s0 += h0; s1 += h1;
            ++cntl;
        }
    }
    atomicMax(&gmaxb[cur * 512 + t], __float_as_uint(m0));
    atomicMax(&gmaxb[cur * 512 + t + 256], __float_as_uint(m1));
    unsafeAtomicAdd(&gsum[cur * 512 + t], s0);
    unsafeAtomicAdd(&gsum[cur * 512 + t + 256], s1);
    if (t == 0) unsafeAtomicAdd(&gcnt[cur], (float)cntl);
}

// ---------------- readout MLP + log_softmax (tiny, one block) ----------------
__global__ void __launch_bounds__(512) readout(
        const u32* __restrict__ gmaxb, const float* __restrict__ gsum,
        const float* __restrict__ gcnt,
        const float* __restrict__ l1w, const float* __restrict__ l1b,
        const float* __restrict__ bn3,
        const float* __restrict__ l2w, const float* __restrict__ l2b,
        const float* __restrict__ bn4,
        const float* __restrict__ l3w, const float* __restrict__ l3b,
        float* __restrict__ out) {
    __shared__ float G[8 * 1024];
    __shared__ float G1[8 * 512];
    __shared__ float G2[8 * 256];
    int t = threadIdx.x;
    for (int idx = t; idx < 8192; idx += 512) {
        int b = idx >> 10, j = idx & 1023;
        float v;
        if (j < 512) v = __uint_as_float(gmaxb[b * 512 + j]);
        else v = gsum[b * 512 + (j - 512)] / fmaxf(gcnt[b], 1.0f);
        G[idx] = v;
    }
    __syncthreads();
    {
        int o = t;
        float acc[8];
        #pragma unroll
        for (int b = 0; b < 8; ++b) acc[b] = l1b[o];
        for (int k = 0; k < 1024; ++k) {
            float w = l1w[k * 512 + o];
            #pragma unroll
            for (int b = 0; b < 8; ++b) acc[b] += G[b * 1024 + k] * w;
        }
        float ga = bn3[o], be = bn3[512 + o], mn = bn3[1024 + o], vr = bn3[1536 + o];
        float sc = (float)(1.0 / sqrt((double)vr + 1e-5));
        #pragma unroll
        for (int b = 0; b < 8; ++b) {
            float v = (acc[b] - mn) * sc * ga + be;
            G1[b * 512 + o] = v > 0.0f ? v : 0.0f;
        }
    }
    __syncthreads();
    if (t < 256) {
        int o = t;
        float acc[8];
        #pragma unroll
        for (int b = 0; b < 8; ++b) acc[b] = l2b[o];
        for (int k = 0; k < 512; ++k) {
            float w = l2w[k * 256 + o];
            #pragma unroll
            for (int b = 0; b < 8; ++b) acc[b] += G1[b * 512 + k] * w;
        }
        float ga = bn4[o], be = bn4[256 + o], mn = bn4[512 + o], vr = bn4[768 + o];
        float sc = (float)(1.0 / sqrt((double)vr + 1e-5));
        #pragma unroll
        for (int b = 0; b < 8; ++b) {
            float v = (acc[b] - mn) * sc * ga + be;
            v = v > 0.0f ? v : 0.0f;
            G2[b * 256 + o] = v;
            out[32 + b * 256 + o] = v;
        }
    }
    __syncthreads();
    if (t < 8) {
        int b = t;
        float r[4];
        #pragma unroll
        for (int c = 0; c < 4; ++c) {
            float acc = l3b[c];
            for (int k = 0; k < 256; ++k) acc += G2[b * 256 + k] * l3w[k * 4 + c];
            r[c] = acc > 0.0f ? acc : 0.0f;
        }
        float mx = fmaxf(fmaxf(r[0], r[1]), fmaxf(r[2], r[3]));
        float s = 0.0f;
        #pragma unroll
        for (int c = 0; c < 4; ++c) s += expf(r[c] - mx);
        float lse = mx + logf(s);
        #pragma unroll
        for (int c = 0; c < 4; ++c) out[b * 4 + c] = r[c] - lse;
    }
}

extern "C" void kernel_launch(void* const* d_in, const int* in_sizes, int n_in,
                              void* d_out, int out_size, void* d_ws, size_t ws_size,
                              hipStream_t stream) {
    const float* x      = (const float*)d_in[0];
    const int*   ei     = (const int*)d_in[1];
    const int*   batch  = (const int*)d_in[2];
    const float* pool_w = (const float*)d_in[3];
    const float* pool_b = (const float*)d_in[4];
    const float* c1_w0  = (const float*)d_in[5];
    const float* c1_w1  = (const float*)d_in[6];
    const float* c1_b   = (const float*)d_in[7];
    const float* c2_w0  = (const float*)d_in[8];
    const float* c2_w1  = (const float*)d_in[9];
    const float* c2_b   = (const float*)d_in[10];
    const float* bn1    = (const float*)d_in[11];
    const float* bn2    = (const float*)d_in[12];
    const float* bn3    = (const float*)d_in[13];
    const float* bn4    = (const float*)d_in[14];
    const float* l1w    = (const float*)d_in[15];
    const float* l1b    = (const float*)d_in[16];
    const float* l2w    = (const float*)d_in[17];
    const float* l2b    = (const float*)d_in[18];
    const float* l3w    = (const float*)d_in[19];
    const float* l3b    = (const float*)d_in[20];
    float* out = (float*)d_out;
    char* ws = (char*)d_ws;

    double* a_d   = (double*)(ws + WS_A_D);
    double* b_d   = (double*)(ws + WS_B_D);
    u32*    emax  = (u32*)(ws + WS_EMAX);
    double* ssum  = (double*)(ws + WS_SSUM);
    double* exd   = (double*)(ws + WS_EXD);
    u64*    key   = (u64*)(ws + WS_KEY);
    u64*    best  = (u64*)(ws + WS_BEST);
    u32*    used  = (u32*)(ws + WS_USED);
    int*    act0  = (int*)(ws + WS_ACT0);
    int*    act1  = (int*)(ws + WS_ACT1);
    unsigned short* bthi = (unsigned short*)(ws + WS_BTHI);
    unsigned short* btlo = (unsigned short*)(ws + WS_BTLO);
    u32*    ht    = (u32*)(ws + WS_HT);
    float*  score = (float*)(ws + WS_SCORE);
    int*    sel   = (int*)(ws + WS_SEL);
    int*    clus  = (int*)(ws + WS_CLUST);
    int*    other = (int*)(ws + WS_OTHER);
    float*  nsc   = (float*)(ws + WS_NSC);
    int*    ce_u  = (int*)(ws + WS_CEU);
    int*    ce_v  = (int*)(ws + WS_CEV);
    u32*    deg   = (u32*)(ws + WS_DEG);
    float*  dis   = (float*)(ws + WS_DIS);
    int*    misc  = (int*)(ws + WS_MISC);
    u32*    gmaxb = (u32*)(ws + WS_GMAX);
    float*  gsum  = (float*)(ws + WS_GSUM);
    float*  gcnt  = (float*)(ws + WS_GCNT);
    float*  P     = (float*)(ws + WS_P);
    float*  H     = (float*)(ws + WS_H);

    // ---- phase A: scores, matching, coarse graph ----
    init_misc<<<NN / 256, 256, 0, stream>>>(emax, ssum, deg, misc, gmaxb, gsum, gcnt,
                                            best, used);
    node_dots<<<NN / 4, 256, 0, stream>>>(x, pool_w, a_d, b_d);
    edge_p1<<<NE / 256, 256, 0, stream>>>(ei, a_d, b_d, pool_b, exd, emax);
    edge_p2<<<NE / 256, 256, 0, stream>>>(ei, exd, emax, ssum);
    edge_p3<<<NE / 256, 256, 0, stream>>>(ei, exd, ssum, score, key, sel, act0, best);

    // flattened peeling: round r list in act[r%2], count misc[1 + r%2]
    {
        static const int gr[13] = {512, 512, 256, 128, 64, 32, 16, 8, 8, 4, 4, 4, 4};
        int* acts[2] = {act0, act1};
        for (int r = 0; r < 12; ++r) {
            int c = r & 1, n = 1 - c;
            mk_sel<<<gr[r], 256, 0, stream>>>(key, ei, acts[c], &misc[1 + c],
                                              &misc[1 + n], best, used, sel);
            mk_compact<<<gr[r], 256, 0, stream>>>(ei, acts[c], &misc[1 + c],
                                                  acts[n], &misc[1 + n], best, used);
            mk_min<<<gr[r + 1], 256, 0, stream>>>(key, ei, acts[n], &misc[1 + n], best);
        }
        match_fin<<<1, 1024, 0, stream>>>(key, ei, sel, best, used,
                                          act0, act1, &misc[1]);
    }

    cluster_init<<<NN / 256, 256, 0, stream>>>(clus, other, nsc);
    apply_sel<<<NE / 256, 256, 0, stream>>>(ei, sel, score, clus, other, nsc);
    init_ht<<<HTS / 256, 256, 0, stream>>>(ht);
    coarse_build<<<NE / 256, 256, 0, stream>>>(ei, clus, ht, misc, ce_u, ce_v, deg);
    dis_kernel<<<NN / 256, 256, 0, stream>>>(deg, dis);

    // ---- phase B: ChebConv layers (MFMA), pooling, readout ----
    dim3 gg(8, 256);
    conv_b<<<dim3(4, 132), 256, 0, stream>>>(c1_w0, c1_w1, bthi, btlo, FIN, 1056);
    gemm_mfma<true><<<gg, 256, 0, stream>>>(x, bthi, btlo, P, FIN, 1056, FIN, clus, other, nsc);
    spmm_add<<<(NE * 128) / 256, 256, 0, stream>>>(P, ce_u, ce_v, dis, misc);
    act_bn<<<(NN * 128) / 256, 256, 0, stream>>>(P, c1_b, bn1, H);

    conv_b<<<dim3(4, 64), 256, 0, stream>>>(c2_w0, c2_w1, bthi, btlo, 512, 512);
    gemm_mfma<false><<<gg, 256, 0, stream>>>(H, bthi, btlo, P, 512, 512, 512, clus, other, nsc);
    spmm_add<<<(NE * 128) / 256, 256, 0, stream>>>(P, ce_u, ce_v, dis, misc);
    act_bn<<<(NN * 128) / 256, 256, 0, stream>>>(P, c2_b, bn2, H);

    pool_kernel<<<NN / 64, 256, 0, stream>>>(H, clus, batch, gmaxb, gsum, gcnt);
    readout<<<1, 512, 0, stream>>>(gmaxb, gsum, gcnt, l1w, l1b, bn3,
                                   l2w, l2b, bn4, l3w, l3b, out);
}

// Round 4
// 2753.969 us; speedup vs baseline: 2.4414x; 1.1520x over previous
//
#include <hip/hip_runtime.h>
#include <hip/hip_bf16.h>
#include <cstdint>
#include <cmath>

typedef unsigned int u32;
typedef unsigned long long u64;
typedef float f32x4 __attribute__((ext_vector_type(4)));
typedef __bf16 bf16x8 __attribute__((ext_vector_type(8)));
typedef unsigned short us8 __attribute__((ext_vector_type(8)));
typedef unsigned short us4 __attribute__((ext_vector_type(4)));

#define NN 32768
#define NE 131072
#define FIN 1025
#define HTS 262144
#define HTM (HTS - 1)

// ---------------- workspace layout (byte offsets) ----------------
// Phase A (scores+matching) scratch [0, 4456448) is overlaid in phase B by Bt+pxlast.
#define WS_A_D    0ul          // double[NN]
#define WS_B_D    262144ul     // double[NN]
#define WS_EMAX   524288ul     // u32[NN]
#define WS_SSUM   655360ul     // double[NN]
#define WS_EXD    917504ul     // double[NE]
#define WS_KEY    1966080ul    // u64[NE]
#define WS_BEST   3014656ul    // u64[NN]
#define WS_USED   3276800ul    // u32[NN]
#define WS_ACT0   3407872ul    // int[NE]
#define WS_ACT1   3932160ul    // int[NE]   (zone ends 4456448)
#define WS_BTHI   0ul          // ushort[1024*1024] = 2097152 B  (phase B)
#define WS_BTLO   2097152ul    // ushort[1024*1024]              (phase B, ends 4194304)
#define WS_PXL    4194304ul    // float[NN] = 131072 B           (phase B, ends 4325376)
#define WS_HT     1966080ul    // u32[HTS] overlays KEY (key dead before coarse_build)
// persistent across phases:
#define WS_SCORE  4456448ul    // float[NE]
#define WS_SEL    4980736ul    // int[NE]
#define WS_CLUST  5505024ul    // int[NN]
#define WS_OTHER  5636096ul    // int[NN]
#define WS_NSC    5767168ul    // float[NN]
#define WS_CEU    5898240ul    // int[NE]
#define WS_CEV    6422528ul    // int[NE]
#define WS_DEG    6946816ul    // u32[NN]
#define WS_DIS    7077888ul    // float[NN]
#define WS_MISC   7208960ul    // int[64]  [0]=coarse cnt, [1]=listA cnt, [2]=listB cnt
#define WS_GMAX   7209216ul    // u32[8*512]
#define WS_GSUM   7225600ul    // float[8*512]
#define WS_GCNT   7241984ul    // float[64]
#define WS_P      7242240ul    // float[NN*1024]
#define WS_H      141459968ul  // Ax bf16[NN*1024] (gemm1), then H fp32[NN*512]  -> ends 208568832

__device__ __forceinline__ u32 enc_f(float f) {
    u32 b = __float_as_uint(f);
    return (b & 0x80000000u) ? ~b : (b | 0x80000000u);
}
__device__ __forceinline__ float dec_f(u32 m) {
    return (m & 0x80000000u) ? __uint_as_float(m ^ 0x80000000u) : __uint_as_float(~m);
}
__device__ __forceinline__ double wave_sum(double v) {
    #pragma unroll
    for (int off = 32; off > 0; off >>= 1) v += __shfl_down(v, off, 64);
    return v;
}
__device__ __forceinline__ unsigned short f2bf(float v) {   // RNE f32->bf16
    u32 b = __float_as_uint(v);
    u32 r = b + 0x7FFFu + ((b >> 16) & 1u);
    return (unsigned short)(r >> 16);
}
__device__ __forceinline__ float bf2f(unsigned short h) {
    return __uint_as_float(((u32)h) << 16);
}
__device__ __forceinline__ bf16x8 ld_frag(const unsigned short* p) {
    union { us8 u; bf16x8 b; } t;
    t.u = *(const us8*)p;
    return t.b;
}
// async global->LDS, 16B per lane; lds must be wave-uniform base (lane writes base+lane*16)
__device__ __forceinline__ void dma16(unsigned short* lds, const unsigned short* g) {
    __builtin_amdgcn_global_load_lds((const __attribute__((address_space(1))) u32*)g,
                                     (__attribute__((address_space(3))) u32*)lds, 16, 0, 0);
}

// ---------------- init ----------------
__global__ void init_misc(u32* emax, double* ssum, u32* deg,
                          int* misc, u32* gmaxb, float* gsum, float* gcnt,
                          u64* best, u32* used) {
    int i = blockIdx.x * 256 + threadIdx.x;
    if (i < NN) { emax[i] = 0u; ssum[i] = 0.0; deg[i] = 0u; best[i] = ~0ull; used[i] = 0u; }
    if (i < 4096) { gmaxb[i] = 0u; gsum[i] = 0.0f; }
    if (i < 64) { misc[i] = (i == 1) ? NE : 0; gcnt[i] = 0.0f; }
}
__global__ void init_ht(u32* ht) {
    int i = blockIdx.x * 256 + threadIdx.x;
    if (i < HTS) ht[i] = 0xFFFFFFFFu;
}

// ---------------- per-node dots with pool_w halves (double accum) ----------------
__global__ void node_dots(const float* __restrict__ x, const float* __restrict__ pw,
                          double* a_d, double* b_d) {
    int wave = (blockIdx.x * blockDim.x + threadIdx.x) >> 6;
    int lane = threadIdx.x & 63;
    if (wave >= NN) return;
    const float* xr = x + (size_t)wave * FIN;
    double s0 = 0.0, s1 = 0.0;
    for (int f = lane; f < FIN; f += 64) {
        double xv = (double)xr[f];
        s0 += xv * (double)pw[f];
        s1 += xv * (double)pw[FIN + f];
    }
    s0 = wave_sum(s0); s1 = wave_sum(s1);
    if (lane == 0) { a_d[wave] = s0; b_d[wave] = s1; }
}

// ---------------- edge score pipeline ----------------
__global__ void edge_p1(const int* __restrict__ ei, const double* __restrict__ a_d,
                        const double* __restrict__ b_d, const float* __restrict__ pb,
                        double* e_d, u32* emax) {
    int k = blockIdx.x * 256 + threadIdx.x;
    if (k >= NE) return;
    int u = ei[k], v = ei[NE + k];
    double e = a_d[u] + b_d[v] + (double)pb[0];
    e_d[k] = e;
    atomicMax(&emax[v], enc_f((float)e));
}
__global__ void edge_p2(const int* __restrict__ ei, double* e_d,
                        const u32* __restrict__ emax, double* ssum) {
    int k = blockIdx.x * 256 + threadIdx.x;
    if (k >= NE) return;
    int v = ei[NE + k];
    float mf = dec_f(emax[v]);
    double ex = exp(e_d[k] - (double)mf);
    e_d[k] = ex;
    unsafeAtomicAdd(&ssum[v], ex);
}
// also: worklist init + round-0 min pass
__global__ void edge_p3(const int* __restrict__ ei, const double* __restrict__ e_d,
                        const double* __restrict__ ssum, float* score, u64* key,
                        int* sel, int* act0, u64* best) {
    int k = blockIdx.x * 256 + threadIdx.x;
    if (k >= NE) return;
    int u = ei[k], v = ei[NE + k];
    float sc = (float)(e_d[k] / ssum[v] + 0.5);
    score[k] = sc;
    u32 m = enc_f(sc);
    u64 kk = ((u64)(m ^ 0xFFFFFFFFu) << 32) | (u32)k;  // low = high score, tie: low idx
    key[k] = kk;
    sel[k] = 0;
    act0[k] = k;
    atomicMin(&best[u], kk);
    atomicMin(&best[v], kk);
}

// ---------------- flattened dominant-edge peeling rounds ----------------
__global__ void mk_sel(const u64* __restrict__ key, const int* __restrict__ ei,
                       const int* __restrict__ act, const int* __restrict__ cntp,
                       int* ncntp, const u64* __restrict__ best,
                       u32* used, int* sel) {
    int cnt = cntp[0];
    int stride = gridDim.x * blockDim.x;
    int gid = blockIdx.x * blockDim.x + threadIdx.x;
    if (gid == 0) ncntp[0] = 0;
    for (int i = gid; i < cnt; i += stride) {
        int e = act[i];
        u64 k = key[e];
        int a = ei[e], b = ei[NE + e];
        if (best[a] == k && best[b] == k) { sel[e] = 1; used[a] = 1u; used[b] = 1u; }
    }
}
__global__ void mk_compact(const int* __restrict__ ei, const int* __restrict__ act,
                           const int* __restrict__ cntp, int* nxt, int* ncntp,
                           u64* best, const u32* __restrict__ used) {
    int cnt = cntp[0];
    int stride = gridDim.x * blockDim.x;
    for (int i = blockIdx.x * blockDim.x + threadIdx.x; i < cnt; i += stride) {
        int e = act[i];
        int a = ei[e], b = ei[NE + e];
        best[a] = ~0ull; best[b] = ~0ull;
        bool live = !(used[a] | used[b]);
        u64 mask = __ballot(live);
        if (mask) {
            int lane = threadIdx.x & 63;
            int leader = __ffsll((unsigned long long)mask) - 1;
            int base = 0;
            if (lane == leader) base = atomicAdd(ncntp, __popcll(mask));
            base = __shfl(base, leader, 64);
            if (live) nxt[base + __popcll(mask & ((1ull << lane) - 1ull))] = e;
        }
    }
}
__global__ void mk_min(const u64* __restrict__ key, const int* __restrict__ ei,
                       const int* __restrict__ act, const int* __restrict__ cntp,
                       u64* best) {
    int cnt = cntp[0];
    int stride = gridDim.x * blockDim.x;
    for (int i = blockIdx.x * blockDim.x + threadIdx.x; i < cnt; i += stride) {
        int e = act[i];
        u64 k = key[e];
        atomicMin(&best[ei[e]], k);
        atomicMin(&best[ei[NE + e]], k);
    }
}
// single-block finisher for the tiny tail (loops to completion)
__global__ void __launch_bounds__(1024) match_fin(
        const u64* __restrict__ key, const int* __restrict__ ei,
        int* sel, u64* best, u32* used,
        int* listA, int* listB, const int* __restrict__ cntp) {
    int tid = threadIdx.x;
    int cnt = cntp[0];
    int* cur = listA; int* nxt = listB;
    __shared__ int s_n;
    for (int round = 0; round < 4096 && cnt > 0; ++round) {
        for (int i = tid; i < cnt; i += 1024) {
            int e = cur[i]; u64 k = key[e];
            atomicMin(&best[ei[e]], k);
            atomicMin(&best[ei[NE + e]], k);
        }
        __syncthreads();
        for (int i = tid; i < cnt; i += 1024) {
            int e = cur[i]; u64 k = key[e];
            int a = ei[e], b = ei[NE + e];
            if (best[a] == k && best[b] == k) { sel[e] = 1; used[a] = 1u; used[b] = 1u; }
        }
        if (tid == 0) s_n = 0;
        __syncthreads();
        for (int i = tid; i < cnt; i += 1024) {
            int e = cur[i];
            int a = ei[e], b = ei[NE + e];
            best[a] = ~0ull; best[b] = ~0ull;
            if (!(used[a] | used[b])) {
                int idx = atomicAdd(&s_n, 1);
                nxt[idx] = e;
            }
        }
        __syncthreads();
        cnt = s_n;
        int* t = cur; cur = nxt; nxt = t;
        __syncthreads();
    }
}

__global__ void cluster_init(int* cluster, int* other, float* nscore) {
    int n = blockIdx.x * 256 + threadIdx.x;
    if (n >= NN) return;
    cluster[n] = n; other[n] = -1; nscore[n] = 1.0f;
}
__global__ void apply_sel(const int* __restrict__ ei, const int* __restrict__ sel,
                          const float* __restrict__ score,
                          int* cluster, int* other, float* nscore) {
    int e = blockIdx.x * 256 + threadIdx.x;
    if (e >= NE) return;
    if (sel[e] != 1) return;
    int u = ei[e], v = ei[NE + e];
    int rep = min(u, v);
    cluster[u] = rep; cluster[v] = rep;
    if (u != v) other[rep] = u + v - rep;
    nscore[rep] = score[e];
}

// ---------------- coarse graph: dedup (cu,cv) pairs via hash set ----------------
__global__ void coarse_build(const int* __restrict__ ei, const int* __restrict__ cluster,
                             u32* ht, int* misc, int* ce_u, int* ce_v, u32* deg) {
    int e = blockIdx.x * 256 + threadIdx.x;
    if (e >= NE) return;
    int cu = cluster[ei[e]], cv = cluster[ei[NE + e]];
    if (cu == cv) return;
    u32 k = (u32)cu * 32768u + (u32)cv;
    u32 h = ((k * 2654435761u) >> 12) & HTM;
    while (true) {
        u32 old = atomicCAS(&ht[h], 0xFFFFFFFFu, k);
        if (old == 0xFFFFFFFFu) {
            int idx = atomicAdd(&misc[0], 1);
            ce_u[idx] = cu; ce_v[idx] = cv;
            atomicAdd(&deg[cu], 1u);
            break;
        }
        if (old == k) break;
        h = (h + 1) & HTM;
    }
}
__global__ void dis_kernel(const u32* __restrict__ deg, float* dis) {
    int n = blockIdx.x * 256 + threadIdx.x;
    if (n >= NN) return;
    u32 d = deg[n];
    dis[n] = d ? (float)(1.0 / sqrt((double)d)) : 0.0f;
}

// ---------------- pre-gather px -> bf16 Ax[NN][1024], pxlast[NN] fp32 (col 1024) ----------------
__global__ void conv_a1(const float* __restrict__ x, const int* __restrict__ clus,
                        const int* __restrict__ other, const float* __restrict__ nsc,
                        unsigned short* __restrict__ Abf, float* __restrict__ pxl) {
    int r = blockIdx.x;
    int t = threadIdx.x;
    bool valid = (clus[r] == r);
    int o = other[r];
    float s = nsc[r];
    const float* xr = x + (size_t)r * FIN;
    const float* xo = x + (size_t)(o >= 0 ? o : r) * FIN;
    int c0 = t << 2;
    unsigned short h[4];
    #pragma unroll
    for (int j = 0; j < 4; ++j) {
        float v = 0.0f;
        if (valid) {
            v = xr[c0 + j];
            if (o >= 0) v += xo[c0 + j];
            v *= s;
        }
        h[j] = f2bf(v);
    }
    *(us4*)&Abf[(size_t)r * 1024 + c0] = *(const us4*)h;
    if (t == 0) {
        float v = 0.0f;
        if (valid) { v = xr[1024]; if (o >= 0) v += xo[1024]; v *= s; }
        pxl[r] = v;
    }
}

// ---------------- weight transpose + bf16 hi/lo split: Bt[n][KP] ----------------
__global__ void conv_b(const float* __restrict__ B0, const float* __restrict__ B1,
                       unsigned short* __restrict__ Bhi, unsigned short* __restrict__ Blo,
                       int KP) {
    int n = blockIdx.x * 256 + threadIdx.x;   // grid.x = 4 -> n in [0,1024)
    int k0 = blockIdx.y * 8;
    unsigned short h[8], l[8];
    #pragma unroll
    for (int j = 0; j < 8; ++j) {
        int k = k0 + j;
        float v = (n < 512) ? B0[(size_t)k * 512 + n] : B1[(size_t)k * 512 + (n - 512)];
        h[j] = f2bf(v);
        l[j] = f2bf(v - bf2f(h[j]));
    }
    *(us8*)&Bhi[(size_t)n * KP + k0] = *(const us8*)h;
    *(us8*)&Blo[(size_t)n * KP + k0] = *(const us8*)l;
}

// ---------------- bf16 MFMA GEMM: P[M x 1024] = A[M x KP] @ Bt^T (+ rank-1) ----------------
// 128x128 tile, BK=32, 4 waves. A: bf16 via global_load_lds double-buffer (BF16A)
// or fp32->bf16 VGPR staging (!BF16A). B hi/lo fragments direct from global (L2-resident).
template <bool BF16A, bool R1>
__global__ void __launch_bounds__(256, 3) gemm_bf16(
        const unsigned short* __restrict__ Abf, const float* __restrict__ Af,
        const unsigned short* __restrict__ Bhi, const unsigned short* __restrict__ Blo,
        float* __restrict__ P, int KP,
        const float* __restrict__ pxl, const float* __restrict__ w0,
        const float* __restrict__ w1) {
    __shared__ unsigned short Ah[2][128 * 32];
    int tid = threadIdx.x;
    int bid = blockIdx.x;
    // XCD swizzle: xcd = bid&7 owns m-tiles [xcd*32, xcd*32+32), n fastest
    int loc = bid >> 3;
    int bn = (loc & 7) << 7;
    int bm = ((((bid & 7) << 5) | (loc >> 3))) << 7;
    int wave = tid >> 6, lane = tid & 63, quad = lane >> 4, l16 = lane & 15;
    int moff = (wave >> 1) << 6, noff = (wave & 1) << 6;
    int kq = tid & 3, rr = tid >> 2;
    f32x4 acc[4][4];
    #pragma unroll
    for (int i = 0; i < 4; ++i)
        #pragma unroll
        for (int j = 0; j < 4; ++j) acc[i][j] = (f32x4){0.f, 0.f, 0.f, 0.f};

    int KT = KP >> 5;
    const unsigned short* gA = nullptr;
    unsigned short* lA = nullptr;
    if (BF16A) {
        gA = Abf + (size_t)(bm + (wave << 4) + (lane >> 2)) * KP + ((lane & 3) << 3);
        lA = &Ah[0][0] + ((wave << 4) << 5);   // wave-uniform base
        dma16(lA, gA);
        dma16(lA + (64 << 5), gA + (size_t)64 * KP);
    } else {
        #pragma unroll
        for (int p = 0; p < 2; ++p) {
            const float* g = Af + (size_t)(bm + rr + (p << 6)) * KP + (kq << 3);
            float4 t0 = *(const float4*)g, t1 = *(const float4*)(g + 4);
            unsigned short h[8] = {f2bf(t0.x), f2bf(t0.y), f2bf(t0.z), f2bf(t0.w),
                                   f2bf(t1.x), f2bf(t1.y), f2bf(t1.z), f2bf(t1.w)};
            *(us8*)&Ah[0][((rr + (p << 6)) << 5) + (kq << 3)] = *(const us8*)h;
        }
    }
    __syncthreads();

    for (int kt = 0; kt < KT; ++kt) {
        int cur = kt & 1;
        int k0 = kt << 5;
        float4 t0, t1, t2, t3;
        if (BF16A) {
            if (kt + 1 < KT) {   // async prefetch overlaps this iteration's compute
                unsigned short* l = &Ah[1 - cur][0] + ((wave << 4) << 5);
                const unsigned short* g = gA + ((kt + 1) << 5);
                dma16(l, g);
                dma16(l + (64 << 5), g + (size_t)64 * KP);
            }
        } else if (kt + 1 < KT) {
            const float* g = Af + (size_t)(bm + rr) * KP + ((kt + 1) << 5) + (kq << 3);
            t0 = *(const float4*)g; t1 = *(const float4*)(g + 4);
            const float* g2 = g + (size_t)64 * KP;
            t2 = *(const float4*)g2; t3 = *(const float4*)(g2 + 4);
        }
        const unsigned short* lb = &Ah[BF16A ? cur : 0][0];
        bf16x8 af[4], bh4[4], bl4[4];
        #pragma unroll
        for (int i = 0; i < 4; ++i) {
            af[i] = ld_frag(lb + ((moff + (i << 4) + l16) << 5) + (quad << 3));
            size_t nrow = (size_t)(bn + noff + (i << 4) + l16) * KP + k0 + (quad << 3);
            bh4[i] = ld_frag(&Bhi[nrow]);
            bl4[i] = ld_frag(&Blo[nrow]);
        }
        #pragma unroll
        for (int mi = 0; mi < 4; ++mi)
            #pragma unroll
            for (int ni = 0; ni < 4; ++ni) {
                acc[mi][ni] = __builtin_amdgcn_mfma_f32_16x16x32_bf16(af[mi], bh4[ni], acc[mi][ni], 0, 0, 0);
                acc[mi][ni] = __builtin_amdgcn_mfma_f32_16x16x32_bf16(af[mi], bl4[ni], acc[mi][ni], 0, 0, 0);
            }
        __syncthreads();
        if (!BF16A && kt + 1 < KT) {
            unsigned short h[8] = {f2bf(t0.x), f2bf(t0.y), f2bf(t0.z), f2bf(t0.w),
                                   f2bf(t1.x), f2bf(t1.y), f2bf(t1.z), f2bf(t1.w)};
            *(us8*)&Ah[0][(rr << 5) + (kq << 3)] = *(const us8*)h;
            unsigned short h2[8] = {f2bf(t2.x), f2bf(t2.y), f2bf(t2.z), f2bf(t2.w),
                                    f2bf(t3.x), f2bf(t3.y), f2bf(t3.z), f2bf(t3.w)};
            *(us8*)&Ah[0][((rr + 64) << 5) + (kq << 3)] = *(const us8*)h2;
            __syncthreads();
        }
    }
    // epilogue: C/D row=quad*4+r2, col=l16; optional rank-1 (column 1024 of A/B)
    #pragma unroll
    for (int mi = 0; mi < 4; ++mi)
        #pragma unroll
        for (int ni = 0; ni < 4; ++ni) {
            int col = bn + noff + (ni << 4) + l16;
            float wl = 0.0f;
            if (R1) wl = (col < 512) ? w0[524288 + col] : w1[524288 + col - 512];
            #pragma unroll
            for (int r2 = 0; r2 < 4; ++r2) {
                int row = bm + moff + (mi << 4) + (quad << 2) + r2;
                float v = acc[mi][ni][r2];
                if (R1) v += pxl[row] * wl;
                P[(size_t)row * 1024 + col] = v;
            }
        }
}

// ---------------- sparse accumulate: P[b][c] += -dis[a]*dis[b] * P[a][512+c] ----------------
__global__ void spmm_add(float* __restrict__ P,
                         const int* __restrict__ ce_u, const int* __restrict__ ce_v,
                         const float* __restrict__ dis, const int* __restrict__ misc) {
    int idx = blockIdx.x * 256 + threadIdx.x;
    int e = idx >> 7;
    if (e >= misc[0]) return;
    int c = (idx & 127) << 2;
    int a = ce_u[e], b = ce_v[e];
    float coef = -dis[a] * dis[b];
    float4 p = *(const float4*)&P[(size_t)a * 1024 + 512 + c];
    float* dst = &P[(size_t)b * 1024 + c];
    unsafeAtomicAdd(dst + 0, coef * p.x);
    unsafeAtomicAdd(dst + 1, coef * p.y);
    unsafeAtomicAdd(dst + 2, coef * p.z);
    unsafeAtomicAdd(dst + 3, coef * p.w);
}

// ---------------- h = relu(BN(P[:, :512] + bias)) ----------------
__global__ void act_bn(const float* __restrict__ P, const float* __restrict__ bias,
                       const float* __restrict__ bn, float* __restrict__ H) {
    int idx = blockIdx.x * 256 + threadIdx.x;
    if (idx >= NN * 128) return;
    int r = idx >> 7;
    int j4 = (idx & 127) << 2;
    float4 t = *(const float4*)&P[(size_t)r * 1024 + j4];
    float o[4] = {t.x, t.y, t.z, t.w};
    #pragma unroll
    for (int c = 0; c < 4; ++c) {
        int j = j4 + c;
        float ga = bn[j], be = bn[512 + j], mn = bn[1024 + j], vr = bn[1536 + j];
        float sc = (float)(1.0 / sqrt((double)vr + 1e-5));
        float v = (o[c] + bias[j] - mn) * sc * ga + be;
        o[c] = v > 0.0f ? v : 0.0f;
    }
    *(float4*)&H[(size_t)idx << 2] = make_float4(o[0], o[1], o[2], o[3]);
}

// ---------------- global max+mean pool over valid nodes per graph ----------------
__global__ void __launch_bounds__(256) pool_kernel(
        const float* __restrict__ H, const int* __restrict__ cluster,
        const int* __restrict__ batch, u32* gmaxb, float* gsum, float* gcnt) {
    int t = threadIdx.x;
    int n0 = blockIdx.x * 64;
    float m0 = 0.0f, m1 = 0.0f, s0 = 0.0f, s1 = 0.0f;
    int cntl = 0;
    int cur = batch[n0];
    for (int i = 0; i < 64; ++i) {
        int n = n0 + i;
        int bt = batch[n];
        if (bt != cur) {
            atomicMax(&gmaxb[cur * 512 + t], __float_as_uint(m0));
            atomicMax(&gmaxb[cur * 512 + t + 256], __float_as_uint(m1));
            unsafeAtomicAdd(&gsum[cur * 512 + t], s0);
            unsafeAtomicAdd(&gsum[cur * 512 + t + 256], s1);
            if (t == 0) unsafeAtomicAdd(&gcnt[cur], (float)cntl);
            m0 = m1 = s0 = s1 = 0.0f; cntl = 0; cur = bt;
        }
        if (cluster[n] == n) {
            float h0 = H[(size_t)n * 512 + t];
            float h1 = H[(size_t)n * 512 + t + 256];
            m0 = fmaxf(m0, h0); m1 = fmaxf(m1, h1);
            s0 += h0; s1 += h1;
            ++cntl;
        }
    }
    atomicMax(&gmaxb[cur * 512 + t], __float_as_uint(m0));
    atomicMax(&gmaxb[cur * 512 + t + 256], __float_as_uint(m1));
    unsafeAtomicAdd(&gsum[cur * 512 + t], s0);
    unsafeAtomicAdd(&gsum[cur * 512 + t + 256], s1);
    if (t == 0) unsafeAtomicAdd(&gcnt[cur], (float)cntl);
}

// ---------------- readout MLP + log_softmax (tiny, one block) ----------------
__global__ void __launch_bounds__(512) readout(
        const u32* __restrict__ gmaxb, const float* __restrict__ gsum,
        const float* __restrict__ gcnt,
        const float* __restrict__ l1w, const float* __restrict__ l1b,
        const float* __restrict__ bn3,
        const float* __restrict__ l2w, const float* __restrict__ l2b,
        const float* __restrict__ bn4,
        const float* __restrict__ l3w, const float* __restrict__ l3b,
        float* __restrict__ out) {
    __shared__ float G[8 * 1024];
    __shared__ float G1[8 * 512];
    __shared__ float G2[8 * 256];
    int t = threadIdx.x;
    for (int idx = t; idx < 8192; idx += 512) {
        int b = idx >> 10, j = idx & 1023;
        float v;
        if (j < 512) v = __uint_as_float(gmaxb[b * 512 + j]);
        else v = gsum[b * 512 + (j - 512)] / fmaxf(gcnt[b], 1.0f);
        G[idx] = v;
    }
    __syncthreads();
    {
        int o = t;
        float acc[8];
        #pragma unroll
        for (int b = 0; b < 8; ++b) acc[b] = l1b[o];
        for (int k = 0; k < 1024; ++k) {
            float w = l1w[k * 512 + o];
            #pragma unroll
            for (int b = 0; b < 8; ++b) acc[b] += G[b * 1024 + k] * w;
        }
        float ga = bn3[o], be = bn3[512 + o], mn = bn3[1024 + o], vr = bn3[1536 + o];
        float sc = (float)(1.0 / sqrt((double)vr + 1e-5));
        #pragma unroll
        for (int b = 0; b < 8; ++b) {
            float v = (acc[b] - mn) * sc * ga + be;
            G1[b * 512 + o] = v > 0.0f ? v : 0.0f;
        }
    }
    __syncthreads();
    if (t < 256) {
        int o = t;
        float acc[8];
        #pragma unroll
        for (int b = 0; b < 8; ++b) acc[b] = l2b[o];
        for (int k = 0; k < 512; ++k) {
            float w = l2w[k * 256 + o];
            #pragma unroll
            for (int b = 0; b < 8; ++b) acc[b] += G1[b * 512 + k] * w;
        }
        float ga = bn4[o], be = bn4[256 + o], mn = bn4[512 + o], vr = bn4[768 + o];
        float sc = (float)(1.0 / sqrt((double)vr + 1e-5));
        #pragma unroll
        for (int b = 0; b < 8; ++b) {
            float v = (acc[b] - mn) * sc * ga + be;
            v = v > 0.0f ? v : 0.0f;
            G2[b * 256 + o] = v;
            out[32 + b * 256 + o] = v;
        }
    }
    __syncthreads();
    if (t < 8) {
        int b = t;
        float r[4];
        #pragma unroll
        for (int c = 0; c < 4; ++c) {
            float acc = l3b[c];
            for (int k = 0; k < 256; ++k) acc += G2[b * 256 + k] * l3w[k * 4 + c];
            r[c] = acc > 0.0f ? acc : 0.0f;
        }
        float mx = fmaxf(fmaxf(r[0], r[1]), fmaxf(r[2], r[3]));
        float s = 0.0f;
        #pragma unroll
        for (int c = 0; c < 4; ++c) s += expf(r[c] - mx);
        float lse = mx + logf(s);
        #pragma unroll
        for (int c = 0; c < 4; ++c) out[b * 4 + c] = r[c] - lse;
    }
}

extern "C" void kernel_launch(void* const* d_in, const int* in_sizes, int n_in,
                              void* d_out, int out_size, void* d_ws, size_t ws_size,
                              hipStream_t stream) {
    const float* x      = (const float*)d_in[0];
    const int*   ei     = (const int*)d_in[1];
    const int*   batch  = (const int*)d_in[2];
    const float* pool_w = (const float*)d_in[3];
    const float* pool_b = (const float*)d_in[4];
    const float* c1_w0  = (const float*)d_in[5];
    const float* c1_w1  = (const float*)d_in[6];
    const float* c1_b   = (const float*)d_in[7];
    const float* c2_w0  = (const float*)d_in[8];
    const float* c2_w1  = (const float*)d_in[9];
    const float* c2_b   = (const float*)d_in[10];
    const float* bn1    = (const float*)d_in[11];
    const float* bn2    = (const float*)d_in[12];
    const float* bn3    = (const float*)d_in[13];
    const float* bn4    = (const float*)d_in[14];
    const float* l1w    = (const float*)d_in[15];
    const float* l1b    = (const float*)d_in[16];
    const float* l2w    = (const float*)d_in[17];
    const float* l2b    = (const float*)d_in[18];
    const float* l3w    = (const float*)d_in[19];
    const float* l3b    = (const float*)d_in[20];
    float* out = (float*)d_out;
    char* ws = (char*)d_ws;

    double* a_d   = (double*)(ws + WS_A_D);
    double* b_d   = (double*)(ws + WS_B_D);
    u32*    emax  = (u32*)(ws + WS_EMAX);
    double* ssum  = (double*)(ws + WS_SSUM);
    double* exd   = (double*)(ws + WS_EXD);
    u64*    key   = (u64*)(ws + WS_KEY);
    u64*    best  = (u64*)(ws + WS_BEST);
    u32*    used  = (u32*)(ws + WS_USED);
    int*    act0  = (int*)(ws + WS_ACT0);
    int*    act1  = (int*)(ws + WS_ACT1);
    unsigned short* bthi = (unsigned short*)(ws + WS_BTHI);
    unsigned short* btlo = (unsigned short*)(ws + WS_BTLO);
    float*  pxl   = (float*)(ws + WS_PXL);
    u32*    ht    = (u32*)(ws + WS_HT);
    float*  score = (float*)(ws + WS_SCORE);
    int*    sel   = (int*)(ws + WS_SEL);
    int*    clus  = (int*)(ws + WS_CLUST);
    int*    other = (int*)(ws + WS_OTHER);
    float*  nsc   = (float*)(ws + WS_NSC);
    int*    ce_u  = (int*)(ws + WS_CEU);
    int*    ce_v  = (int*)(ws + WS_CEV);
    u32*    deg   = (u32*)(ws + WS_DEG);
    float*  dis   = (float*)(ws + WS_DIS);
    int*    misc  = (int*)(ws + WS_MISC);
    u32*    gmaxb = (u32*)(ws + WS_GMAX);
    float*  gsum  = (float*)(ws + WS_GSUM);
    float*  gcnt  = (float*)(ws + WS_GCNT);
    float*  P     = (float*)(ws + WS_P);
    unsigned short* ax = (unsigned short*)(ws + WS_H);   // Ax overlays H region
    float*  H     = (float*)(ws + WS_H);

    // ---- phase A: scores, matching, coarse graph ----
    init_misc<<<NN / 256, 256, 0, stream>>>(emax, ssum, deg, misc, gmaxb, gsum, gcnt,
                                            best, used);
    node_dots<<<NN / 4, 256, 0, stream>>>(x, pool_w, a_d, b_d);
    edge_p1<<<NE / 256, 256, 0, stream>>>(ei, a_d, b_d, pool_b, exd, emax);
    edge_p2<<<NE / 256, 256, 0, stream>>>(ei, exd, emax, ssum);
    edge_p3<<<NE / 256, 256, 0, stream>>>(ei, exd, ssum, score, key, sel, act0, best);

    // flattened peeling: round r list in act[r%2], count misc[1 + r%2]
    {
        static const int gr[13] = {512, 512, 256, 128, 64, 32, 16, 8, 8, 4, 4, 4, 4};
        int* acts[2] = {act0, act1};
        for (int r = 0; r < 12; ++r) {
            int c = r & 1, n = 1 - c;
            mk_sel<<<gr[r], 256, 0, stream>>>(key, ei, acts[c], &misc[1 + c],
                                              &misc[1 + n], best, used, sel);
            mk_compact<<<gr[r], 256, 0, stream>>>(ei, acts[c], &misc[1 + c],
                                                  acts[n], &misc[1 + n], best, used);
            mk_min<<<gr[r + 1], 256, 0, stream>>>(key, ei, acts[n], &misc[1 + n], best);
        }
        match_fin<<<1, 1024, 0, stream>>>(key, ei, sel, best, used,
                                          act0, act1, &misc[1]);
    }

    cluster_init<<<NN / 256, 256, 0, stream>>>(clus, other, nsc);
    apply_sel<<<NE / 256, 256, 0, stream>>>(ei, sel, score, clus, other, nsc);
    init_ht<<<HTS / 256, 256, 0, stream>>>(ht);
    coarse_build<<<NE / 256, 256, 0, stream>>>(ei, clus, ht, misc, ce_u, ce_v, deg);
    dis_kernel<<<NN / 256, 256, 0, stream>>>(deg, dis);

    // ---- phase B: ChebConv layers (MFMA), pooling, readout ----
    conv_b<<<dim3(4, 128), 256, 0, stream>>>(c1_w0, c1_w1, bthi, btlo, 1024);
    conv_a1<<<NN, 256, 0, stream>>>(x, clus, other, nsc, ax, pxl);
    gemm_bf16<true, true><<<2048, 256, 0, stream>>>(ax, nullptr, bthi, btlo, P, 1024,
                                                    pxl, c1_w0, c1_w1);
    spmm_add<<<(NE * 128) / 256, 256, 0, stream>>>(P, ce_u, ce_v, dis, misc);
    act_bn<<<(NN * 128) / 256, 256, 0, stream>>>(P, c1_b, bn1, H);

    conv_b<<<dim3(4, 64), 256, 0, stream>>>(c2_w0, c2_w1, bthi, btlo, 512);
    gemm_bf16<false, false><<<2048, 256, 0, stream>>>(nullptr, H, bthi, btlo, P, 512,
                                                      nullptr, nullptr, nullptr);
    spmm_add<<<(NE * 128) / 256, 256, 0, stream>>>(P, ce_u, ce_v, dis, misc);
    act_bn<<<(NN * 128) / 256, 256, 0, stream>>>(P, c2_b, bn2, H);

    pool_kernel<<<NN / 64, 256, 0, stream>>>(H, clus, batch, gmaxb, gsum, gcnt);
    readout<<<1, 512, 0, stream>>>(gmaxb, gsum, gcnt, l1w, l1b, bn3,
                                   l2w, l2b, bn4, l3w, l3b, out);
}

// Round 5
// 1299.226 us; speedup vs baseline: 5.1750x; 2.1197x over previous
//
#include <hip/hip_runtime.h>
#include <hip/hip_bf16.h>
#include <cstdint>
#include <cmath>

typedef unsigned int u32;
typedef unsigned long long u64;
typedef float f32x4 __attribute__((ext_vector_type(4)));
typedef __bf16 bf16x8 __attribute__((ext_vector_type(8)));
typedef unsigned short us8 __attribute__((ext_vector_type(8)));
typedef unsigned short us4 __attribute__((ext_vector_type(4)));

#define NN 32768
#define NE 131072
#define FIN 1025
#define HTS 262144
#define HTM (HTS - 1)

// ---------------- workspace layout (byte offsets) ----------------
// Phase A (scores+matching) scratch [0, 4456448) is overlaid in phase B by Bt+pxlast.
#define WS_A_D    0ul          // double[NN]
#define WS_B_D    262144ul     // double[NN]
#define WS_EMAX   524288ul     // u32[NN]
#define WS_SSUM   655360ul     // double[NN]
#define WS_EXD    917504ul     // double[NE]
#define WS_CIN    917504ul     // u32[NN]  overlays EXD head (exd dead after edge_p3;
                               //          cin zeroed in cluster_init, used til scan)
#define WS_KEY    1966080ul    // u64[NE]
#define WS_BEST   3014656ul    // u64[NN]
#define WS_USED   3276800ul    // u32[NN]
#define WS_CUR    3276800ul    // int[NN]  overlays USED (dead after match_fin)
#define WS_ACT0   3407872ul    // int[NE]
#define WS_ACT1   3932160ul    // int[NE]   (zone ends 4456448)
#define WS_BTHI   0ul          // ushort[1024*1024] = 2097152 B  (phase B)
#define WS_BTLO   2097152ul    // ushort[1024*1024]              (phase B, ends 4194304)
#define WS_PXL    4194304ul    // float[NN] = 131072 B           (phase B, ends 4325376)
#define WS_HT     1966080ul    // u32[HTS] overlays KEY (key dead before coarse_build)
// persistent across phases:
#define WS_SCORE  4456448ul    // float[NE]
#define WS_CSRA   4456448ul    // int[NE]  overlays SCORE (score dead after apply_sel)
#define WS_SEL    4980736ul    // int[NE]
#define WS_CSRC   4980736ul    // float[NE] overlays SEL (sel dead after apply_sel)
#define WS_CLUST  5505024ul    // int[NN]
#define WS_OTHER  5636096ul    // int[NN]
#define WS_NSC    5767168ul    // float[NN]
#define WS_CEU    5898240ul    // int[NE]
#define WS_CEV    6422528ul    // int[NE]
#define WS_DEG    6946816ul    // u32[NN]
#define WS_OFF    6946816ul    // int[NN]  overlays DEG (deg dead after dis_kernel)
#define WS_DIS    7077888ul    // float[NN]
#define WS_MISC   7208960ul    // int[64]  [0]=coarse cnt, [1]=listA cnt, [2]=listB cnt
#define WS_GMAX   7209216ul    // u32[8*512]
#define WS_GSUM   7225600ul    // float[8*512]
#define WS_GCNT   7241984ul    // float[64]
#define WS_P      7242240ul    // float[NN*1024]
#define WS_H      141459968ul  // Ax bf16[NN*1024] (gemm1), then H fp32[NN*512]  -> ends 208568832

__device__ __forceinline__ u32 enc_f(float f) {
    u32 b = __float_as_uint(f);
    return (b & 0x80000000u) ? ~b : (b | 0x80000000u);
}
__device__ __forceinline__ float dec_f(u32 m) {
    return (m & 0x80000000u) ? __uint_as_float(m ^ 0x80000000u) : __uint_as_float(~m);
}
__device__ __forceinline__ double wave_sum(double v) {
    #pragma unroll
    for (int off = 32; off > 0; off >>= 1) v += __shfl_down(v, off, 64);
    return v;
}
__device__ __forceinline__ unsigned short f2bf(float v) {   // RNE f32->bf16
    u32 b = __float_as_uint(v);
    u32 r = b + 0x7FFFu + ((b >> 16) & 1u);
    return (unsigned short)(r >> 16);
}
__device__ __forceinline__ float bf2f(unsigned short h) {
    return __uint_as_float(((u32)h) << 16);
}
__device__ __forceinline__ bf16x8 ld_frag(const unsigned short* p) {
    union { us8 u; bf16x8 b; } t;
    t.u = *(const us8*)p;
    return t.b;
}
__device__ __forceinline__ void dma16(unsigned short* lds, const unsigned short* g) {
    __builtin_amdgcn_global_load_lds((const __attribute__((address_space(1))) u32*)g,
                                     (__attribute__((address_space(3))) u32*)lds, 16, 0, 0);
}

// ---------------- init ----------------
__global__ void init_misc(u32* emax, double* ssum, u32* deg,
                          int* misc, u32* gmaxb, float* gsum, float* gcnt,
                          u64* best, u32* used) {
    int i = blockIdx.x * 256 + threadIdx.x;
    if (i < NN) { emax[i] = 0u; ssum[i] = 0.0; deg[i] = 0u; best[i] = ~0ull; used[i] = 0u; }
    if (i < 4096) { gmaxb[i] = 0u; gsum[i] = 0.0f; }
    if (i < 64) { misc[i] = (i == 1) ? NE : 0; gcnt[i] = 0.0f; }
}
__global__ void init_ht(u32* ht) {
    int i = blockIdx.x * 256 + threadIdx.x;
    if (i < HTS) ht[i] = 0xFFFFFFFFu;
}

// ---------------- per-node dots with pool_w halves (double accum) ----------------
__global__ void node_dots(const float* __restrict__ x, const float* __restrict__ pw,
                          double* a_d, double* b_d) {
    int wave = (blockIdx.x * blockDim.x + threadIdx.x) >> 6;
    int lane = threadIdx.x & 63;
    if (wave >= NN) return;
    const float* xr = x + (size_t)wave * FIN;
    double s0 = 0.0, s1 = 0.0;
    for (int f = lane; f < FIN; f += 64) {
        double xv = (double)xr[f];
        s0 += xv * (double)pw[f];
        s1 += xv * (double)pw[FIN + f];
    }
    s0 = wave_sum(s0); s1 = wave_sum(s1);
    if (lane == 0) { a_d[wave] = s0; b_d[wave] = s1; }
}

// ---------------- edge score pipeline ----------------
__global__ void edge_p1(const int* __restrict__ ei, const double* __restrict__ a_d,
                        const double* __restrict__ b_d, const float* __restrict__ pb,
                        double* e_d, u32* emax) {
    int k = blockIdx.x * 256 + threadIdx.x;
    if (k >= NE) return;
    int u = ei[k], v = ei[NE + k];
    double e = a_d[u] + b_d[v] + (double)pb[0];
    e_d[k] = e;
    atomicMax(&emax[v], enc_f((float)e));
}
__global__ void edge_p2(const int* __restrict__ ei, double* e_d,
                        const u32* __restrict__ emax, double* ssum) {
    int k = blockIdx.x * 256 + threadIdx.x;
    if (k >= NE) return;
    int v = ei[NE + k];
    float mf = dec_f(emax[v]);
    double ex = exp(e_d[k] - (double)mf);
    e_d[k] = ex;
    unsafeAtomicAdd(&ssum[v], ex);
}
// also: worklist init + round-0 min pass
__global__ void edge_p3(const int* __restrict__ ei, const double* __restrict__ e_d,
                        const double* __restrict__ ssum, float* score, u64* key,
                        int* sel, int* act0, u64* best) {
    int k = blockIdx.x * 256 + threadIdx.x;
    if (k >= NE) return;
    int u = ei[k], v = ei[NE + k];
    float sc = (float)(e_d[k] / ssum[v] + 0.5);
    score[k] = sc;
    u32 m = enc_f(sc);
    u64 kk = ((u64)(m ^ 0xFFFFFFFFu) << 32) | (u32)k;  // low = high score, tie: low idx
    key[k] = kk;
    sel[k] = 0;
    act0[k] = k;
    atomicMin(&best[u], kk);
    atomicMin(&best[v], kk);
}

// ---------------- flattened dominant-edge peeling rounds ----------------
__global__ void mk_sel(const u64* __restrict__ key, const int* __restrict__ ei,
                       const int* __restrict__ act, const int* __restrict__ cntp,
                       int* ncntp, const u64* __restrict__ best,
                       u32* used, int* sel) {
    int cnt = cntp[0];
    int stride = gridDim.x * blockDim.x;
    int gid = blockIdx.x * blockDim.x + threadIdx.x;
    if (gid == 0) ncntp[0] = 0;
    for (int i = gid; i < cnt; i += stride) {
        int e = act[i];
        u64 k = key[e];
        int a = ei[e], b = ei[NE + e];
        if (best[a] == k && best[b] == k) { sel[e] = 1; used[a] = 1u; used[b] = 1u; }
    }
}
__global__ void mk_compact(const int* __restrict__ ei, const int* __restrict__ act,
                           const int* __restrict__ cntp, int* nxt, int* ncntp,
                           u64* best, const u32* __restrict__ used) {
    int cnt = cntp[0];
    int stride = gridDim.x * blockDim.x;
    for (int i = blockIdx.x * blockDim.x + threadIdx.x; i < cnt; i += stride) {
        int e = act[i];
        int a = ei[e], b = ei[NE + e];
        best[a] = ~0ull; best[b] = ~0ull;
        bool live = !(used[a] | used[b]);
        u64 mask = __ballot(live);
        if (mask) {
            int lane = threadIdx.x & 63;
            int leader = __ffsll((unsigned long long)mask) - 1;
            int base = 0;
            if (lane == leader) base = atomicAdd(ncntp, __popcll(mask));
            base = __shfl(base, leader, 64);
            if (live) nxt[base + __popcll(mask & ((1ull << lane) - 1ull))] = e;
        }
    }
}
__global__ void mk_min(const u64* __restrict__ key, const int* __restrict__ ei,
                       const int* __restrict__ act, const int* __restrict__ cntp,
                       u64* best) {
    int cnt = cntp[0];
    int stride = gridDim.x * blockDim.x;
    for (int i = blockIdx.x * blockDim.x + threadIdx.x; i < cnt; i += stride) {
        int e = act[i];
        u64 k = key[e];
        atomicMin(&best[ei[e]], k);
        atomicMin(&best[ei[NE + e]], k);
    }
}
// single-block finisher for the tiny tail (loops to completion)
__global__ void __launch_bounds__(1024) match_fin(
        const u64* __restrict__ key, const int* __restrict__ ei,
        int* sel, u64* best, u32* used,
        int* listA, int* listB, const int* __restrict__ cntp) {
    int tid = threadIdx.x;
    int cnt = cntp[0];
    int* cur = listA; int* nxt = listB;
    __shared__ int s_n;
    for (int round = 0; round < 4096 && cnt > 0; ++round) {
        for (int i = tid; i < cnt; i += 1024) {
            int e = cur[i]; u64 k = key[e];
            atomicMin(&best[ei[e]], k);
            atomicMin(&best[ei[NE + e]], k);
        }
        __syncthreads();
        for (int i = tid; i < cnt; i += 1024) {
            int e = cur[i]; u64 k = key[e];
            int a = ei[e], b = ei[NE + e];
            if (best[a] == k && best[b] == k) { sel[e] = 1; used[a] = 1u; used[b] = 1u; }
        }
        if (tid == 0) s_n = 0;
        __syncthreads();
        for (int i = tid; i < cnt; i += 1024) {
            int e = cur[i];
            int a = ei[e], b = ei[NE + e];
            best[a] = ~0ull; best[b] = ~0ull;
            if (!(used[a] | used[b])) {
                int idx = atomicAdd(&s_n, 1);
                nxt[idx] = e;
            }
        }
        __syncthreads();
        cnt = s_n;
        int* t = cur; cur = nxt; nxt = t;
        __syncthreads();
    }
}

__global__ void cluster_init(int* cluster, int* other, float* nscore, u32* cin) {
    int n = blockIdx.x * 256 + threadIdx.x;
    if (n >= NN) return;
    cluster[n] = n; other[n] = -1; nscore[n] = 1.0f; cin[n] = 0u;
}
__global__ void apply_sel(const int* __restrict__ ei, const int* __restrict__ sel,
                          const float* __restrict__ score,
                          int* cluster, int* other, float* nscore) {
    int e = blockIdx.x * 256 + threadIdx.x;
    if (e >= NE) return;
    if (sel[e] != 1) return;
    int u = ei[e], v = ei[NE + e];
    int rep = min(u, v);
    cluster[u] = rep; cluster[v] = rep;
    if (u != v) other[rep] = u + v - rep;
    nscore[rep] = score[e];
}

// ---------------- coarse graph: dedup (cu,cv) pairs via hash set ----------------
__global__ void coarse_build(const int* __restrict__ ei, const int* __restrict__ cluster,
                             u32* ht, int* misc, int* ce_u, int* ce_v, u32* deg,
                             u32* cin) {
    int e = blockIdx.x * 256 + threadIdx.x;
    if (e >= NE) return;
    int cu = cluster[ei[e]], cv = cluster[ei[NE + e]];
    if (cu == cv) return;
    u32 k = (u32)cu * 32768u + (u32)cv;
    u32 h = ((k * 2654435761u) >> 12) & HTM;
    while (true) {
        u32 old = atomicCAS(&ht[h], 0xFFFFFFFFu, k);
        if (old == 0xFFFFFFFFu) {
            int idx = atomicAdd(&misc[0], 1);
            ce_u[idx] = cu; ce_v[idx] = cv;
            atomicAdd(&deg[cu], 1u);
            atomicAdd(&cin[cv], 1u);
            break;
        }
        if (old == k) break;
        h = (h + 1) & HTM;
    }
}
__global__ void dis_kernel(const u32* __restrict__ deg, float* dis) {
    int n = blockIdx.x * 256 + threadIdx.x;
    if (n >= NN) return;
    u32 d = deg[n];
    dis[n] = d ? (float)(1.0 / sqrt((double)d)) : 0.0f;
}

// ---------------- CSR build: exclusive scan of cin -> off, cur ----------------
__global__ void __launch_bounds__(1024) scan_kernel(const u32* __restrict__ cin,
                                                    int* off, int* cur) {
    __shared__ int part[1024];
    int t = threadIdx.x;
    int base = t << 5;      // 32 elements per thread
    int loc[32];
    int s = 0;
    #pragma unroll
    for (int i = 0; i < 32; ++i) { loc[i] = s; s += (int)cin[base + i]; }
    part[t] = s;
    __syncthreads();
    for (int d = 1; d < 1024; d <<= 1) {
        int v = (t >= d) ? part[t - d] : 0;
        __syncthreads();
        if (t >= d) part[t] += v;
        __syncthreads();
    }
    int pre = (t == 0) ? 0 : part[t - 1];
    #pragma unroll
    for (int i = 0; i < 32; ++i) {
        int v = pre + loc[i];
        off[base + i] = v;
        cur[base + i] = v;
    }
}
__global__ void csr_scatter(const int* __restrict__ ce_u, const int* __restrict__ ce_v,
                            const float* __restrict__ dis, const int* __restrict__ misc,
                            int* cur, int* csr_a, float* csr_c) {
    int e = blockIdx.x * 256 + threadIdx.x;
    if (e >= misc[0]) return;
    int a = ce_u[e], b = ce_v[e];
    int pos = atomicAdd(&cur[b], 1);
    csr_a[pos] = a;
    csr_c[pos] = -dis[a] * dis[b];
}

// ---------------- pre-gather px -> bf16 Ax[NN][1024], pxlast[NN] fp32 (col 1024) ----------------
__global__ void conv_a1(const float* __restrict__ x, const int* __restrict__ clus,
                        const int* __restrict__ other, const float* __restrict__ nsc,
                        unsigned short* __restrict__ Abf, float* __restrict__ pxl) {
    int r = blockIdx.x;
    int t = threadIdx.x;
    bool valid = (clus[r] == r);
    int o = other[r];
    float s = nsc[r];
    const float* xr = x + (size_t)r * FIN;
    const float* xo = x + (size_t)(o >= 0 ? o : r) * FIN;
    int c0 = t << 2;
    unsigned short h[4];
    #pragma unroll
    for (int j = 0; j < 4; ++j) {
        float v = 0.0f;
        if (valid) {
            v = xr[c0 + j];
            if (o >= 0) v += xo[c0 + j];
            v *= s;
        }
        h[j] = f2bf(v);
    }
    *(us4*)&Abf[(size_t)r * 1024 + c0] = *(const us4*)h;
    if (t == 0) {
        float v = 0.0f;
        if (valid) { v = xr[1024]; if (o >= 0) v += xo[1024]; v *= s; }
        pxl[r] = v;
    }
}

// ---------------- weight transpose + bf16 hi/lo split: Bt[n][KP] ----------------
__global__ void conv_b(const float* __restrict__ B0, const float* __restrict__ B1,
                       unsigned short* __restrict__ Bhi, unsigned short* __restrict__ Blo,
                       int KP) {
    int n = blockIdx.x * 256 + threadIdx.x;
    int k0 = blockIdx.y * 8;
    unsigned short h[8], l[8];
    #pragma unroll
    for (int j = 0; j < 8; ++j) {
        int k = k0 + j;
        float v = (n < 512) ? B0[(size_t)k * 512 + n] : B1[(size_t)k * 512 + (n - 512)];
        h[j] = f2bf(v);
        l[j] = f2bf(v - bf2f(h[j]));
    }
    *(us8*)&Bhi[(size_t)n * KP + k0] = *(const us8*)h;
    *(us8*)&Blo[(size_t)n * KP + k0] = *(const us8*)l;
}

// ---------------- bf16 MFMA GEMM: P[M x 1024] = A[M x KP] @ Bt^T (+ rank-1) ----------------
template <bool BF16A, bool R1>
__global__ void __launch_bounds__(256, 3) gemm_bf16(
        const unsigned short* __restrict__ Abf, const float* __restrict__ Af,
        const unsigned short* __restrict__ Bhi, const unsigned short* __restrict__ Blo,
        float* __restrict__ P, int KP,
        const float* __restrict__ pxl, const float* __restrict__ w0,
        const float* __restrict__ w1) {
    __shared__ unsigned short Ah[2][128 * 32];
    int tid = threadIdx.x;
    int bid = blockIdx.x;
    int loc = bid >> 3;
    int bn = (loc & 7) << 7;
    int bm = ((((bid & 7) << 5) | (loc >> 3))) << 7;
    int wave = tid >> 6, lane = tid & 63, quad = lane >> 4, l16 = lane & 15;
    int moff = (wave >> 1) << 6, noff = (wave & 1) << 6;
    int kq = tid & 3, rr = tid >> 2;
    f32x4 acc[4][4];
    #pragma unroll
    for (int i = 0; i < 4; ++i)
        #pragma unroll
        for (int j = 0; j < 4; ++j) acc[i][j] = (f32x4){0.f, 0.f, 0.f, 0.f};

    int KT = KP >> 5;
    const unsigned short* gA = nullptr;
    unsigned short* lA = nullptr;
    if (BF16A) {
        gA = Abf + (size_t)(bm + (wave << 4) + (lane >> 2)) * KP + ((lane & 3) << 3);
        lA = &Ah[0][0] + ((wave << 4) << 5);
        dma16(lA, gA);
        dma16(lA + (64 << 5), gA + (size_t)64 * KP);
    } else {
        #pragma unroll
        for (int p = 0; p < 2; ++p) {
            const float* g = Af + (size_t)(bm + rr + (p << 6)) * KP + (kq << 3);
            float4 t0 = *(const float4*)g, t1 = *(const float4*)(g + 4);
            unsigned short h[8] = {f2bf(t0.x), f2bf(t0.y), f2bf(t0.z), f2bf(t0.w),
                                   f2bf(t1.x), f2bf(t1.y), f2bf(t1.z), f2bf(t1.w)};
            *(us8*)&Ah[0][((rr + (p << 6)) << 5) + (kq << 3)] = *(const us8*)h;
        }
    }
    __syncthreads();

    for (int kt = 0; kt < KT; ++kt) {
        int cur = kt & 1;
        int k0 = kt << 5;
        float4 t0, t1, t2, t3;
        if (BF16A) {
            if (kt + 1 < KT) {
                unsigned short* l = &Ah[1 - cur][0] + ((wave << 4) << 5);
                const unsigned short* g = gA + ((kt + 1) << 5);
                dma16(l, g);
                dma16(l + (64 << 5), g + (size_t)64 * KP);
            }
        } else if (kt + 1 < KT) {
            const float* g = Af + (size_t)(bm + rr) * KP + ((kt + 1) << 5) + (kq << 3);
            t0 = *(const float4*)g; t1 = *(const float4*)(g + 4);
            const float* g2 = g + (size_t)64 * KP;
            t2 = *(const float4*)g2; t3 = *(const float4*)(g2 + 4);
        }
        const unsigned short* lb = &Ah[BF16A ? cur : 0][0];
        bf16x8 af[4], bh4[4], bl4[4];
        #pragma unroll
        for (int i = 0; i < 4; ++i) {
            af[i] = ld_frag(lb + ((moff + (i << 4) + l16) << 5) + (quad << 3));
            size_t nrow = (size_t)(bn + noff + (i << 4) + l16) * KP + k0 + (quad << 3);
            bh4[i] = ld_frag(&Bhi[nrow]);
            bl4[i] = ld_frag(&Blo[nrow]);
        }
        #pragma unroll
        for (int mi = 0; mi < 4; ++mi)
            #pragma unroll
            for (int ni = 0; ni < 4; ++ni) {
                acc[mi][ni] = __builtin_amdgcn_mfma_f32_16x16x32_bf16(af[mi], bh4[ni], acc[mi][ni], 0, 0, 0);
                acc[mi][ni] = __builtin_amdgcn_mfma_f32_16x16x32_bf16(af[mi], bl4[ni], acc[mi][ni], 0, 0, 0);
            }
        __syncthreads();
        if (!BF16A && kt + 1 < KT) {
            unsigned short h[8] = {f2bf(t0.x), f2bf(t0.y), f2bf(t0.z), f2bf(t0.w),
                                   f2bf(t1.x), f2bf(t1.y), f2bf(t1.z), f2bf(t1.w)};
            *(us8*)&Ah[0][(rr << 5) + (kq << 3)] = *(const us8*)h;
            unsigned short h2[8] = {f2bf(t2.x), f2bf(t2.y), f2bf(t2.z), f2bf(t2.w),
                                    f2bf(t3.x), f2bf(t3.y), f2bf(t3.z), f2bf(t3.w)};
            *(us8*)&Ah[0][((rr + 64) << 5) + (kq << 3)] = *(const us8*)h2;
            __syncthreads();
        }
    }
    #pragma unroll
    for (int mi = 0; mi < 4; ++mi)
        #pragma unroll
        for (int ni = 0; ni < 4; ++ni) {
            int col = bn + noff + (ni << 4) + l16;
            float wl = 0.0f;
            if (R1) wl = (col < 512) ? w0[524288 + col] : w1[524288 + col - 512];
            #pragma unroll
            for (int r2 = 0; r2 < 4; ++r2) {
                int row = bm + moff + (mi << 4) + (quad << 2) + r2;
                float v = acc[mi][ni][r2];
                if (R1) v += pxl[row] * wl;
                P[(size_t)row * 1024 + col] = v;
            }
        }
}

// ---------------- fused gather + BN + ReLU: one wave per destination row ----------------
// H[b] = relu(BN(P0[b] + sum_{(a->b)} coef*P1[a] + bias))
__global__ void __launch_bounds__(256) cheb_fuse(
        const float* __restrict__ P, const int* __restrict__ off,
        const int* __restrict__ csr_a, const float* __restrict__ csr_c,
        const int* __restrict__ misc, const float* __restrict__ bias,
        const float* __restrict__ bn, float* __restrict__ H) {
    int b = (blockIdx.x * 256 + threadIdx.x) >> 6;
    int lane = threadIdx.x & 63;
    if (b >= NN) return;
    int s = off[b];
    int e = (b < NN - 1) ? off[b + 1] : misc[0];
    int c0 = lane << 3;
    float a0[4], a1[4];
    {
        float4 t0 = *(const float4*)&P[(size_t)b * 1024 + c0];
        float4 t1 = *(const float4*)&P[(size_t)b * 1024 + c0 + 4];
        a0[0] = t0.x; a0[1] = t0.y; a0[2] = t0.z; a0[3] = t0.w;
        a1[0] = t1.x; a1[1] = t1.y; a1[2] = t1.z; a1[3] = t1.w;
    }
    for (int j = s; j < e; ++j) {
        int a = csr_a[j];
        float cf = csr_c[j];
        float4 p0 = *(const float4*)&P[(size_t)a * 1024 + 512 + c0];
        float4 p1 = *(const float4*)&P[(size_t)a * 1024 + 512 + c0 + 4];
        a0[0] = fmaf(cf, p0.x, a0[0]); a0[1] = fmaf(cf, p0.y, a0[1]);
        a0[2] = fmaf(cf, p0.z, a0[2]); a0[3] = fmaf(cf, p0.w, a0[3]);
        a1[0] = fmaf(cf, p1.x, a1[0]); a1[1] = fmaf(cf, p1.y, a1[1]);
        a1[2] = fmaf(cf, p1.z, a1[2]); a1[3] = fmaf(cf, p1.w, a1[3]);
    }
    float o[8];
    #pragma unroll
    for (int i = 0; i < 8; ++i) {
        int j = c0 + i;
        float acc = (i < 4) ? a0[i] : a1[i - 4];
        float ga = bn[j], be = bn[512 + j], mn = bn[1024 + j], vr = bn[1536 + j];
        float sc = (float)(1.0 / sqrt((double)vr + 1e-5));
        float v = (acc + bias[j] - mn) * sc * ga + be;
        o[i] = v > 0.0f ? v : 0.0f;
    }
    *(float4*)&H[(size_t)b * 512 + c0] = make_float4(o[0], o[1], o[2], o[3]);
    *(float4*)&H[(size_t)b * 512 + c0 + 4] = make_float4(o[4], o[5], o[6], o[7]);
}

// ---------------- global max+mean pool over valid nodes per graph ----------------
__global__ void __launch_bounds__(256) pool_kernel(
        const float* __restrict__ H, const int* __restrict__ cluster,
        const int* __restrict__ batch, u32* gmaxb, float* gsum, float* gcnt) {
    int t = threadIdx.x;
    int n0 = blockIdx.x * 64;
    float m0 = 0.0f, m1 = 0.0f, s0 = 0.0f, s1 = 0.0f;
    int cntl = 0;
    int cur = batch[n0];
    for (int i = 0; i < 64; ++i) {
        int n = n0 + i;
        int bt = batch[n];
        if (bt != cur) {
            atomicMax(&gmaxb[cur * 512 + t], __float_as_uint(m0));
            atomicMax(&gmaxb[cur * 512 + t + 256], __float_as_uint(m1));
            unsafeAtomicAdd(&gsum[cur * 512 + t], s0);
            unsafeAtomicAdd(&gsum[cur * 512 + t + 256], s1);
            if (t == 0) unsafeAtomicAdd(&gcnt[cur], (float)cntl);
            m0 = m1 = s0 = s1 = 0.0f; cntl = 0; cur = bt;
        }
        if (cluster[n] == n) {
            float h0 = H[(size_t)n * 512 + t];
            float h1 = H[(size_t)n * 512 + t + 256];
            m0 = fmaxf(m0, h0); m1 = fmaxf(m1, h1);
            s0 += h0; s1 += h1;
            ++cntl;
        }
    }
    atomicMax(&gmaxb[cur * 512 + t], __float_as_uint(m0));
    atomicMax(&gmaxb[cur * 512 + t + 256], __float_as_uint(m1));
    unsafeAtomicAdd(&gsum[cur * 512 + t], s0);
    unsafeAtomicAdd(&gsum[cur * 512 + t + 256], s1);
    if (t == 0) unsafeAtomicAdd(&gcnt[cur], (float)cntl);
}

// ---------------- readout MLP + log_softmax (tiny, one block) ----------------
__global__ void __launch_bounds__(512) readout(
        const u32* __restrict__ gmaxb, const float* __restrict__ gsum,
        const float* __restrict__ gcnt,
        const float* __restrict__ l1w, const float* __restrict__ l1b,
        const float* __restrict__ bn3,
        const float* __restrict__ l2w, const float* __restrict__ l2b,
        const float* __restrict__ bn4,
        const float* __restrict__ l3w, const float* __restrict__ l3b,
        float* __restrict__ out) {
    __shared__ float G[8 * 1024];
    __shared__ float G1[8 * 512];
    __shared__ float G2[8 * 256];
    int t = threadIdx.x;
    for (int idx = t; idx < 8192; idx += 512) {
        int b = idx >> 10, j = idx & 1023;
        float v;
        if (j < 512) v = __uint_as_float(gmaxb[b * 512 + j]);
        else v = gsum[b * 512 + (j - 512)] / fmaxf(gcnt[b], 1.0f);
        G[idx] = v;
    }
    __syncthreads();
    {
        int o = t;
        float acc[8];
        #pragma unroll
        for (int b = 0; b < 8; ++b) acc[b] = l1b[o];
        for (int k = 0; k < 1024; ++k) {
            float w = l1w[k * 512 + o];
            #pragma unroll
            for (int b = 0; b < 8; ++b) acc[b] += G[b * 1024 + k] * w;
        }
        float ga = bn3[o], be = bn3[512 + o], mn = bn3[1024 + o], vr = bn3[1536 + o];
        float sc = (float)(1.0 / sqrt((double)vr + 1e-5));
        #pragma unroll
        for (int b = 0; b < 8; ++b) {
            float v = (acc[b] - mn) * sc * ga + be;
            G1[b * 512 + o] = v > 0.0f ? v : 0.0f;
        }
    }
    __syncthreads();
    if (t < 256) {
        int o = t;
        float acc[8];
        #pragma unroll
        for (int b = 0; b < 8; ++b) acc[b] = l2b[o];
        for (int k = 0; k < 512; ++k) {
            float w = l2w[k * 256 + o];
            #pragma unroll
            for (int b = 0; b < 8; ++b) acc[b] += G1[b * 512 + k] * w;
        }
        float ga = bn4[o], be = bn4[256 + o], mn = bn4[512 + o], vr = bn4[768 + o];
        float sc = (float)(1.0 / sqrt((double)vr + 1e-5));
        #pragma unroll
        for (int b = 0; b < 8; ++b) {
            float v = (acc[b] - mn) * sc * ga + be;
            v = v > 0.0f ? v : 0.0f;
            G2[b * 256 + o] = v;
            out[32 + b * 256 + o] = v;
        }
    }
    __syncthreads();
    if (t < 8) {
        int b = t;
        float r[4];
        #pragma unroll
        for (int c = 0; c < 4; ++c) {
            float acc = l3b[c];
            for (int k = 0; k < 256; ++k) acc += G2[b * 256 + k] * l3w[k * 4 + c];
            r[c] = acc > 0.0f ? acc : 0.0f;
        }
        float mx = fmaxf(fmaxf(r[0], r[1]), fmaxf(r[2], r[3]));
        float s = 0.0f;
        #pragma unroll
        for (int c = 0; c < 4; ++c) s += expf(r[c] - mx);
        float lse = mx + logf(s);
        #pragma unroll
        for (int c = 0; c < 4; ++c) out[b * 4 + c] = r[c] - lse;
    }
}

extern "C" void kernel_launch(void* const* d_in, const int* in_sizes, int n_in,
                              void* d_out, int out_size, void* d_ws, size_t ws_size,
                              hipStream_t stream) {
    const float* x      = (const float*)d_in[0];
    const int*   ei     = (const int*)d_in[1];
    const int*   batch  = (const int*)d_in[2];
    const float* pool_w = (const float*)d_in[3];
    const float* pool_b = (const float*)d_in[4];
    const float* c1_w0  = (const float*)d_in[5];
    const float* c1_w1  = (const float*)d_in[6];
    const float* c1_b   = (const float*)d_in[7];
    const float* c2_w0  = (const float*)d_in[8];
    const float* c2_w1  = (const float*)d_in[9];
    const float* c2_b   = (const float*)d_in[10];
    const float* bn1    = (const float*)d_in[11];
    const float* bn2    = (const float*)d_in[12];
    const float* bn3    = (const float*)d_in[13];
    const float* bn4    = (const float*)d_in[14];
    const float* l1w    = (const float*)d_in[15];
    const float* l1b    = (const float*)d_in[16];
    const float* l2w    = (const float*)d_in[17];
    const float* l2b    = (const float*)d_in[18];
    const float* l3w    = (const float*)d_in[19];
    const float* l3b    = (const float*)d_in[20];
    float* out = (float*)d_out;
    char* ws = (char*)d_ws;

    double* a_d   = (double*)(ws + WS_A_D);
    double* b_d   = (double*)(ws + WS_B_D);
    u32*    emax  = (u32*)(ws + WS_EMAX);
    double* ssum  = (double*)(ws + WS_SSUM);
    double* exd   = (double*)(ws + WS_EXD);
    u32*    cin   = (u32*)(ws + WS_CIN);
    u64*    key   = (u64*)(ws + WS_KEY);
    u64*    best  = (u64*)(ws + WS_BEST);
    u32*    used  = (u32*)(ws + WS_USED);
    int*    curp  = (int*)(ws + WS_CUR);
    int*    act0  = (int*)(ws + WS_ACT0);
    int*    act1  = (int*)(ws + WS_ACT1);
    unsigned short* bthi = (unsigned short*)(ws + WS_BTHI);
    unsigned short* btlo = (unsigned short*)(ws + WS_BTLO);
    float*  pxl   = (float*)(ws + WS_PXL);
    u32*    ht    = (u32*)(ws + WS_HT);
    float*  score = (float*)(ws + WS_SCORE);
    int*    csr_a = (int*)(ws + WS_CSRA);
    int*    sel   = (int*)(ws + WS_SEL);
    float*  csr_c = (float*)(ws + WS_CSRC);
    int*    clus  = (int*)(ws + WS_CLUST);
    int*    other = (int*)(ws + WS_OTHER);
    float*  nsc   = (float*)(ws + WS_NSC);
    int*    ce_u  = (int*)(ws + WS_CEU);
    int*    ce_v  = (int*)(ws + WS_CEV);
    u32*    deg   = (u32*)(ws + WS_DEG);
    int*    off   = (int*)(ws + WS_OFF);
    float*  dis   = (float*)(ws + WS_DIS);
    int*    misc  = (int*)(ws + WS_MISC);
    u32*    gmaxb = (u32*)(ws + WS_GMAX);
    float*  gsum  = (float*)(ws + WS_GSUM);
    float*  gcnt  = (float*)(ws + WS_GCNT);
    float*  P     = (float*)(ws + WS_P);
    unsigned short* ax = (unsigned short*)(ws + WS_H);
    float*  H     = (float*)(ws + WS_H);

    // ---- phase A: scores, matching, coarse graph ----
    init_misc<<<NN / 256, 256, 0, stream>>>(emax, ssum, deg, misc, gmaxb, gsum, gcnt,
                                            best, used);
    node_dots<<<NN / 4, 256, 0, stream>>>(x, pool_w, a_d, b_d);
    edge_p1<<<NE / 256, 256, 0, stream>>>(ei, a_d, b_d, pool_b, exd, emax);
    edge_p2<<<NE / 256, 256, 0, stream>>>(ei, exd, emax, ssum);
    edge_p3<<<NE / 256, 256, 0, stream>>>(ei, exd, ssum, score, key, sel, act0, best);

    {
        static const int gr[13] = {512, 512, 256, 128, 64, 32, 16, 8, 8, 4, 4, 4, 4};
        int* acts[2] = {act0, act1};
        for (int r = 0; r < 12; ++r) {
            int c = r & 1, n = 1 - c;
            mk_sel<<<gr[r], 256, 0, stream>>>(key, ei, acts[c], &misc[1 + c],
                                              &misc[1 + n], best, used, sel);
            mk_compact<<<gr[r], 256, 0, stream>>>(ei, acts[c], &misc[1 + c],
                                                  acts[n], &misc[1 + n], best, used);
            mk_min<<<gr[r + 1], 256, 0, stream>>>(key, ei, acts[n], &misc[1 + n], best);
        }
        match_fin<<<1, 1024, 0, stream>>>(key, ei, sel, best, used,
                                          act0, act1, &misc[1]);
    }

    cluster_init<<<NN / 256, 256, 0, stream>>>(clus, other, nsc, cin);
    apply_sel<<<NE / 256, 256, 0, stream>>>(ei, sel, score, clus, other, nsc);
    init_ht<<<HTS / 256, 256, 0, stream>>>(ht);
    coarse_build<<<NE / 256, 256, 0, stream>>>(ei, clus, ht, misc, ce_u, ce_v, deg, cin);
    dis_kernel<<<NN / 256, 256, 0, stream>>>(deg, dis);
    scan_kernel<<<1, 1024, 0, stream>>>(cin, off, curp);
    csr_scatter<<<NE / 256, 256, 0, stream>>>(ce_u, ce_v, dis, misc, curp, csr_a, csr_c);

    // ---- phase B: ChebConv layers (MFMA + fused gather/BN/ReLU), pooling, readout ----
    conv_b<<<dim3(4, 128), 256, 0, stream>>>(c1_w0, c1_w1, bthi, btlo, 1024);
    conv_a1<<<NN, 256, 0, stream>>>(x, clus, other, nsc, ax, pxl);
    gemm_bf16<true, true><<<2048, 256, 0, stream>>>(ax, nullptr, bthi, btlo, P, 1024,
                                                    pxl, c1_w0, c1_w1);
    cheb_fuse<<<NN / 4, 256, 0, stream>>>(P, off, csr_a, csr_c, misc, c1_b, bn1, H);

    conv_b<<<dim3(4, 64), 256, 0, stream>>>(c2_w0, c2_w1, bthi, btlo, 512);
    gemm_bf16<false, false><<<2048, 256, 0, stream>>>(nullptr, H, bthi, btlo, P, 512,
                                                      nullptr, nullptr, nullptr);
    cheb_fuse<<<NN / 4, 256, 0, stream>>>(P, off, csr_a, csr_c, misc, c2_b, bn2, H);

    pool_kernel<<<NN / 64, 256, 0, stream>>>(H, clus, batch, gmaxb, gsum, gcnt);
    readout<<<1, 512, 0, stream>>>(gmaxb, gsum, gcnt, l1w, l1b, bn3,
                                   l2w, l2b, bn4, l3w, l3b, out);
}

// Round 6
// 1225.291 us; speedup vs baseline: 5.4873x; 1.0603x over previous
//
#include <hip/hip_runtime.h>
#include <hip/hip_bf16.h>
#include <cstdint>
#include <cmath>

typedef unsigned int u32;
typedef unsigned long long u64;
typedef float f32x4 __attribute__((ext_vector_type(4)));
typedef __bf16 bf16x8 __attribute__((ext_vector_type(8)));
typedef unsigned short us8 __attribute__((ext_vector_type(8)));
typedef unsigned short us4 __attribute__((ext_vector_type(4)));

#define NN 32768
#define NE 131072
#define FIN 1025
#define HTS 262144
#define HTM (HTS - 1)

// ---------------- workspace layout (byte offsets) ----------------
#define WS_A_D    0ul          // double[NN]
#define WS_B_D    262144ul     // double[NN]
#define WS_EMAX   524288ul     // u32[NN]
#define WS_SSUM   655360ul     // double[NN]
#define WS_EXD    917504ul     // double[NE]
#define WS_CIN    917504ul     // u32[NN]  overlays EXD head
#define WS_KEY    1966080ul    // u64[NE]
#define WS_BEST   3014656ul    // u64[NN]
#define WS_USED   3276800ul    // u32[NN]
#define WS_CUR    3276800ul    // int[NN]  overlays USED (dead after match_fin)
#define WS_ACT0   3407872ul    // int[NE]
#define WS_ACT1   3932160ul    // int[NE]   (zone ends 4456448)
#define WS_BTHI   0ul          // ushort[1024*1024] = 2097152 B  (phase B)
#define WS_PXL    4194304ul    // float[NN]                      (phase B)
#define WS_HT     1966080ul    // u32[HTS] overlays KEY
// persistent:
#define WS_SCORE  4456448ul    // float[NE]
#define WS_CSRA   4456448ul    // int[NE]  overlays SCORE (dead after apply_sel)
#define WS_SEL    4980736ul    // int[NE]
#define WS_CSRC   4980736ul    // float[NE] overlays SEL (dead after apply_sel)
#define WS_CLUST  5505024ul    // int[NN]
#define WS_OTHER  5636096ul    // int[NN]
#define WS_NSC    5767168ul    // float[NN]
#define WS_CEU    5898240ul    // int[NE]
#define WS_CEV    6422528ul    // int[NE]
#define WS_DEG    6946816ul    // u32[NN]
#define WS_OFF    6946816ul    // int[NN]  overlays DEG
#define WS_DIS    7077888ul    // float[NN]
#define WS_MISC   7208960ul    // int[64]
#define WS_GMAX   7209216ul    // u32[8*512]
#define WS_GSUM   7225600ul    // float[8*512]
#define WS_GCNT   7241984ul    // float[64]
#define WS_P      7242240ul    // float[NN*1024]
#define WS_H      141459968ul  // Ax bf16[NN*1024] -> Hb bf16[NN*512] -> H f32[NN*512]

__device__ __forceinline__ u32 enc_f(float f) {
    u32 b = __float_as_uint(f);
    return (b & 0x80000000u) ? ~b : (b | 0x80000000u);
}
__device__ __forceinline__ float dec_f(u32 m) {
    return (m & 0x80000000u) ? __uint_as_float(m ^ 0x80000000u) : __uint_as_float(~m);
}
__device__ __forceinline__ double wave_sum(double v) {
    #pragma unroll
    for (int off = 32; off > 0; off >>= 1) v += __shfl_down(v, off, 64);
    return v;
}
__device__ __forceinline__ unsigned short f2bf(float v) {   // RNE f32->bf16
    u32 b = __float_as_uint(v);
    u32 r = b + 0x7FFFu + ((b >> 16) & 1u);
    return (unsigned short)(r >> 16);
}
__device__ __forceinline__ bf16x8 ld_frag(const unsigned short* p) {
    union { us8 u; bf16x8 b; } t;
    t.u = *(const us8*)p;
    return t.b;
}

// ---------------- init ----------------
__global__ void init_misc(u32* emax, double* ssum, u32* deg,
                          int* misc, u32* gmaxb, float* gsum, float* gcnt,
                          u64* best, u32* used) {
    int i = blockIdx.x * 256 + threadIdx.x;
    if (i < NN) { emax[i] = 0u; ssum[i] = 0.0; deg[i] = 0u; best[i] = ~0ull; used[i] = 0u; }
    if (i < 4096) { gmaxb[i] = 0u; gsum[i] = 0.0f; }
    if (i < 64) { misc[i] = (i == 1) ? NE : 0; gcnt[i] = 0.0f; }
}
__global__ void init_ht(u32* ht) {
    int i = blockIdx.x * 256 + threadIdx.x;
    if (i < HTS) ht[i] = 0xFFFFFFFFu;
}

// ---------------- per-node dots with pool_w halves (double accum) ----------------
__global__ void node_dots(const float* __restrict__ x, const float* __restrict__ pw,
                          double* a_d, double* b_d) {
    int wave = (blockIdx.x * blockDim.x + threadIdx.x) >> 6;
    int lane = threadIdx.x & 63;
    if (wave >= NN) return;
    const float* xr = x + (size_t)wave * FIN;
    double s0 = 0.0, s1 = 0.0;
    for (int f = lane; f < FIN; f += 64) {
        double xv = (double)xr[f];
        s0 += xv * (double)pw[f];
        s1 += xv * (double)pw[FIN + f];
    }
    s0 = wave_sum(s0); s1 = wave_sum(s1);
    if (lane == 0) { a_d[wave] = s0; b_d[wave] = s1; }
}

// ---------------- edge score pipeline ----------------
__global__ void edge_p1(const int* __restrict__ ei, const double* __restrict__ a_d,
                        const double* __restrict__ b_d, const float* __restrict__ pb,
                        double* e_d, u32* emax) {
    int k = blockIdx.x * 256 + threadIdx.x;
    if (k >= NE) return;
    int u = ei[k], v = ei[NE + k];
    double e = a_d[u] + b_d[v] + (double)pb[0];
    e_d[k] = e;
    atomicMax(&emax[v], enc_f((float)e));
}
__global__ void edge_p2(const int* __restrict__ ei, double* e_d,
                        const u32* __restrict__ emax, double* ssum) {
    int k = blockIdx.x * 256 + threadIdx.x;
    if (k >= NE) return;
    int v = ei[NE + k];
    float mf = dec_f(emax[v]);
    double ex = exp(e_d[k] - (double)mf);
    e_d[k] = ex;
    unsafeAtomicAdd(&ssum[v], ex);
}
__global__ void edge_p3(const int* __restrict__ ei, const double* __restrict__ e_d,
                        const double* __restrict__ ssum, float* score, u64* key,
                        int* sel, int* act0, u64* best) {
    int k = blockIdx.x * 256 + threadIdx.x;
    if (k >= NE) return;
    int u = ei[k], v = ei[NE + k];
    float sc = (float)(e_d[k] / ssum[v] + 0.5);
    score[k] = sc;
    u32 m = enc_f(sc);
    u64 kk = ((u64)(m ^ 0xFFFFFFFFu) << 32) | (u32)k;  // low = high score, tie: low idx
    key[k] = kk;
    sel[k] = 0;
    act0[k] = k;
    atomicMin(&best[u], kk);
    atomicMin(&best[v], kk);
}

// ---------------- flattened dominant-edge peeling rounds ----------------
__global__ void mk_sel(const u64* __restrict__ key, const int* __restrict__ ei,
                       const int* __restrict__ act, const int* __restrict__ cntp,
                       int* ncntp, const u64* __restrict__ best,
                       u32* used, int* sel) {
    int cnt = cntp[0];
    int stride = gridDim.x * blockDim.x;
    int gid = blockIdx.x * blockDim.x + threadIdx.x;
    if (gid == 0) ncntp[0] = 0;
    for (int i = gid; i < cnt; i += stride) {
        int e = act[i];
        u64 k = key[e];
        int a = ei[e], b = ei[NE + e];
        if (best[a] == k && best[b] == k) { sel[e] = 1; used[a] = 1u; used[b] = 1u; }
    }
}
__global__ void mk_compact(const int* __restrict__ ei, const int* __restrict__ act,
                           const int* __restrict__ cntp, int* nxt, int* ncntp,
                           u64* best, const u32* __restrict__ used) {
    int cnt = cntp[0];
    int stride = gridDim.x * blockDim.x;
    for (int i = blockIdx.x * blockDim.x + threadIdx.x; i < cnt; i += stride) {
        int e = act[i];
        int a = ei[e], b = ei[NE + e];
        best[a] = ~0ull; best[b] = ~0ull;
        bool live = !(used[a] | used[b]);
        u64 mask = __ballot(live);
        if (mask) {
            int lane = threadIdx.x & 63;
            int leader = __ffsll((unsigned long long)mask) - 1;
            int base = 0;
            if (lane == leader) base = atomicAdd(ncntp, __popcll(mask));
            base = __shfl(base, leader, 64);
            if (live) nxt[base + __popcll(mask & ((1ull << lane) - 1ull))] = e;
        }
    }
}
__global__ void mk_min(const u64* __restrict__ key, const int* __restrict__ ei,
                       const int* __restrict__ act, const int* __restrict__ cntp,
                       u64* best) {
    int cnt = cntp[0];
    int stride = gridDim.x * blockDim.x;
    for (int i = blockIdx.x * blockDim.x + threadIdx.x; i < cnt; i += stride) {
        int e = act[i];
        u64 k = key[e];
        atomicMin(&best[ei[e]], k);
        atomicMin(&best[ei[NE + e]], k);
    }
}
__global__ void __launch_bounds__(1024) match_fin(
        const u64* __restrict__ key, const int* __restrict__ ei,
        int* sel, u64* best, u32* used,
        int* listA, int* listB, const int* __restrict__ cntp) {
    int tid = threadIdx.x;
    int cnt = cntp[0];
    int* cur = listA; int* nxt = listB;
    __shared__ int s_n;
    for (int round = 0; round < 4096 && cnt > 0; ++round) {
        for (int i = tid; i < cnt; i += 1024) {
            int e = cur[i]; u64 k = key[e];
            atomicMin(&best[ei[e]], k);
            atomicMin(&best[ei[NE + e]], k);
        }
        __syncthreads();
        for (int i = tid; i < cnt; i += 1024) {
            int e = cur[i]; u64 k = key[e];
            int a = ei[e], b = ei[NE + e];
            if (best[a] == k && best[b] == k) { sel[e] = 1; used[a] = 1u; used[b] = 1u; }
        }
        if (tid == 0) s_n = 0;
        __syncthreads();
        for (int i = tid; i < cnt; i += 1024) {
            int e = cur[i];
            int a = ei[e], b = ei[NE + e];
            best[a] = ~0ull; best[b] = ~0ull;
            if (!(used[a] | used[b])) {
                int idx = atomicAdd(&s_n, 1);
                nxt[idx] = e;
            }
        }
        __syncthreads();
        cnt = s_n;
        int* t = cur; cur = nxt; nxt = t;
        __syncthreads();
    }
}

__global__ void cluster_init(int* cluster, int* other, float* nscore, u32* cin) {
    int n = blockIdx.x * 256 + threadIdx.x;
    if (n >= NN) return;
    cluster[n] = n; other[n] = -1; nscore[n] = 1.0f; cin[n] = 0u;
}
__global__ void apply_sel(const int* __restrict__ ei, const int* __restrict__ sel,
                          const float* __restrict__ score,
                          int* cluster, int* other, float* nscore) {
    int e = blockIdx.x * 256 + threadIdx.x;
    if (e >= NE) return;
    if (sel[e] != 1) return;
    int u = ei[e], v = ei[NE + e];
    int rep = min(u, v);
    cluster[u] = rep; cluster[v] = rep;
    if (u != v) other[rep] = u + v - rep;
    nscore[rep] = score[e];
}

// ---------------- coarse graph: dedup (cu,cv) pairs via hash set ----------------
__global__ void coarse_build(const int* __restrict__ ei, const int* __restrict__ cluster,
                             u32* ht, int* misc, int* ce_u, int* ce_v, u32* deg,
                             u32* cin) {
    int e = blockIdx.x * 256 + threadIdx.x;
    if (e >= NE) return;
    int cu = cluster[ei[e]], cv = cluster[ei[NE + e]];
    if (cu == cv) return;
    u32 k = (u32)cu * 32768u + (u32)cv;
    u32 h = ((k * 2654435761u) >> 12) & HTM;
    while (true) {
        u32 old = atomicCAS(&ht[h], 0xFFFFFFFFu, k);
        if (old == 0xFFFFFFFFu) {
            int idx = atomicAdd(&misc[0], 1);
            ce_u[idx] = cu; ce_v[idx] = cv;
            atomicAdd(&deg[cu], 1u);
            atomicAdd(&cin[cv], 1u);
            break;
        }
        if (old == k) break;
        h = (h + 1) & HTM;
    }
}
__global__ void dis_kernel(const u32* __restrict__ deg, float* dis) {
    int n = blockIdx.x * 256 + threadIdx.x;
    if (n >= NN) return;
    u32 d = deg[n];
    dis[n] = d ? (float)(1.0 / sqrt((double)d)) : 0.0f;
}

// ---------------- CSR build: exclusive scan of cin -> off, cur ----------------
__global__ void __launch_bounds__(1024) scan_kernel(const u32* __restrict__ cin,
                                                    int* off, int* cur) {
    __shared__ int part[1024];
    int t = threadIdx.x;
    int base = t << 5;
    int loc[32];
    int s = 0;
    #pragma unroll
    for (int i = 0; i < 32; ++i) { loc[i] = s; s += (int)cin[base + i]; }
    part[t] = s;
    __syncthreads();
    for (int d = 1; d < 1024; d <<= 1) {
        int v = (t >= d) ? part[t - d] : 0;
        __syncthreads();
        if (t >= d) part[t] += v;
        __syncthreads();
    }
    int pre = (t == 0) ? 0 : part[t - 1];
    #pragma unroll
    for (int i = 0; i < 32; ++i) {
        int v = pre + loc[i];
        off[base + i] = v;
        cur[base + i] = v;
    }
}
__global__ void csr_scatter(const int* __restrict__ ce_u, const int* __restrict__ ce_v,
                            const float* __restrict__ dis, const int* __restrict__ misc,
                            int* cur, int* csr_a, float* csr_c) {
    int e = blockIdx.x * 256 + threadIdx.x;
    if (e >= misc[0]) return;
    int a = ce_u[e], b = ce_v[e];
    int pos = atomicAdd(&cur[b], 1);
    csr_a[pos] = a;
    csr_c[pos] = -dis[a] * dis[b];
}

// ---------------- pre-gather px -> bf16 Ax[NN][1024], pxlast[NN] fp32 (col 1024) ----------------
__global__ void conv_a1(const float* __restrict__ x, const int* __restrict__ clus,
                        const int* __restrict__ other, const float* __restrict__ nsc,
                        unsigned short* __restrict__ Abf, float* __restrict__ pxl) {
    int r = blockIdx.x;
    int t = threadIdx.x;
    bool valid = (clus[r] == r);
    int o = other[r];
    float s = nsc[r];
    const float* xr = x + (size_t)r * FIN;
    const float* xo = x + (size_t)(o >= 0 ? o : r) * FIN;
    int c0 = t << 2;
    unsigned short h[4];
    #pragma unroll
    for (int j = 0; j < 4; ++j) {
        float v = 0.0f;
        if (valid) {
            v = xr[c0 + j];
            if (o >= 0) v += xo[c0 + j];
            v *= s;
        }
        h[j] = f2bf(v);
    }
    *(us4*)&Abf[(size_t)r * 1024 + c0] = *(const us4*)h;
    if (t == 0) {
        float v = 0.0f;
        if (valid) { v = xr[1024]; if (o >= 0) v += xo[1024]; v *= s; }
        pxl[r] = v;
    }
}

// ---------------- weight transpose -> bf16 Bt[n][KP] (single precision bf16) ----------------
__global__ void conv_b(const float* __restrict__ B0, const float* __restrict__ B1,
                       unsigned short* __restrict__ Bhi, int KP) {
    int n = blockIdx.x * 256 + threadIdx.x;
    int k0 = blockIdx.y * 8;
    unsigned short h[8];
    #pragma unroll
    for (int j = 0; j < 8; ++j) {
        int k = k0 + j;
        float v = (n < 512) ? B0[(size_t)k * 512 + n] : B1[(size_t)k * 512 + (n - 512)];
        h[j] = f2bf(v);
    }
    *(us8*)&Bhi[(size_t)n * KP + k0] = *(const us8*)h;
}

// ---------------- LDS-free bf16 MFMA GEMM: P[M x 1024] = A @ Bt^T (+ rank-1) ----------------
// 128x128 tile, 4 waves (each 64x64), BK=32, ping-pong register prefetch of A & B
// fragments straight from global (L2-resident). No LDS, no barriers.
template <bool R1>
__global__ void __launch_bounds__(256, 3) gemm_nolds(
        const unsigned short* __restrict__ Abf, const unsigned short* __restrict__ Bhi,
        float* __restrict__ P, int KP,
        const float* __restrict__ pxl, const float* __restrict__ w0,
        const float* __restrict__ w1) {
    int tid = threadIdx.x;
    int bid = blockIdx.x;
    // XCD swizzle: xcd = bid&7 owns m-range, n fastest within
    int loc = bid >> 3;
    int bn = (loc & 7) << 7;
    int bm = ((((bid & 7) << 5) | (loc >> 3))) << 7;
    int wave = tid >> 6, lane = tid & 63, quad = lane >> 4, l16 = lane & 15;
    int moff = (wave >> 1) << 6, noff = (wave & 1) << 6;
    f32x4 acc[4][4];
    #pragma unroll
    for (int i = 0; i < 4; ++i)
        #pragma unroll
        for (int j = 0; j < 4; ++j) acc[i][j] = (f32x4){0.f, 0.f, 0.f, 0.f};

    const unsigned short* pa[4];
    const unsigned short* pb[4];
    #pragma unroll
    for (int i = 0; i < 4; ++i) {
        pa[i] = Abf + (size_t)(bm + moff + (i << 4) + l16) * KP + (quad << 3);
        pb[i] = Bhi + (size_t)(bn + noff + (i << 4) + l16) * KP + (quad << 3);
    }
    bf16x8 a0[4], b0[4], a1[4], b1[4];
    #pragma unroll
    for (int i = 0; i < 4; ++i) { a0[i] = ld_frag(pa[i]); b0[i] = ld_frag(pb[i]); }

    int KT = KP >> 5;   // even (32 or 16)
    for (int kt = 0; kt < KT; kt += 2) {
        int off1 = (kt + 1) << 5;
        #pragma unroll
        for (int i = 0; i < 4; ++i) { a1[i] = ld_frag(pa[i] + off1); b1[i] = ld_frag(pb[i] + off1); }
        #pragma unroll
        for (int mi = 0; mi < 4; ++mi)
            #pragma unroll
            for (int ni = 0; ni < 4; ++ni)
                acc[mi][ni] = __builtin_amdgcn_mfma_f32_16x16x32_bf16(a0[mi], b0[ni], acc[mi][ni], 0, 0, 0);
        if (kt + 2 < KT) {
            int off2 = (kt + 2) << 5;
            #pragma unroll
            for (int i = 0; i < 4; ++i) { a0[i] = ld_frag(pa[i] + off2); b0[i] = ld_frag(pb[i] + off2); }
        }
        #pragma unroll
        for (int mi = 0; mi < 4; ++mi)
            #pragma unroll
            for (int ni = 0; ni < 4; ++ni)
                acc[mi][ni] = __builtin_amdgcn_mfma_f32_16x16x32_bf16(a1[mi], b1[ni], acc[mi][ni], 0, 0, 0);
    }
    // epilogue: C/D row=quad*4+r2, col=l16; optional rank-1 (column 1024 of A/B)
    #pragma unroll
    for (int mi = 0; mi < 4; ++mi)
        #pragma unroll
        for (int ni = 0; ni < 4; ++ni) {
            int col = bn + noff + (ni << 4) + l16;
            float wl = 0.0f;
            if (R1) wl = (col < 512) ? w0[524288 + col] : w1[524288 + col - 512];
            #pragma unroll
            for (int r2 = 0; r2 < 4; ++r2) {
                int row = bm + moff + (mi << 4) + (quad << 2) + r2;
                float v = acc[mi][ni][r2];
                if (R1) v += pxl[row] * wl;
                P[(size_t)row * 1024 + col] = v;
            }
        }
}

// ---------------- fused gather + BN + ReLU: one wave per destination row ----------------
// out[b] = relu(BN(P0[b] + sum_{(a->b)} coef*P1[a] + bias)); bf16 or fp32 output
template <bool BF16OUT>
__global__ void __launch_bounds__(256) cheb_fuse(
        const float* __restrict__ P, const int* __restrict__ off,
        const int* __restrict__ csr_a, const float* __restrict__ csr_c,
        const int* __restrict__ misc, const float* __restrict__ bias,
        const float* __restrict__ bn, float* __restrict__ Hf,
        unsigned short* __restrict__ Hb) {
    int b = (blockIdx.x * 256 + threadIdx.x) >> 6;
    int lane = threadIdx.x & 63;
    if (b >= NN) return;
    int s = off[b];
    int e = (b < NN - 1) ? off[b + 1] : misc[0];
    int c0 = lane << 3;
    float a0[4], a1[4];
    {
        float4 t0 = *(const float4*)&P[(size_t)b * 1024 + c0];
        float4 t1 = *(const float4*)&P[(size_t)b * 1024 + c0 + 4];
        a0[0] = t0.x; a0[1] = t0.y; a0[2] = t0.z; a0[3] = t0.w;
        a1[0] = t1.x; a1[1] = t1.y; a1[2] = t1.z; a1[3] = t1.w;
    }
    for (int j = s; j < e; ++j) {
        int a = csr_a[j];
        float cf = csr_c[j];
        float4 p0 = *(const float4*)&P[(size_t)a * 1024 + 512 + c0];
        float4 p1 = *(const float4*)&P[(size_t)a * 1024 + 512 + c0 + 4];
        a0[0] = fmaf(cf, p0.x, a0[0]); a0[1] = fmaf(cf, p0.y, a0[1]);
        a0[2] = fmaf(cf, p0.z, a0[2]); a0[3] = fmaf(cf, p0.w, a0[3]);
        a1[0] = fmaf(cf, p1.x, a1[0]); a1[1] = fmaf(cf, p1.y, a1[1]);
        a1[2] = fmaf(cf, p1.z, a1[2]); a1[3] = fmaf(cf, p1.w, a1[3]);
    }
    float o[8];
    #pragma unroll
    for (int i = 0; i < 8; ++i) {
        int j = c0 + i;
        float acc = (i < 4) ? a0[i] : a1[i - 4];
        float ga = bn[j], be = bn[512 + j], mn = bn[1024 + j], vr = bn[1536 + j];
        float sc = (float)(1.0 / sqrt((double)vr + 1e-5));
        float v = (acc + bias[j] - mn) * sc * ga + be;
        o[i] = v > 0.0f ? v : 0.0f;
    }
    if (BF16OUT) {
        unsigned short h[8];
        #pragma unroll
        for (int i = 0; i < 8; ++i) h[i] = f2bf(o[i]);
        *(us8*)&Hb[(size_t)b * 512 + c0] = *(const us8*)h;
    } else {
        *(float4*)&Hf[(size_t)b * 512 + c0] = make_float4(o[0], o[1], o[2], o[3]);
        *(float4*)&Hf[(size_t)b * 512 + c0 + 4] = make_float4(o[4], o[5], o[6], o[7]);
    }
}

// ---------------- global max+mean pool over valid nodes per graph ----------------
__global__ void __launch_bounds__(256) pool_kernel(
        const float* __restrict__ H, const int* __restrict__ cluster,
        const int* __restrict__ batch, u32* gmaxb, float* gsum, float* gcnt) {
    int t = threadIdx.x;
    int n0 = blockIdx.x * 64;
    float m0 = 0.0f, m1 = 0.0f, s0 = 0.0f, s1 = 0.0f;
    int cntl = 0;
    int cur = batch[n0];
    for (int i = 0; i < 64; ++i) {
        int n = n0 + i;
        int bt = batch[n];
        if (bt != cur) {
            atomicMax(&gmaxb[cur * 512 + t], __float_as_uint(m0));
            atomicMax(&gmaxb[cur * 512 + t + 256], __float_as_uint(m1));
            unsafeAtomicAdd(&gsum[cur * 512 + t], s0);
            unsafeAtomicAdd(&gsum[cur * 512 + t + 256], s1);
            if (t == 0) unsafeAtomicAdd(&gcnt[cur], (float)cntl);
            m0 = m1 = s0 = s1 = 0.0f; cntl = 0; cur = bt;
        }
        if (cluster[n] == n) {
            float h0 = H[(size_t)n * 512 + t];
            float h1 = H[(size_t)n * 512 + t + 256];
            m0 = fmaxf(m0, h0); m1 = fmaxf(m1, h1);
            s0 += h0; s1 += h1;
            ++cntl;
        }
    }
    atomicMax(&gmaxb[cur * 512 + t], __float_as_uint(m0));
    atomicMax(&gmaxb[cur * 512 + t + 256], __float_as_uint(m1));
    unsafeAtomicAdd(&gsum[cur * 512 + t], s0);
    unsafeAtomicAdd(&gsum[cur * 512 + t + 256], s1);
    if (t == 0) unsafeAtomicAdd(&gcnt[cur], (float)cntl);
}

// ---------------- readout MLP + log_softmax (tiny, one block) ----------------
__global__ void __launch_bounds__(512) readout(
        const u32* __restrict__ gmaxb, const float* __restrict__ gsum,
        const float* __restrict__ gcnt,
        const float* __restrict__ l1w, const float* __restrict__ l1b,
        const float* __restrict__ bn3,
        const float* __restrict__ l2w, const float* __restrict__ l2b,
        const float* __restrict__ bn4,
        const float* __restrict__ l3w, const float* __restrict__ l3b,
        float* __restrict__ out) {
    __shared__ float G[8 * 1024];
    __shared__ float G1[8 * 512];
    __shared__ float G2[8 * 256];
    int t = threadIdx.x;
    for (int idx = t; idx < 8192; idx += 512) {
        int b = idx >> 10, j = idx & 1023;
        float v;
        if (j < 512) v = __uint_as_float(gmaxb[b * 512 + j]);
        else v = gsum[b * 512 + (j - 512)] / fmaxf(gcnt[b], 1.0f);
        G[idx] = v;
    }
    __syncthreads();
    {
        int o = t;
        float acc[8];
        #pragma unroll
        for (int b = 0; b < 8; ++b) acc[b] = l1b[o];
        for (int k = 0; k < 1024; ++k) {
            float w = l1w[k * 512 + o];
            #pragma unroll
            for (int b = 0; b < 8; ++b) acc[b] += G[b * 1024 + k] * w;
        }
        float ga = bn3[o], be = bn3[512 + o], mn = bn3[1024 + o], vr = bn3[1536 + o];
        float sc = (float)(1.0 / sqrt((double)vr + 1e-5));
        #pragma unroll
        for (int b = 0; b < 8; ++b) {
            float v = (acc[b] - mn) * sc * ga + be;
            G1[b * 512 + o] = v > 0.0f ? v : 0.0f;
        }
    }
    __syncthreads();
    if (t < 256) {
        int o = t;
        float acc[8];
        #pragma unroll
        for (int b = 0; b < 8; ++b) acc[b] = l2b[o];
        for (int k = 0; k < 512; ++k) {
            float w = l2w[k * 256 + o];
            #pragma unroll
            for (int b = 0; b < 8; ++b) acc[b] += G1[b * 512 + k] * w;
        }
        float ga = bn4[o], be = bn4[256 + o], mn = bn4[512 + o], vr = bn4[768 + o];
        float sc = (float)(1.0 / sqrt((double)vr + 1e-5));
        #pragma unroll
        for (int b = 0; b < 8; ++b) {
            float v = (acc[b] - mn) * sc * ga + be;
            v = v > 0.0f ? v : 0.0f;
            G2[b * 256 + o] = v;
            out[32 + b * 256 + o] = v;
        }
    }
    __syncthreads();
    if (t < 8) {
        int b = t;
        float r[4];
        #pragma unroll
        for (int c = 0; c < 4; ++c) {
            float acc = l3b[c];
            for (int k = 0; k < 256; ++k) acc += G2[b * 256 + k] * l3w[k * 4 + c];
            r[c] = acc > 0.0f ? acc : 0.0f;
        }
        float mx = fmaxf(fmaxf(r[0], r[1]), fmaxf(r[2], r[3]));
        float s = 0.0f;
        #pragma unroll
        for (int c = 0; c < 4; ++c) s += expf(r[c] - mx);
        float lse = mx + logf(s);
        #pragma unroll
        for (int c = 0; c < 4; ++c) out[b * 4 + c] = r[c] - lse;
    }
}

extern "C" void kernel_launch(void* const* d_in, const int* in_sizes, int n_in,
                              void* d_out, int out_size, void* d_ws, size_t ws_size,
                              hipStream_t stream) {
    const float* x      = (const float*)d_in[0];
    const int*   ei     = (const int*)d_in[1];
    const int*   batch  = (const int*)d_in[2];
    const float* pool_w = (const float*)d_in[3];
    const float* pool_b = (const float*)d_in[4];
    const float* c1_w0  = (const float*)d_in[5];
    const float* c1_w1  = (const float*)d_in[6];
    const float* c1_b   = (const float*)d_in[7];
    const float* c2_w0  = (const float*)d_in[8];
    const float* c2_w1  = (const float*)d_in[9];
    const float* c2_b   = (const float*)d_in[10];
    const float* bn1    = (const float*)d_in[11];
    const float* bn2    = (const float*)d_in[12];
    const float* bn3    = (const float*)d_in[13];
    const float* bn4    = (const float*)d_in[14];
    const float* l1w    = (const float*)d_in[15];
    const float* l1b    = (const float*)d_in[16];
    const float* l2w    = (const float*)d_in[17];
    const float* l2b    = (const float*)d_in[18];
    const float* l3w    = (const float*)d_in[19];
    const float* l3b    = (const float*)d_in[20];
    float* out = (float*)d_out;
    char* ws = (char*)d_ws;

    double* a_d   = (double*)(ws + WS_A_D);
    double* b_d   = (double*)(ws + WS_B_D);
    u32*    emax  = (u32*)(ws + WS_EMAX);
    double* ssum  = (double*)(ws + WS_SSUM);
    double* exd   = (double*)(ws + WS_EXD);
    u32*    cin   = (u32*)(ws + WS_CIN);
    u64*    key   = (u64*)(ws + WS_KEY);
    u64*    best  = (u64*)(ws + WS_BEST);
    u32*    used  = (u32*)(ws + WS_USED);
    int*    curp  = (int*)(ws + WS_CUR);
    int*    act0  = (int*)(ws + WS_ACT0);
    int*    act1  = (int*)(ws + WS_ACT1);
    unsigned short* bthi = (unsigned short*)(ws + WS_BTHI);
    float*  pxl   = (float*)(ws + WS_PXL);
    u32*    ht    = (u32*)(ws + WS_HT);
    float*  score = (float*)(ws + WS_SCORE);
    int*    csr_a = (int*)(ws + WS_CSRA);
    int*    sel   = (int*)(ws + WS_SEL);
    float*  csr_c = (float*)(ws + WS_CSRC);
    int*    clus  = (int*)(ws + WS_CLUST);
    int*    other = (int*)(ws + WS_OTHER);
    float*  nsc   = (float*)(ws + WS_NSC);
    int*    ce_u  = (int*)(ws + WS_CEU);
    int*    ce_v  = (int*)(ws + WS_CEV);
    u32*    deg   = (u32*)(ws + WS_DEG);
    int*    off   = (int*)(ws + WS_OFF);
    float*  dis   = (float*)(ws + WS_DIS);
    int*    misc  = (int*)(ws + WS_MISC);
    u32*    gmaxb = (u32*)(ws + WS_GMAX);
    float*  gsum  = (float*)(ws + WS_GSUM);
    float*  gcnt  = (float*)(ws + WS_GCNT);
    float*  P     = (float*)(ws + WS_P);
    unsigned short* ax = (unsigned short*)(ws + WS_H);   // Ax bf16 (gemm1 A)
    unsigned short* hb = (unsigned short*)(ws + WS_H);   // Hb bf16 (gemm2 A, overlays dead Ax)
    float*  H     = (float*)(ws + WS_H);                 // final H fp32 (overlays dead Hb)

    // ---- phase A: scores, matching, coarse graph ----
    init_misc<<<NN / 256, 256, 0, stream>>>(emax, ssum, deg, misc, gmaxb, gsum, gcnt,
                                            best, used);
    node_dots<<<NN / 4, 256, 0, stream>>>(x, pool_w, a_d, b_d);
    edge_p1<<<NE / 256, 256, 0, stream>>>(ei, a_d, b_d, pool_b, exd, emax);
    edge_p2<<<NE / 256, 256, 0, stream>>>(ei, exd, emax, ssum);
    edge_p3<<<NE / 256, 256, 0, stream>>>(ei, exd, ssum, score, key, sel, act0, best);

    {
        static const int gr[9] = {512, 512, 256, 128, 64, 32, 16, 8, 8};
        int* acts[2] = {act0, act1};
        for (int r = 0; r < 8; ++r) {
            int c = r & 1, n = 1 - c;
            mk_sel<<<gr[r], 256, 0, stream>>>(key, ei, acts[c], &misc[1 + c],
                                              &misc[1 + n], best, used, sel);
            mk_compact<<<gr[r], 256, 0, stream>>>(ei, acts[c], &misc[1 + c],
                                                  acts[n], &misc[1 + n], best, used);
            mk_min<<<gr[r + 1], 256, 0, stream>>>(key, ei, acts[n], &misc[1 + n], best);
        }
        match_fin<<<1, 1024, 0, stream>>>(key, ei, sel, best, used,
                                          act0, act1, &misc[1]);
    }

    cluster_init<<<NN / 256, 256, 0, stream>>>(clus, other, nsc, cin);
    apply_sel<<<NE / 256, 256, 0, stream>>>(ei, sel, score, clus, other, nsc);
    init_ht<<<HTS / 256, 256, 0, stream>>>(ht);
    coarse_build<<<NE / 256, 256, 0, stream>>>(ei, clus, ht, misc, ce_u, ce_v, deg, cin);
    dis_kernel<<<NN / 256, 256, 0, stream>>>(deg, dis);
    scan_kernel<<<1, 1024, 0, stream>>>(cin, off, curp);
    csr_scatter<<<NE / 256, 256, 0, stream>>>(ce_u, ce_v, dis, misc, curp, csr_a, csr_c);

    // ---- phase B: ChebConv layers (LDS-free MFMA + fused gather/BN/ReLU) ----
    conv_b<<<dim3(4, 128), 256, 0, stream>>>(c1_w0, c1_w1, bthi, 1024);
    conv_a1<<<NN, 256, 0, stream>>>(x, clus, other, nsc, ax, pxl);
    gemm_nolds<true><<<2048, 256, 0, stream>>>(ax, bthi, P, 1024, pxl, c1_w0, c1_w1);
    cheb_fuse<true><<<NN / 4, 256, 0, stream>>>(P, off, csr_a, csr_c, misc, c1_b, bn1,
                                                nullptr, hb);

    conv_b<<<dim3(4, 64), 256, 0, stream>>>(c2_w0, c2_w1, bthi, 512);
    gemm_nolds<false><<<2048, 256, 0, stream>>>(hb, bthi, P, 512, nullptr, nullptr, nullptr);
    cheb_fuse<false><<<NN / 4, 256, 0, stream>>>(P, off, csr_a, csr_c, misc, c2_b, bn2,
                                                 H, nullptr);

    pool_kernel<<<NN / 64, 256, 0, stream>>>(H, clus, batch, gmaxb, gsum, gcnt);
    readout<<<1, 512, 0, stream>>>(gmaxb, gsum, gcnt, l1w, l1b, bn3,
                                   l2w, l2b, bn4, l3w, l3b, out);
}

// Round 7
// 1071.583 us; speedup vs baseline: 6.2744x; 1.1434x over previous
//
#include <hip/hip_runtime.h>
#include <hip/hip_bf16.h>
#include <cstdint>
#include <cmath>

typedef unsigned int u32;
typedef unsigned long long u64;
typedef float f32x4 __attribute__((ext_vector_type(4)));
typedef __bf16 bf16x8 __attribute__((ext_vector_type(8)));
typedef unsigned short us8 __attribute__((ext_vector_type(8)));
typedef unsigned short us4 __attribute__((ext_vector_type(4)));

#define NN 32768
#define NE 131072
#define FIN 1025
#define HTS 262144
#define HTM (HTS - 1)

// ---------------- workspace layout (byte offsets) ----------------
#define WS_A_D    0ul          // double[NN]
#define WS_B_D    262144ul     // double[NN]
#define WS_EMAX   524288ul     // u32[NN]
#define WS_SSUM   655360ul     // double[NN]
#define WS_EXD    917504ul     // double[NE]
#define WS_CIN    917504ul     // u32[NN]  overlays EXD head
#define WS_KEY    1966080ul    // u64[NE]
#define WS_BEST   3014656ul    // u64[NN]
#define WS_USED   3276800ul    // u32[NN]
#define WS_CUR    3276800ul    // int[NN]  overlays USED (dead after match_fin)
#define WS_ACT0   3407872ul    // int[NE]
#define WS_ACT1   3932160ul    // int[NE]   (zone ends 4456448)
#define WS_BTHI   0ul          // ushort[1024*1024] packed frag order (phase B)
#define WS_PXL    4194304ul    // float[NN]                            (phase B)
#define WS_HT     1966080ul    // u32[HTS] overlays KEY
// persistent:
#define WS_SCORE  4456448ul    // float[NE]
#define WS_CSRA   4456448ul    // int[NE]  overlays SCORE (dead after apply_sel)
#define WS_SEL    4980736ul    // int[NE]
#define WS_CSRC   4980736ul    // float[NE] overlays SEL (dead after apply_sel)
#define WS_CLUST  5505024ul    // int[NN]
#define WS_OTHER  5636096ul    // int[NN]
#define WS_NSC    5767168ul    // float[NN]
#define WS_CEU    5898240ul    // int[NE]
#define WS_CEV    6422528ul    // int[NE]
#define WS_DEG    6946816ul    // u32[NN]
#define WS_OFF    6946816ul    // int[NN]  overlays DEG
#define WS_DIS    7077888ul    // float[NN]
#define WS_MISC   7208960ul    // int[64]
#define WS_GMAX   7209216ul    // u32[8*512]
#define WS_GSUM   7225600ul    // float[8*512]
#define WS_GCNT   7241984ul    // float[64]
#define WS_P      7242240ul    // float[NN*1024]
#define WS_H      141459968ul  // Ax/Hb bf16 packed -> H f32[NN*512]

__device__ __forceinline__ u32 enc_f(float f) {
    u32 b = __float_as_uint(f);
    return (b & 0x80000000u) ? ~b : (b | 0x80000000u);
}
__device__ __forceinline__ float dec_f(u32 m) {
    return (m & 0x80000000u) ? __uint_as_float(m ^ 0x80000000u) : __uint_as_float(~m);
}
__device__ __forceinline__ double wave_sum(double v) {
    #pragma unroll
    for (int off = 32; off > 0; off >>= 1) v += __shfl_down(v, off, 64);
    return v;
}
__device__ __forceinline__ unsigned short f2bf(float v) {   // RNE f32->bf16
    u32 b = __float_as_uint(v);
    u32 r = b + 0x7FFFu + ((b >> 16) & 1u);
    return (unsigned short)(r >> 16);
}
__device__ __forceinline__ bf16x8 ld_frag(const unsigned short* p) {
    union { us8 u; bf16x8 b; } t;
    t.u = *(const us8*)p;
    return t.b;
}

// ---------------- init ----------------
__global__ void init_misc(u32* emax, double* ssum, u32* deg,
                          int* misc, u32* gmaxb, float* gsum, float* gcnt,
                          u64* best, u32* used) {
    int i = blockIdx.x * 256 + threadIdx.x;
    if (i < NN) { emax[i] = 0u; ssum[i] = 0.0; deg[i] = 0u; best[i] = ~0ull; used[i] = 0u; }
    if (i < 4096) { gmaxb[i] = 0u; gsum[i] = 0.0f; }
    if (i < 64) { misc[i] = (i == 1) ? NE : 0; gcnt[i] = 0.0f; }
}
__global__ void init_ht(u32* ht) {
    int i = blockIdx.x * 256 + threadIdx.x;
    if (i < HTS) ht[i] = 0xFFFFFFFFu;
}

// ---------------- per-node dots with pool_w halves (double accum) ----------------
__global__ void node_dots(const float* __restrict__ x, const float* __restrict__ pw,
                          double* a_d, double* b_d) {
    int wave = (blockIdx.x * blockDim.x + threadIdx.x) >> 6;
    int lane = threadIdx.x & 63;
    if (wave >= NN) return;
    const float* xr = x + (size_t)wave * FIN;
    double s0 = 0.0, s1 = 0.0;
    for (int f = lane; f < FIN; f += 64) {
        double xv = (double)xr[f];
        s0 += xv * (double)pw[f];
        s1 += xv * (double)pw[FIN + f];
    }
    s0 = wave_sum(s0); s1 = wave_sum(s1);
    if (lane == 0) { a_d[wave] = s0; b_d[wave] = s1; }
}

// ---------------- edge score pipeline ----------------
__global__ void edge_p1(const int* __restrict__ ei, const double* __restrict__ a_d,
                        const double* __restrict__ b_d, const float* __restrict__ pb,
                        double* e_d, u32* emax) {
    int k = blockIdx.x * 256 + threadIdx.x;
    if (k >= NE) return;
    int u = ei[k], v = ei[NE + k];
    double e = a_d[u] + b_d[v] + (double)pb[0];
    e_d[k] = e;
    atomicMax(&emax[v], enc_f((float)e));
}
__global__ void edge_p2(const int* __restrict__ ei, double* e_d,
                        const u32* __restrict__ emax, double* ssum) {
    int k = blockIdx.x * 256 + threadIdx.x;
    if (k >= NE) return;
    int v = ei[NE + k];
    float mf = dec_f(emax[v]);
    double ex = exp(e_d[k] - (double)mf);
    e_d[k] = ex;
    unsafeAtomicAdd(&ssum[v], ex);
}
__global__ void edge_p3(const int* __restrict__ ei, const double* __restrict__ e_d,
                        const double* __restrict__ ssum, float* score, u64* key,
                        int* sel, int* act0, u64* best) {
    int k = blockIdx.x * 256 + threadIdx.x;
    if (k >= NE) return;
    int u = ei[k], v = ei[NE + k];
    float sc = (float)(e_d[k] / ssum[v] + 0.5);
    score[k] = sc;
    u32 m = enc_f(sc);
    u64 kk = ((u64)(m ^ 0xFFFFFFFFu) << 32) | (u32)k;  // low = high score, tie: low idx
    key[k] = kk;
    sel[k] = 0;
    act0[k] = k;
    atomicMin(&best[u], kk);
    atomicMin(&best[v], kk);
}

// ---------------- flattened dominant-edge peeling rounds ----------------
__global__ void mk_sel(const u64* __restrict__ key, const int* __restrict__ ei,
                       const int* __restrict__ act, const int* __restrict__ cntp,
                       int* ncntp, const u64* __restrict__ best,
                       u32* used, int* sel) {
    int cnt = cntp[0];
    int stride = gridDim.x * blockDim.x;
    int gid = blockIdx.x * blockDim.x + threadIdx.x;
    if (gid == 0) ncntp[0] = 0;
    for (int i = gid; i < cnt; i += stride) {
        int e = act[i];
        u64 k = key[e];
        int a = ei[e], b = ei[NE + e];
        if (best[a] == k && best[b] == k) { sel[e] = 1; used[a] = 1u; used[b] = 1u; }
    }
}
__global__ void mk_compact(const int* __restrict__ ei, const int* __restrict__ act,
                           const int* __restrict__ cntp, int* nxt, int* ncntp,
                           u64* best, const u32* __restrict__ used) {
    int cnt = cntp[0];
    int stride = gridDim.x * blockDim.x;
    for (int i = blockIdx.x * blockDim.x + threadIdx.x; i < cnt; i += stride) {
        int e = act[i];
        int a = ei[e], b = ei[NE + e];
        best[a] = ~0ull; best[b] = ~0ull;
        bool live = !(used[a] | used[b]);
        u64 mask = __ballot(live);
        if (mask) {
            int lane = threadIdx.x & 63;
            int leader = __ffsll((unsigned long long)mask) - 1;
            int base = 0;
            if (lane == leader) base = atomicAdd(ncntp, __popcll(mask));
            base = __shfl(base, leader, 64);
            if (live) nxt[base + __popcll(mask & ((1ull << lane) - 1ull))] = e;
        }
    }
}
__global__ void mk_min(const u64* __restrict__ key, const int* __restrict__ ei,
                       const int* __restrict__ act, const int* __restrict__ cntp,
                       u64* best) {
    int cnt = cntp[0];
    int stride = gridDim.x * blockDim.x;
    for (int i = blockIdx.x * blockDim.x + threadIdx.x; i < cnt; i += stride) {
        int e = act[i];
        u64 k = key[e];
        atomicMin(&best[ei[e]], k);
        atomicMin(&best[ei[NE + e]], k);
    }
}
__global__ void __launch_bounds__(1024) match_fin(
        const u64* __restrict__ key, const int* __restrict__ ei,
        int* sel, u64* best, u32* used,
        int* listA, int* listB, const int* __restrict__ cntp) {
    int tid = threadIdx.x;
    int cnt = cntp[0];
    int* cur = listA; int* nxt = listB;
    __shared__ int s_n;
    for (int round = 0; round < 4096 && cnt > 0; ++round) {
        for (int i = tid; i < cnt; i += 1024) {
            int e = cur[i]; u64 k = key[e];
            atomicMin(&best[ei[e]], k);
            atomicMin(&best[ei[NE + e]], k);
        }
        __syncthreads();
        for (int i = tid; i < cnt; i += 1024) {
            int e = cur[i]; u64 k = key[e];
            int a = ei[e], b = ei[NE + e];
            if (best[a] == k && best[b] == k) { sel[e] = 1; used[a] = 1u; used[b] = 1u; }
        }
        if (tid == 0) s_n = 0;
        __syncthreads();
        for (int i = tid; i < cnt; i += 1024) {
            int e = cur[i];
            int a = ei[e], b = ei[NE + e];
            best[a] = ~0ull; best[b] = ~0ull;
            if (!(used[a] | used[b])) {
                int idx = atomicAdd(&s_n, 1);
                nxt[idx] = e;
            }
        }
        __syncthreads();
        cnt = s_n;
        int* t = cur; cur = nxt; nxt = t;
        __syncthreads();
    }
}

__global__ void cluster_init(int* cluster, int* other, float* nscore, u32* cin) {
    int n = blockIdx.x * 256 + threadIdx.x;
    if (n >= NN) return;
    cluster[n] = n; other[n] = -1; nscore[n] = 1.0f; cin[n] = 0u;
}
__global__ void apply_sel(const int* __restrict__ ei, const int* __restrict__ sel,
                          const float* __restrict__ score,
                          int* cluster, int* other, float* nscore) {
    int e = blockIdx.x * 256 + threadIdx.x;
    if (e >= NE) return;
    if (sel[e] != 1) return;
    int u = ei[e], v = ei[NE + e];
    int rep = min(u, v);
    cluster[u] = rep; cluster[v] = rep;
    if (u != v) other[rep] = u + v - rep;
    nscore[rep] = score[e];
}

// ---------------- coarse graph: dedup (cu,cv) pairs via hash set ----------------
__global__ void coarse_build(const int* __restrict__ ei, const int* __restrict__ cluster,
                             u32* ht, int* misc, int* ce_u, int* ce_v, u32* deg,
                             u32* cin) {
    int e = blockIdx.x * 256 + threadIdx.x;
    if (e >= NE) return;
    int cu = cluster[ei[e]], cv = cluster[ei[NE + e]];
    if (cu == cv) return;
    u32 k = (u32)cu * 32768u + (u32)cv;
    u32 h = ((k * 2654435761u) >> 12) & HTM;
    while (true) {
        u32 old = atomicCAS(&ht[h], 0xFFFFFFFFu, k);
        if (old == 0xFFFFFFFFu) {
            int idx = atomicAdd(&misc[0], 1);
            ce_u[idx] = cu; ce_v[idx] = cv;
            atomicAdd(&deg[cu], 1u);
            atomicAdd(&cin[cv], 1u);
            break;
        }
        if (old == k) break;
        h = (h + 1) & HTM;
    }
}
__global__ void dis_kernel(const u32* __restrict__ deg, float* dis) {
    int n = blockIdx.x * 256 + threadIdx.x;
    if (n >= NN) return;
    u32 d = deg[n];
    dis[n] = d ? (float)(1.0 / sqrt((double)d)) : 0.0f;
}

// ---------------- CSR build: exclusive scan of cin -> off, cur ----------------
__global__ void __launch_bounds__(1024) scan_kernel(const u32* __restrict__ cin,
                                                    int* off, int* cur) {
    __shared__ int part[1024];
    int t = threadIdx.x;
    int base = t << 5;
    int loc[32];
    int s = 0;
    #pragma unroll
    for (int i = 0; i < 32; ++i) { loc[i] = s; s += (int)cin[base + i]; }
    part[t] = s;
    __syncthreads();
    for (int d = 1; d < 1024; d <<= 1) {
        int v = (t >= d) ? part[t - d] : 0;
        __syncthreads();
        if (t >= d) part[t] += v;
        __syncthreads();
    }
    int pre = (t == 0) ? 0 : part[t - 1];
    #pragma unroll
    for (int i = 0; i < 32; ++i) {
        int v = pre + loc[i];
        off[base + i] = v;
        cur[base + i] = v;
    }
}
__global__ void csr_scatter(const int* __restrict__ ce_u, const int* __restrict__ ce_v,
                            const float* __restrict__ dis, const int* __restrict__ misc,
                            int* cur, int* csr_a, float* csr_c) {
    int e = blockIdx.x * 256 + threadIdx.x;
    if (e >= misc[0]) return;
    int a = ce_u[e], b = ce_v[e];
    int pos = atomicAdd(&cur[b], 1);
    csr_a[pos] = a;
    csr_c[pos] = -dis[a] * dis[b];
}

// ---- packed fragment index: row r, col k -> ushort offset ----
// tile=r>>4, l16=r&15, kt=k>>5, quad=(k>>3)&3, j=k&7
// off = ((tile*KT + kt)*64 + quad*16 + l16)*8 + j   (lane = quad*16+l16)
__device__ __forceinline__ size_t pk_idx(int r, int k, int KT) {
    return ((((size_t)(r >> 4) * KT + (k >> 5)) << 6) + (((k >> 3) & 3) << 4) + (r & 15)) << 3;
}

// ---------------- pre-gather px -> packed bf16 Ax, pxlast[NN] (col 1024) ----------------
__global__ void __launch_bounds__(128) conv_a1(
        const float* __restrict__ x, const int* __restrict__ clus,
        const int* __restrict__ other, const float* __restrict__ nsc,
        unsigned short* __restrict__ Abf, float* __restrict__ pxl) {
    int r = blockIdx.x;
    int t = threadIdx.x;
    bool valid = (clus[r] == r);
    int o = other[r];
    float s = nsc[r];
    const float* xr = x + (size_t)r * FIN;
    const float* xo = x + (size_t)(o >= 0 ? o : r) * FIN;
    int c0 = t << 3;
    unsigned short h[8];
    #pragma unroll
    for (int j = 0; j < 8; ++j) {
        float v = 0.0f;
        if (valid) {
            v = xr[c0 + j];
            if (o >= 0) v += xo[c0 + j];
            v *= s;
        }
        h[j] = f2bf(v);
    }
    *(us8*)&Abf[pk_idx(r, c0, 32)] = *(const us8*)h;
    if (t == 0) {
        float v = 0.0f;
        if (valid) { v = xr[1024]; if (o >= 0) v += xo[1024]; v *= s; }
        pxl[r] = v;
    }
}

// ---------------- weight transpose -> packed bf16 Bt ----------------
__global__ void conv_b(const float* __restrict__ B0, const float* __restrict__ B1,
                       unsigned short* __restrict__ Bp, int KT) {
    int n = blockIdx.x * 256 + threadIdx.x;
    int k0 = blockIdx.y * 8;
    unsigned short h[8];
    #pragma unroll
    for (int j = 0; j < 8; ++j) {
        int k = k0 + j;
        float v = (n < 512) ? B0[(size_t)k * 512 + n] : B1[(size_t)k * 512 + (n - 512)];
        h[j] = f2bf(v);
    }
    *(us8*)&Bp[pk_idx(n, k0, KT)] = *(const us8*)h;
}

// ---------------- packed-fragment bf16 MFMA GEMM: P[M x 1024] = A @ B^T (+rank-1) ----------------
// 128x128 tile, 4 waves (64x64 each), BK=32. All loads fully coalesced (1024B/wave),
// ping-pong register prefetch, no LDS, no barriers.
template <bool R1>
__global__ void __launch_bounds__(256, 3) gemm_pk(
        const unsigned short* __restrict__ Ap, const unsigned short* __restrict__ Bp,
        float* __restrict__ P, int KT,
        const float* __restrict__ pxl, const float* __restrict__ w0,
        const float* __restrict__ w1) {
    int tid = threadIdx.x;
    int bid = blockIdx.x;
    // XCD swizzle: xcd = bid&7 owns m-range, n fastest within
    int loc = bid >> 3;
    int bn = (loc & 7) << 7;
    int bm = ((((bid & 7) << 5) | (loc >> 3))) << 7;
    int wave = tid >> 6, lane = tid & 63, quad = lane >> 4, l16 = lane & 15;
    int moff = (wave >> 1) << 6, noff = (wave & 1) << 6;
    f32x4 acc[4][4];
    #pragma unroll
    for (int i = 0; i < 4; ++i)
        #pragma unroll
        for (int j = 0; j < 4; ++j) acc[i][j] = (f32x4){0.f, 0.f, 0.f, 0.f};

    int tm0 = (bm + moff) >> 4, tn0 = (bn + noff) >> 4;
    const unsigned short* pa[4];
    const unsigned short* pb[4];
    #pragma unroll
    for (int i = 0; i < 4; ++i) {
        pa[i] = Ap + (((size_t)(tm0 + i) * KT) << 9) + (lane << 3);
        pb[i] = Bp + (((size_t)(tn0 + i) * KT) << 9) + (lane << 3);
    }
    bf16x8 a0[4], b0[4], a1[4], b1[4];
    #pragma unroll
    for (int i = 0; i < 4; ++i) { a0[i] = ld_frag(pa[i]); b0[i] = ld_frag(pb[i]); }

    for (int kt = 0; kt < KT; kt += 2) {
        size_t o1 = ((size_t)(kt + 1)) << 9;
        #pragma unroll
        for (int i = 0; i < 4; ++i) { a1[i] = ld_frag(pa[i] + o1); b1[i] = ld_frag(pb[i] + o1); }
        #pragma unroll
        for (int mi = 0; mi < 4; ++mi)
            #pragma unroll
            for (int ni = 0; ni < 4; ++ni)
                acc[mi][ni] = __builtin_amdgcn_mfma_f32_16x16x32_bf16(a0[mi], b0[ni], acc[mi][ni], 0, 0, 0);
        if (kt + 2 < KT) {
            size_t o2 = ((size_t)(kt + 2)) << 9;
            #pragma unroll
            for (int i = 0; i < 4; ++i) { a0[i] = ld_frag(pa[i] + o2); b0[i] = ld_frag(pb[i] + o2); }
        }
        #pragma unroll
        for (int mi = 0; mi < 4; ++mi)
            #pragma unroll
            for (int ni = 0; ni < 4; ++ni)
                acc[mi][ni] = __builtin_amdgcn_mfma_f32_16x16x32_bf16(a1[mi], b1[ni], acc[mi][ni], 0, 0, 0);
    }
    // epilogue: C/D row=quad*4+r2, col=l16; optional rank-1 (column 1024 of A/B)
    #pragma unroll
    for (int mi = 0; mi < 4; ++mi)
        #pragma unroll
        for (int ni = 0; ni < 4; ++ni) {
            int col = bn + noff + (ni << 4) + l16;
            float wl = 0.0f;
            if (R1) wl = (col < 512) ? w0[524288 + col] : w1[524288 + col - 512];
            #pragma unroll
            for (int r2 = 0; r2 < 4; ++r2) {
                int row = bm + moff + (mi << 4) + (quad << 2) + r2;
                float v = acc[mi][ni][r2];
                if (R1) v += pxl[row] * wl;
                P[(size_t)row * 1024 + col] = v;
            }
        }
}

// ---------------- fused gather + BN + ReLU: one wave per destination row ----------------
// out[b] = relu(BN(P0[b] + sum_{(a->b)} coef*P1[a] + bias)); packed bf16 or fp32 output
template <bool BF16OUT>
__global__ void __launch_bounds__(256) cheb_fuse(
        const float* __restrict__ P, const int* __restrict__ off,
        const int* __restrict__ csr_a, const float* __restrict__ csr_c,
        const int* __restrict__ misc, const float* __restrict__ bias,
        const float* __restrict__ bn, float* __restrict__ Hf,
        unsigned short* __restrict__ Hb) {
    int b = (blockIdx.x * 256 + threadIdx.x) >> 6;
    int lane = threadIdx.x & 63;
    if (b >= NN) return;
    int s = off[b];
    int e = (b < NN - 1) ? off[b + 1] : misc[0];
    int c0 = lane << 3;
    float a0[4], a1[4];
    {
        float4 t0 = *(const float4*)&P[(size_t)b * 1024 + c0];
        float4 t1 = *(const float4*)&P[(size_t)b * 1024 + c0 + 4];
        a0[0] = t0.x; a0[1] = t0.y; a0[2] = t0.z; a0[3] = t0.w;
        a1[0] = t1.x; a1[1] = t1.y; a1[2] = t1.z; a1[3] = t1.w;
    }
    for (int j = s; j < e; ++j) {
        int a = csr_a[j];
        float cf = csr_c[j];
        float4 p0 = *(const float4*)&P[(size_t)a * 1024 + 512 + c0];
        float4 p1 = *(const float4*)&P[(size_t)a * 1024 + 512 + c0 + 4];
        a0[0] = fmaf(cf, p0.x, a0[0]); a0[1] = fmaf(cf, p0.y, a0[1]);
        a0[2] = fmaf(cf, p0.z, a0[2]); a0[3] = fmaf(cf, p0.w, a0[3]);
        a1[0] = fmaf(cf, p1.x, a1[0]); a1[1] = fmaf(cf, p1.y, a1[1]);
        a1[2] = fmaf(cf, p1.z, a1[2]); a1[3] = fmaf(cf, p1.w, a1[3]);
    }
    float o[8];
    #pragma unroll
    for (int i = 0; i < 8; ++i) {
        int j = c0 + i;
        float acc = (i < 4) ? a0[i] : a1[i - 4];
        float ga = bn[j], be = bn[512 + j], mn = bn[1024 + j], vr = bn[1536 + j];
        float sc = (float)(1.0 / sqrt((double)vr + 1e-5));
        float v = (acc + bias[j] - mn) * sc * ga + be;
        o[i] = v > 0.0f ? v : 0.0f;
    }
    if (BF16OUT) {
        unsigned short h[8];
        #pragma unroll
        for (int i = 0; i < 8; ++i) h[i] = f2bf(o[i]);
        *(us8*)&Hb[pk_idx(b, c0, 16)] = *(const us8*)h;   // packed for layer-2 GEMM
    } else {
        *(float4*)&Hf[(size_t)b * 512 + c0] = make_float4(o[0], o[1], o[2], o[3]);
        *(float4*)&Hf[(size_t)b * 512 + c0 + 4] = make_float4(o[4], o[5], o[6], o[7]);
    }
}

// ---------------- global max+mean pool over valid nodes per graph ----------------
__global__ void __launch_bounds__(256) pool_kernel(
        const float* __restrict__ H, const int* __restrict__ cluster,
        const int* __restrict__ batch, u32* gmaxb, float* gsum, float* gcnt) {
    int t = threadIdx.x;
    int n0 = blockIdx.x * 64;
    float m0 = 0.0f, m1 = 0.0f, s0 = 0.0f, s1 = 0.0f;
    int cntl = 0;
    int cur = batch[n0];
    for (int i = 0; i < 64; ++i) {
        int n = n0 + i;
        int bt = batch[n];
        if (bt != cur) {
            atomicMax(&gmaxb[cur * 512 + t], __float_as_uint(m0));
            atomicMax(&gmaxb[cur * 512 + t + 256], __float_as_uint(m1));
            unsafeAtomicAdd(&gsum[cur * 512 + t], s0);
            unsafeAtomicAdd(&gsum[cur * 512 + t + 256], s1);
            if (t == 0) unsafeAtomicAdd(&gcnt[cur], (float)cntl);
            m0 = m1 = s0 = s1 = 0.0f; cntl = 0; cur = bt;
        }
        if (cluster[n] == n) {
            float h0 = H[(size_t)n * 512 + t];
            float h1 = H[(size_t)n * 512 + t + 256];
            m0 = fmaxf(m0, h0); m1 = fmaxf(m1, h1);
            s0 += h0; s1 += h1;
            ++cntl;
        }
    }
    atomicMax(&gmaxb[cur * 512 + t], __float_as_uint(m0));
    atomicMax(&gmaxb[cur * 512 + t + 256], __float_as_uint(m1));
    unsafeAtomicAdd(&gsum[cur * 512 + t], s0);
    unsafeAtomicAdd(&gsum[cur * 512 + t + 256], s1);
    if (t == 0) unsafeAtomicAdd(&gcnt[cur], (float)cntl);
}

// ---------------- readout MLP + log_softmax (tiny, one block) ----------------
__global__ void __launch_bounds__(512) readout(
        const u32* __restrict__ gmaxb, const float* __restrict__ gsum,
        const float* __restrict__ gcnt,
        const float* __restrict__ l1w, const float* __restrict__ l1b,
        const float* __restrict__ bn3,
        const float* __restrict__ l2w, const float* __restrict__ l2b,
        const float* __restrict__ bn4,
        const float* __restrict__ l3w, const float* __restrict__ l3b,
        float* __restrict__ out) {
    __shared__ float G[8 * 1024];
    __shared__ float G1[8 * 512];
    __shared__ float G2[8 * 256];
    int t = threadIdx.x;
    for (int idx = t; idx < 8192; idx += 512) {
        int b = idx >> 10, j = idx & 1023;
        float v;
        if (j < 512) v = __uint_as_float(gmaxb[b * 512 + j]);
        else v = gsum[b * 512 + (j - 512)] / fmaxf(gcnt[b], 1.0f);
        G[idx] = v;
    }
    __syncthreads();
    {
        int o = t;
        float acc[8];
        #pragma unroll
        for (int b = 0; b < 8; ++b) acc[b] = l1b[o];
        for (int k = 0; k < 1024; ++k) {
            float w = l1w[k * 512 + o];
            #pragma unroll
            for (int b = 0; b < 8; ++b) acc[b] += G[b * 1024 + k] * w;
        }
        float ga = bn3[o], be = bn3[512 + o], mn = bn3[1024 + o], vr = bn3[1536 + o];
        float sc = (float)(1.0 / sqrt((double)vr + 1e-5));
        #pragma unroll
        for (int b = 0; b < 8; ++b) {
            float v = (acc[b] - mn) * sc * ga + be;
            G1[b * 512 + o] = v > 0.0f ? v : 0.0f;
        }
    }
    __syncthreads();
    if (t < 256) {
        int o = t;
        float acc[8];
        #pragma unroll
        for (int b = 0; b < 8; ++b) acc[b] = l2b[o];
        for (int k = 0; k < 512; ++k) {
            float w = l2w[k * 256 + o];
            #pragma unroll
            for (int b = 0; b < 8; ++b) acc[b] += G1[b * 512 + k] * w;
        }
        float ga = bn4[o], be = bn4[256 + o], mn = bn4[512 + o], vr = bn4[768 + o];
        float sc = (float)(1.0 / sqrt((double)vr + 1e-5));
        #pragma unroll
        for (int b = 0; b < 8; ++b) {
            float v = (acc[b] - mn) * sc * ga + be;
            v = v > 0.0f ? v : 0.0f;
            G2[b * 256 + o] = v;
            out[32 + b * 256 + o] = v;
        }
    }
    __syncthreads();
    if (t < 8) {
        int b = t;
        float r[4];
        #pragma unroll
        for (int c = 0; c < 4; ++c) {
            float acc = l3b[c];
            for (int k = 0; k < 256; ++k) acc += G2[b * 256 + k] * l3w[k * 4 + c];
            r[c] = acc > 0.0f ? acc : 0.0f;
        }
        float mx = fmaxf(fmaxf(r[0], r[1]), fmaxf(r[2], r[3]));
        float s = 0.0f;
        #pragma unroll
        for (int c = 0; c < 4; ++c) s += expf(r[c] - mx);
        float lse = mx + logf(s);
        #pragma unroll
        for (int c = 0; c < 4; ++c) out[b * 4 + c] = r[c] - lse;
    }
}

extern "C" void kernel_launch(void* const* d_in, const int* in_sizes, int n_in,
                              void* d_out, int out_size, void* d_ws, size_t ws_size,
                              hipStream_t stream) {
    const float* x      = (const float*)d_in[0];
    const int*   ei     = (const int*)d_in[1];
    const int*   batch  = (const int*)d_in[2];
    const float* pool_w = (const float*)d_in[3];
    const float* pool_b = (const float*)d_in[4];
    const float* c1_w0  = (const float*)d_in[5];
    const float* c1_w1  = (const float*)d_in[6];
    const float* c1_b   = (const float*)d_in[7];
    const float* c2_w0  = (const float*)d_in[8];
    const float* c2_w1  = (const float*)d_in[9];
    const float* c2_b   = (const float*)d_in[10];
    const float* bn1    = (const float*)d_in[11];
    const float* bn2    = (const float*)d_in[12];
    const float* bn3    = (const float*)d_in[13];
    const float* bn4    = (const float*)d_in[14];
    const float* l1w    = (const float*)d_in[15];
    const float* l1b    = (const float*)d_in[16];
    const float* l2w    = (const float*)d_in[17];
    const float* l2b    = (const float*)d_in[18];
    const float* l3w    = (const float*)d_in[19];
    const float* l3b    = (const float*)d_in[20];
    float* out = (float*)d_out;
    char* ws = (char*)d_ws;

    double* a_d   = (double*)(ws + WS_A_D);
    double* b_d   = (double*)(ws + WS_B_D);
    u32*    emax  = (u32*)(ws + WS_EMAX);
    double* ssum  = (double*)(ws + WS_SSUM);
    double* exd   = (double*)(ws + WS_EXD);
    u32*    cin   = (u32*)(ws + WS_CIN);
    u64*    key   = (u64*)(ws + WS_KEY);
    u64*    best  = (u64*)(ws + WS_BEST);
    u32*    used  = (u32*)(ws + WS_USED);
    int*    curp  = (int*)(ws + WS_CUR);
    int*    act0  = (int*)(ws + WS_ACT0);
    int*    act1  = (int*)(ws + WS_ACT1);
    unsigned short* bthi = (unsigned short*)(ws + WS_BTHI);
    float*  pxl   = (float*)(ws + WS_PXL);
    u32*    ht    = (u32*)(ws + WS_HT);
    float*  score = (float*)(ws + WS_SCORE);
    int*    csr_a = (int*)(ws + WS_CSRA);
    int*    sel   = (int*)(ws + WS_SEL);
    float*  csr_c = (float*)(ws + WS_CSRC);
    int*    clus  = (int*)(ws + WS_CLUST);
    int*    other = (int*)(ws + WS_OTHER);
    float*  nsc   = (float*)(ws + WS_NSC);
    int*    ce_u  = (int*)(ws + WS_CEU);
    int*    ce_v  = (int*)(ws + WS_CEV);
    u32*    deg   = (u32*)(ws + WS_DEG);
    int*    off   = (int*)(ws + WS_OFF);
    float*  dis   = (float*)(ws + WS_DIS);
    int*    misc  = (int*)(ws + WS_MISC);
    u32*    gmaxb = (u32*)(ws + WS_GMAX);
    float*  gsum  = (float*)(ws + WS_GSUM);
    float*  gcnt  = (float*)(ws + WS_GCNT);
    float*  P     = (float*)(ws + WS_P);
    unsigned short* ax = (unsigned short*)(ws + WS_H);   // packed Ax bf16 (gemm1 A)
    unsigned short* hb = (unsigned short*)(ws + WS_H);   // packed Hb bf16 (gemm2 A)
    float*  H     = (float*)(ws + WS_H);                 // final H fp32

    // ---- phase A: scores, matching, coarse graph ----
    init_misc<<<NN / 256, 256, 0, stream>>>(emax, ssum, deg, misc, gmaxb, gsum, gcnt,
                                            best, used);
    node_dots<<<NN / 4, 256, 0, stream>>>(x, pool_w, a_d, b_d);
    edge_p1<<<NE / 256, 256, 0, stream>>>(ei, a_d, b_d, pool_b, exd, emax);
    edge_p2<<<NE / 256, 256, 0, stream>>>(ei, exd, emax, ssum);
    edge_p3<<<NE / 256, 256, 0, stream>>>(ei, exd, ssum, score, key, sel, act0, best);

    {
        static const int gr[9] = {512, 512, 256, 128, 64, 32, 16, 8, 8};
        int* acts[2] = {act0, act1};
        for (int r = 0; r < 8; ++r) {
            int c = r & 1, n = 1 - c;
            mk_sel<<<gr[r], 256, 0, stream>>>(key, ei, acts[c], &misc[1 + c],
                                              &misc[1 + n], best, used, sel);
            mk_compact<<<gr[r], 256, 0, stream>>>(ei, acts[c], &misc[1 + c],
                                                  acts[n], &misc[1 + n], best, used);
            mk_min<<<gr[r + 1], 256, 0, stream>>>(key, ei, acts[n], &misc[1 + n], best);
        }
        match_fin<<<1, 1024, 0, stream>>>(key, ei, sel, best, used,
                                          act0, act1, &misc[1]);
    }

    cluster_init<<<NN / 256, 256, 0, stream>>>(clus, other, nsc, cin);
    apply_sel<<<NE / 256, 256, 0, stream>>>(ei, sel, score, clus, other, nsc);
    init_ht<<<HTS / 256, 256, 0, stream>>>(ht);
    coarse_build<<<NE / 256, 256, 0, stream>>>(ei, clus, ht, misc, ce_u, ce_v, deg, cin);
    dis_kernel<<<NN / 256, 256, 0, stream>>>(deg, dis);
    scan_kernel<<<1, 1024, 0, stream>>>(cin, off, curp);
    csr_scatter<<<NE / 256, 256, 0, stream>>>(ce_u, ce_v, dis, misc, curp, csr_a, csr_c);

    // ---- phase B: ChebConv layers (packed-fragment MFMA + fused gather/BN/ReLU) ----
    conv_b<<<dim3(4, 128), 256, 0, stream>>>(c1_w0, c1_w1, bthi, 32);
    conv_a1<<<NN, 128, 0, stream>>>(x, clus, other, nsc, ax, pxl);
    gemm_pk<true><<<2048, 256, 0, stream>>>(ax, bthi, P, 32, pxl, c1_w0, c1_w1);
    cheb_fuse<true><<<NN / 4, 256, 0, stream>>>(P, off, csr_a, csr_c, misc, c1_b, bn1,
                                                nullptr, hb);

    conv_b<<<dim3(4, 64), 256, 0, stream>>>(c2_w0, c2_w1, bthi, 16);
    gemm_pk<false><<<2048, 256, 0, stream>>>(hb, bthi, P, 16, nullptr, nullptr, nullptr);
    cheb_fuse<false><<<NN / 4, 256, 0, stream>>>(P, off, csr_a, csr_c, misc, c2_b, bn2,
                                                 H, nullptr);

    pool_kernel<<<NN / 64, 256, 0, stream>>>(H, clus, batch, gmaxb, gsum, gcnt);
    readout<<<1, 512, 0, stream>>>(gmaxb, gsum, gcnt, l1w, l1b, bn3,
                                   l2w, l2b, bn4, l3w, l3b, out);
}

// Round 8
// 891.254 us; speedup vs baseline: 7.5439x; 1.2023x over previous
//
#include <hip/hip_runtime.h>
#include <hip/hip_bf16.h>
#include <cstdint>
#include <cmath>

typedef unsigned int u32;
typedef unsigned long long u64;
typedef float f32x4 __attribute__((ext_vector_type(4)));
typedef __bf16 bf16x8 __attribute__((ext_vector_type(8)));
typedef unsigned short us8 __attribute__((ext_vector_type(8)));
typedef unsigned short us4 __attribute__((ext_vector_type(4)));

#define NN 32768
#define NE 131072
#define FIN 1025
#define HTS 262144
#define HTM (HTS - 1)

// ---------------- workspace layout (byte offsets) ----------------
#define WS_A_D    0ul          // double[NN]
#define WS_B_D    262144ul     // double[NN]
#define WS_EMAX   524288ul     // u32[NN]
#define WS_SSUM   655360ul     // double[NN]
#define WS_EXD    917504ul     // double[NE]
#define WS_CIN    917504ul     // u32[NN]  overlays EXD head
#define WS_KEY    1966080ul    // u64[NE]
#define WS_BEST   3014656ul    // u64[NN]
#define WS_USED   3276800ul    // u32[NN]
#define WS_CUR    3276800ul    // int[NN]  overlays USED (dead after match_fin)
#define WS_ACT0   3407872ul    // int[NE]
#define WS_ACT1   3932160ul    // int[NE]   (zone ends 4456448)
#define WS_BTHI   0ul          // ushort[1024*1024] packed frag order (phase B)
#define WS_PXL    4194304ul    // float[NN]                            (phase B)
#define WS_HT     1966080ul    // u32[HTS] overlays KEY (dead after coarse_build)
// readout scratch (phase B, overlays dead HT tail):
#define WS_RACC1  2097152ul    // float[8*512]
#define WS_RACC2  2113536ul    // float[8*256]
#define WS_RG1    2121728ul    // float[8*512]
// persistent:
#define WS_SCORE  4456448ul    // float[NE]
#define WS_CSRA   4456448ul    // int[NE]  overlays SCORE (dead after apply_sel)
#define WS_SEL    4980736ul    // int[NE]
#define WS_CSRC   4980736ul    // float[NE] overlays SEL (dead after apply_sel)
#define WS_CLUST  5505024ul    // int[NN]
#define WS_OTHER  5636096ul    // int[NN]
#define WS_NSC    5767168ul    // float[NN]
#define WS_CEU    5898240ul    // int[NE]
#define WS_CEV    6422528ul    // int[NE]
#define WS_DEG    6946816ul    // u32[NN]
#define WS_OFF    6946816ul    // int[NN]  overlays DEG
#define WS_DIS    7077888ul    // float[NN]
#define WS_MISC   7208960ul    // int[64]
#define WS_GMAX   7209216ul    // u32[8*512]
#define WS_GSUM   7225600ul    // float[8*512]
#define WS_GCNT   7241984ul    // float[64]
#define WS_P      7242240ul    // float[NN*1024]
#define WS_H      141459968ul  // Ax/Hb bf16 packed -> H f32[NN*512]

__device__ __forceinline__ u32 enc_f(float f) {
    u32 b = __float_as_uint(f);
    return (b & 0x80000000u) ? ~b : (b | 0x80000000u);
}
__device__ __forceinline__ float dec_f(u32 m) {
    return (m & 0x80000000u) ? __uint_as_float(m ^ 0x80000000u) : __uint_as_float(~m);
}
__device__ __forceinline__ double wave_sum(double v) {
    #pragma unroll
    for (int off = 32; off > 0; off >>= 1) v += __shfl_down(v, off, 64);
    return v;
}
__device__ __forceinline__ unsigned short f2bf(float v) {   // RNE f32->bf16
    u32 b = __float_as_uint(v);
    u32 r = b + 0x7FFFu + ((b >> 16) & 1u);
    return (unsigned short)(r >> 16);
}
__device__ __forceinline__ bf16x8 ld_frag(const unsigned short* p) {
    union { us8 u; bf16x8 b; } t;
    t.u = *(const us8*)p;
    return t.b;
}

// ---------------- init ----------------
__global__ void init_misc(u32* emax, double* ssum, u32* deg,
                          int* misc, u32* gmaxb, float* gsum, float* gcnt,
                          u64* best, u32* used) {
    int i = blockIdx.x * 256 + threadIdx.x;
    if (i < NN) { emax[i] = 0u; ssum[i] = 0.0; deg[i] = 0u; best[i] = ~0ull; used[i] = 0u; }
    if (i < 4096) { gmaxb[i] = 0u; gsum[i] = 0.0f; }
    if (i < 64) { misc[i] = (i == 1) ? NE : 0; gcnt[i] = 0.0f; }
}
__global__ void init_ht(u32* ht) {
    int i = blockIdx.x * 256 + threadIdx.x;
    if (i < HTS) ht[i] = 0xFFFFFFFFu;
}

// ---------------- per-node dots with pool_w halves (double accum) ----------------
__global__ void node_dots(const float* __restrict__ x, const float* __restrict__ pw,
                          double* a_d, double* b_d) {
    int wave = (blockIdx.x * blockDim.x + threadIdx.x) >> 6;
    int lane = threadIdx.x & 63;
    if (wave >= NN) return;
    const float* xr = x + (size_t)wave * FIN;
    double s0 = 0.0, s1 = 0.0;
    for (int f = lane; f < FIN; f += 64) {
        double xv = (double)xr[f];
        s0 += xv * (double)pw[f];
        s1 += xv * (double)pw[FIN + f];
    }
    s0 = wave_sum(s0); s1 = wave_sum(s1);
    if (lane == 0) { a_d[wave] = s0; b_d[wave] = s1; }
}

// ---------------- edge score pipeline ----------------
__global__ void edge_p1(const int* __restrict__ ei, const double* __restrict__ a_d,
                        const double* __restrict__ b_d, const float* __restrict__ pb,
                        double* e_d, u32* emax) {
    int k = blockIdx.x * 256 + threadIdx.x;
    if (k >= NE) return;
    int u = ei[k], v = ei[NE + k];
    double e = a_d[u] + b_d[v] + (double)pb[0];
    e_d[k] = e;
    atomicMax(&emax[v], enc_f((float)e));
}
__global__ void edge_p2(const int* __restrict__ ei, double* e_d,
                        const u32* __restrict__ emax, double* ssum) {
    int k = blockIdx.x * 256 + threadIdx.x;
    if (k >= NE) return;
    int v = ei[NE + k];
    float mf = dec_f(emax[v]);
    double ex = exp(e_d[k] - (double)mf);
    e_d[k] = ex;
    unsafeAtomicAdd(&ssum[v], ex);
}
__global__ void edge_p3(const int* __restrict__ ei, const double* __restrict__ e_d,
                        const double* __restrict__ ssum, float* score, u64* key,
                        int* sel, int* act0, u64* best) {
    int k = blockIdx.x * 256 + threadIdx.x;
    if (k >= NE) return;
    int u = ei[k], v = ei[NE + k];
    float sc = (float)(e_d[k] / ssum[v] + 0.5);
    score[k] = sc;
    u32 m = enc_f(sc);
    u64 kk = ((u64)(m ^ 0xFFFFFFFFu) << 32) | (u32)k;  // low = high score, tie: low idx
    key[k] = kk;
    sel[k] = 0;
    act0[k] = k;
    atomicMin(&best[u], kk);
    atomicMin(&best[v], kk);
}

// ---------------- flattened dominant-edge peeling rounds ----------------
__global__ void mk_sel(const u64* __restrict__ key, const int* __restrict__ ei,
                       const int* __restrict__ act, const int* __restrict__ cntp,
                       int* ncntp, const u64* __restrict__ best,
                       u32* used, int* sel) {
    int cnt = cntp[0];
    int stride = gridDim.x * blockDim.x;
    int gid = blockIdx.x * blockDim.x + threadIdx.x;
    if (gid == 0) ncntp[0] = 0;
    for (int i = gid; i < cnt; i += stride) {
        int e = act[i];
        u64 k = key[e];
        int a = ei[e], b = ei[NE + e];
        if (best[a] == k && best[b] == k) { sel[e] = 1; used[a] = 1u; used[b] = 1u; }
    }
}
__global__ void mk_compact(const int* __restrict__ ei, const int* __restrict__ act,
                           const int* __restrict__ cntp, int* nxt, int* ncntp,
                           u64* best, const u32* __restrict__ used) {
    int cnt = cntp[0];
    int stride = gridDim.x * blockDim.x;
    for (int i = blockIdx.x * blockDim.x + threadIdx.x; i < cnt; i += stride) {
        int e = act[i];
        int a = ei[e], b = ei[NE + e];
        best[a] = ~0ull; best[b] = ~0ull;
        bool live = !(used[a] | used[b]);
        u64 mask = __ballot(live);
        if (mask) {
            int lane = threadIdx.x & 63;
            int leader = __ffsll((unsigned long long)mask) - 1;
            int base = 0;
            if (lane == leader) base = atomicAdd(ncntp, __popcll(mask));
            base = __shfl(base, leader, 64);
            if (live) nxt[base + __popcll(mask & ((1ull << lane) - 1ull))] = e;
        }
    }
}
__global__ void mk_min(const u64* __restrict__ key, const int* __restrict__ ei,
                       const int* __restrict__ act, const int* __restrict__ cntp,
                       u64* best) {
    int cnt = cntp[0];
    int stride = gridDim.x * blockDim.x;
    for (int i = blockIdx.x * blockDim.x + threadIdx.x; i < cnt; i += stride) {
        int e = act[i];
        u64 k = key[e];
        atomicMin(&best[ei[e]], k);
        atomicMin(&best[ei[NE + e]], k);
    }
}
__global__ void __launch_bounds__(1024) match_fin(
        const u64* __restrict__ key, const int* __restrict__ ei,
        int* sel, u64* best, u32* used,
        int* listA, int* listB, const int* __restrict__ cntp) {
    int tid = threadIdx.x;
    int cnt = cntp[0];
    int* cur = listA; int* nxt = listB;
    __shared__ int s_n;
    for (int round = 0; round < 4096 && cnt > 0; ++round) {
        for (int i = tid; i < cnt; i += 1024) {
            int e = cur[i]; u64 k = key[e];
            atomicMin(&best[ei[e]], k);
            atomicMin(&best[ei[NE + e]], k);
        }
        __syncthreads();
        for (int i = tid; i < cnt; i += 1024) {
            int e = cur[i]; u64 k = key[e];
            int a = ei[e], b = ei[NE + e];
            if (best[a] == k && best[b] == k) { sel[e] = 1; used[a] = 1u; used[b] = 1u; }
        }
        if (tid == 0) s_n = 0;
        __syncthreads();
        for (int i = tid; i < cnt; i += 1024) {
            int e = cur[i];
            int a = ei[e], b = ei[NE + e];
            best[a] = ~0ull; best[b] = ~0ull;
            if (!(used[a] | used[b])) {
                int idx = atomicAdd(&s_n, 1);
                nxt[idx] = e;
            }
        }
        __syncthreads();
        cnt = s_n;
        int* t = cur; cur = nxt; nxt = t;
        __syncthreads();
    }
}

__global__ void cluster_init(int* cluster, int* other, float* nscore, u32* cin) {
    int n = blockIdx.x * 256 + threadIdx.x;
    if (n >= NN) return;
    cluster[n] = n; other[n] = -1; nscore[n] = 1.0f; cin[n] = 0u;
}
__global__ void apply_sel(const int* __restrict__ ei, const int* __restrict__ sel,
                          const float* __restrict__ score,
                          int* cluster, int* other, float* nscore) {
    int e = blockIdx.x * 256 + threadIdx.x;
    if (e >= NE) return;
    if (sel[e] != 1) return;
    int u = ei[e], v = ei[NE + e];
    int rep = min(u, v);
    cluster[u] = rep; cluster[v] = rep;
    if (u != v) other[rep] = u + v - rep;
    nscore[rep] = score[e];
}

// ---------------- coarse graph: dedup (cu,cv) pairs via hash set ----------------
__global__ void coarse_build(const int* __restrict__ ei, const int* __restrict__ cluster,
                             u32* ht, int* misc, int* ce_u, int* ce_v, u32* deg,
                             u32* cin) {
    int e = blockIdx.x * 256 + threadIdx.x;
    if (e >= NE) return;
    int cu = cluster[ei[e]], cv = cluster[ei[NE + e]];
    if (cu == cv) return;
    u32 k = (u32)cu * 32768u + (u32)cv;
    u32 h = ((k * 2654435761u) >> 12) & HTM;
    while (true) {
        u32 old = atomicCAS(&ht[h], 0xFFFFFFFFu, k);
        if (old == 0xFFFFFFFFu) {
            int idx = atomicAdd(&misc[0], 1);
            ce_u[idx] = cu; ce_v[idx] = cv;
            atomicAdd(&deg[cu], 1u);
            atomicAdd(&cin[cv], 1u);
            break;
        }
        if (old == k) break;
        h = (h + 1) & HTM;
    }
}
// also zeroes readout partial-sum buffers (HT region dead by now)
__global__ void dis_kernel(const u32* __restrict__ deg, float* dis,
                           float* racc1, float* racc2) {
    int n = blockIdx.x * 256 + threadIdx.x;
    if (n >= NN) return;
    u32 d = deg[n];
    dis[n] = d ? (float)(1.0 / sqrt((double)d)) : 0.0f;
    if (n < 4096) racc1[n] = 0.0f;
    if (n < 2048) racc2[n] = 0.0f;
}

// ---------------- CSR build: exclusive scan of cin -> off, cur ----------------
__global__ void __launch_bounds__(1024) scan_kernel(const u32* __restrict__ cin,
                                                    int* off, int* cur) {
    __shared__ int part[1024];
    int t = threadIdx.x;
    int base = t << 5;
    int loc[32];
    int s = 0;
    #pragma unroll
    for (int i = 0; i < 32; ++i) { loc[i] = s; s += (int)cin[base + i]; }
    part[t] = s;
    __syncthreads();
    for (int d = 1; d < 1024; d <<= 1) {
        int v = (t >= d) ? part[t - d] : 0;
        __syncthreads();
        if (t >= d) part[t] += v;
        __syncthreads();
    }
    int pre = (t == 0) ? 0 : part[t - 1];
    #pragma unroll
    for (int i = 0; i < 32; ++i) {
        int v = pre + loc[i];
        off[base + i] = v;
        cur[base + i] = v;
    }
}
__global__ void csr_scatter(const int* __restrict__ ce_u, const int* __restrict__ ce_v,
                            const float* __restrict__ dis, const int* __restrict__ misc,
                            int* cur, int* csr_a, float* csr_c) {
    int e = blockIdx.x * 256 + threadIdx.x;
    if (e >= misc[0]) return;
    int a = ce_u[e], b = ce_v[e];
    int pos = atomicAdd(&cur[b], 1);
    csr_a[pos] = a;
    csr_c[pos] = -dis[a] * dis[b];
}

// ---- packed fragment index: row r, col k -> ushort offset ----
__device__ __forceinline__ size_t pk_idx(int r, int k, int KT) {
    return ((((size_t)(r >> 4) * KT + (k >> 5)) << 6) + (((k >> 3) & 3) << 4) + (r & 15)) << 3;
}

// ---------------- pre-gather px -> packed bf16 Ax, pxlast[NN] (col 1024) ----------------
__global__ void __launch_bounds__(128) conv_a1(
        const float* __restrict__ x, const int* __restrict__ clus,
        const int* __restrict__ other, const float* __restrict__ nsc,
        unsigned short* __restrict__ Abf, float* __restrict__ pxl) {
    int r = blockIdx.x;
    int t = threadIdx.x;
    bool valid = (clus[r] == r);
    int o = other[r];
    float s = nsc[r];
    const float* xr = x + (size_t)r * FIN;
    const float* xo = x + (size_t)(o >= 0 ? o : r) * FIN;
    int c0 = t << 3;
    unsigned short h[8];
    #pragma unroll
    for (int j = 0; j < 8; ++j) {
        float v = 0.0f;
        if (valid) {
            v = xr[c0 + j];
            if (o >= 0) v += xo[c0 + j];
            v *= s;
        }
        h[j] = f2bf(v);
    }
    *(us8*)&Abf[pk_idx(r, c0, 32)] = *(const us8*)h;
    if (t == 0) {
        float v = 0.0f;
        if (valid) { v = xr[1024]; if (o >= 0) v += xo[1024]; v *= s; }
        pxl[r] = v;
    }
}

// ---------------- weight transpose -> packed bf16 Bt ----------------
__global__ void conv_b(const float* __restrict__ B0, const float* __restrict__ B1,
                       unsigned short* __restrict__ Bp, int KT) {
    int n = blockIdx.x * 256 + threadIdx.x;
    int k0 = blockIdx.y * 8;
    unsigned short h[8];
    #pragma unroll
    for (int j = 0; j < 8; ++j) {
        int k = k0 + j;
        float v = (n < 512) ? B0[(size_t)k * 512 + n] : B1[(size_t)k * 512 + (n - 512)];
        h[j] = f2bf(v);
    }
    *(us8*)&Bp[pk_idx(n, k0, KT)] = *(const us8*)h;
}

// ---------------- packed-fragment bf16 MFMA GEMM: P[M x 1024] = A @ B^T (+rank-1) ----------------
template <bool R1>
__global__ void __launch_bounds__(256, 3) gemm_pk(
        const unsigned short* __restrict__ Ap, const unsigned short* __restrict__ Bp,
        float* __restrict__ P, int KT,
        const float* __restrict__ pxl, const float* __restrict__ w0,
        const float* __restrict__ w1) {
    int tid = threadIdx.x;
    int bid = blockIdx.x;
    int loc = bid >> 3;
    int bn = (loc & 7) << 7;
    int bm = ((((bid & 7) << 5) | (loc >> 3))) << 7;
    int wave = tid >> 6, lane = tid & 63, quad = lane >> 4, l16 = lane & 15;
    int moff = (wave >> 1) << 6, noff = (wave & 1) << 6;
    f32x4 acc[4][4];
    #pragma unroll
    for (int i = 0; i < 4; ++i)
        #pragma unroll
        for (int j = 0; j < 4; ++j) acc[i][j] = (f32x4){0.f, 0.f, 0.f, 0.f};

    int tm0 = (bm + moff) >> 4, tn0 = (bn + noff) >> 4;
    const unsigned short* pa[4];
    const unsigned short* pb[4];
    #pragma unroll
    for (int i = 0; i < 4; ++i) {
        pa[i] = Ap + (((size_t)(tm0 + i) * KT) << 9) + (lane << 3);
        pb[i] = Bp + (((size_t)(tn0 + i) * KT) << 9) + (lane << 3);
    }
    bf16x8 a0[4], b0[4], a1[4], b1[4];
    #pragma unroll
    for (int i = 0; i < 4; ++i) { a0[i] = ld_frag(pa[i]); b0[i] = ld_frag(pb[i]); }

    for (int kt = 0; kt < KT; kt += 2) {
        size_t o1 = ((size_t)(kt + 1)) << 9;
        #pragma unroll
        for (int i = 0; i < 4; ++i) { a1[i] = ld_frag(pa[i] + o1); b1[i] = ld_frag(pb[i] + o1); }
        #pragma unroll
        for (int mi = 0; mi < 4; ++mi)
            #pragma unroll
            for (int ni = 0; ni < 4; ++ni)
                acc[mi][ni] = __builtin_amdgcn_mfma_f32_16x16x32_bf16(a0[mi], b0[ni], acc[mi][ni], 0, 0, 0);
        if (kt + 2 < KT) {
            size_t o2 = ((size_t)(kt + 2)) << 9;
            #pragma unroll
            for (int i = 0; i < 4; ++i) { a0[i] = ld_frag(pa[i] + o2); b0[i] = ld_frag(pb[i] + o2); }
        }
        #pragma unroll
        for (int mi = 0; mi < 4; ++mi)
            #pragma unroll
            for (int ni = 0; ni < 4; ++ni)
                acc[mi][ni] = __builtin_amdgcn_mfma_f32_16x16x32_bf16(a1[mi], b1[ni], acc[mi][ni], 0, 0, 0);
    }
    #pragma unroll
    for (int mi = 0; mi < 4; ++mi)
        #pragma unroll
        for (int ni = 0; ni < 4; ++ni) {
            int col = bn + noff + (ni << 4) + l16;
            float wl = 0.0f;
            if (R1) wl = (col < 512) ? w0[524288 + col] : w1[524288 + col - 512];
            #pragma unroll
            for (int r2 = 0; r2 < 4; ++r2) {
                int row = bm + moff + (mi << 4) + (quad << 2) + r2;
                float v = acc[mi][ni][r2];
                if (R1) v += pxl[row] * wl;
                P[(size_t)row * 1024 + col] = v;
            }
        }
}

// ---------------- fused gather + BN + ReLU: one wave per destination row ----------------
template <bool BF16OUT>
__global__ void __launch_bounds__(256) cheb_fuse(
        const float* __restrict__ P, const int* __restrict__ off,
        const int* __restrict__ csr_a, const float* __restrict__ csr_c,
        const int* __restrict__ misc, const float* __restrict__ bias,
        const float* __restrict__ bn, float* __restrict__ Hf,
        unsigned short* __restrict__ Hb) {
    int b = (blockIdx.x * 256 + threadIdx.x) >> 6;
    int lane = threadIdx.x & 63;
    if (b >= NN) return;
    int s = off[b];
    int e = (b < NN - 1) ? off[b + 1] : misc[0];
    int c0 = lane << 3;
    float a0[4], a1[4];
    {
        float4 t0 = *(const float4*)&P[(size_t)b * 1024 + c0];
        float4 t1 = *(const float4*)&P[(size_t)b * 1024 + c0 + 4];
        a0[0] = t0.x; a0[1] = t0.y; a0[2] = t0.z; a0[3] = t0.w;
        a1[0] = t1.x; a1[1] = t1.y; a1[2] = t1.z; a1[3] = t1.w;
    }
    for (int j = s; j < e; ++j) {
        int a = csr_a[j];
        float cf = csr_c[j];
        float4 p0 = *(const float4*)&P[(size_t)a * 1024 + 512 + c0];
        float4 p1 = *(const float4*)&P[(size_t)a * 1024 + 512 + c0 + 4];
        a0[0] = fmaf(cf, p0.x, a0[0]); a0[1] = fmaf(cf, p0.y, a0[1]);
        a0[2] = fmaf(cf, p0.z, a0[2]); a0[3] = fmaf(cf, p0.w, a0[3]);
        a1[0] = fmaf(cf, p1.x, a1[0]); a1[1] = fmaf(cf, p1.y, a1[1]);
        a1[2] = fmaf(cf, p1.z, a1[2]); a1[3] = fmaf(cf, p1.w, a1[3]);
    }
    float o[8];
    #pragma unroll
    for (int i = 0; i < 8; ++i) {
        int j = c0 + i;
        float acc = (i < 4) ? a0[i] : a1[i - 4];
        float ga = bn[j], be = bn[512 + j], mn = bn[1024 + j], vr = bn[1536 + j];
        float sc = (float)(1.0 / sqrt((double)vr + 1e-5));
        float v = (acc + bias[j] - mn) * sc * ga + be;
        o[i] = v > 0.0f ? v : 0.0f;
    }
    if (BF16OUT) {
        unsigned short h[8];
        #pragma unroll
        for (int i = 0; i < 8; ++i) h[i] = f2bf(o[i]);
        *(us8*)&Hb[pk_idx(b, c0, 16)] = *(const us8*)h;   // packed for layer-2 GEMM
    } else {
        *(float4*)&Hf[(size_t)b * 512 + c0] = make_float4(o[0], o[1], o[2], o[3]);
        *(float4*)&Hf[(size_t)b * 512 + c0 + 4] = make_float4(o[4], o[5], o[6], o[7]);
    }
}

// ---------------- global max+mean pool over valid nodes per graph ----------------
__global__ void __launch_bounds__(256) pool_kernel(
        const float* __restrict__ H, const int* __restrict__ cluster,
        const int* __restrict__ batch, u32* gmaxb, float* gsum, float* gcnt) {
    int t = threadIdx.x;
    int n0 = blockIdx.x * 64;
    float m0 = 0.0f, m1 = 0.0f, s0 = 0.0f, s1 = 0.0f;
    int cntl = 0;
    int cur = batch[n0];
    for (int i = 0; i < 64; ++i) {
        int n = n0 + i;
        int bt = batch[n];
        if (bt != cur) {
            atomicMax(&gmaxb[cur * 512 + t], __float_as_uint(m0));
            atomicMax(&gmaxb[cur * 512 + t + 256], __float_as_uint(m1));
            unsafeAtomicAdd(&gsum[cur * 512 + t], s0);
            unsafeAtomicAdd(&gsum[cur * 512 + t + 256], s1);
            if (t == 0) unsafeAtomicAdd(&gcnt[cur], (float)cntl);
            m0 = m1 = s0 = s1 = 0.0f; cntl = 0; cur = bt;
        }
        if (cluster[n] == n) {
            float h0 = H[(size_t)n * 512 + t];
            float h1 = H[(size_t)n * 512 + t + 256];
            m0 = fmaxf(m0, h0); m1 = fmaxf(m1, h1);
            s0 += h0; s1 += h1;
            ++cntl;
        }
    }
    atomicMax(&gmaxb[cur * 512 + t], __float_as_uint(m0));
    atomicMax(&gmaxb[cur * 512 + t + 256], __float_as_uint(m1));
    unsafeAtomicAdd(&gsum[cur * 512 + t], s0);
    unsafeAtomicAdd(&gsum[cur * 512 + t + 256], s1);
    if (t == 0) unsafeAtomicAdd(&gcnt[cur], (float)cntl);
}

// ---------------- parallel readout MLP ----------------
// ro1: layer-1 partials. grid 64 x 512 thr; block owns k-slice of 16.
__global__ void __launch_bounds__(512) ro1(
        const u32* __restrict__ gmaxb, const float* __restrict__ gsum,
        const float* __restrict__ gcnt, const float* __restrict__ l1w,
        float* __restrict__ racc1) {
    int o = threadIdx.x;
    int k0 = blockIdx.x << 4;
    float acc[8] = {0, 0, 0, 0, 0, 0, 0, 0};
    float inv[8];
    #pragma unroll
    for (int b = 0; b < 8; ++b) inv[b] = 1.0f / fmaxf(gcnt[b], 1.0f);
    for (int kk = 0; kk < 16; ++kk) {
        int k = k0 + kk;
        float w = l1w[(size_t)k * 512 + o];
        #pragma unroll
        for (int b = 0; b < 8; ++b) {
            float g = (k < 512) ? __uint_as_float(gmaxb[b * 512 + k])
                                : gsum[b * 512 + (k - 512)] * inv[b];
            acc[b] = fmaf(g, w, acc[b]);
        }
    }
    #pragma unroll
    for (int b = 0; b < 8; ++b) unsafeAtomicAdd(&racc1[b * 512 + o], acc[b]);
}
// ro2: +bias, BN3, ReLU -> rg1
__global__ void __launch_bounds__(512) ro2(
        const float* __restrict__ racc1, const float* __restrict__ l1b,
        const float* __restrict__ bn3, float* __restrict__ rg1) {
    int o = threadIdx.x;
    float ga = bn3[o], be = bn3[512 + o], mn = bn3[1024 + o], vr = bn3[1536 + o];
    float sc = (float)(1.0 / sqrt((double)vr + 1e-5));
    float bi = l1b[o];
    #pragma unroll
    for (int b = 0; b < 8; ++b) {
        float v = (racc1[b * 512 + o] + bi - mn) * sc * ga + be;
        rg1[b * 512 + o] = v > 0.0f ? v : 0.0f;
    }
}
// ro3: layer-2 partials. grid 32 x 256 thr; block owns k-slice of 16.
__global__ void __launch_bounds__(256) ro3(
        const float* __restrict__ rg1, const float* __restrict__ l2w,
        float* __restrict__ racc2) {
    int o = threadIdx.x;
    int k0 = blockIdx.x << 4;
    float acc[8] = {0, 0, 0, 0, 0, 0, 0, 0};
    for (int kk = 0; kk < 16; ++kk) {
        int k = k0 + kk;
        float w = l2w[(size_t)k * 256 + o];
        #pragma unroll
        for (int b = 0; b < 8; ++b) acc[b] = fmaf(rg1[b * 512 + k], w, acc[b]);
    }
    #pragma unroll
    for (int b = 0; b < 8; ++b) unsafeAtomicAdd(&racc2[b * 256 + o], acc[b]);
}
// ro4: BN4+ReLU -> feature out; layer 3 + log_softmax
__global__ void __launch_bounds__(256) ro4(
        const float* __restrict__ racc2, const float* __restrict__ l2b,
        const float* __restrict__ bn4, const float* __restrict__ l3w,
        const float* __restrict__ l3b, float* __restrict__ out) {
    __shared__ float G2[8 * 256];
    int o = threadIdx.x;
    {
        float ga = bn4[o], be = bn4[256 + o], mn = bn4[512 + o], vr = bn4[768 + o];
        float sc = (float)(1.0 / sqrt((double)vr + 1e-5));
        float bi = l2b[o];
        #pragma unroll
        for (int b = 0; b < 8; ++b) {
            float v = (racc2[b * 256 + o] + bi - mn) * sc * ga + be;
            v = v > 0.0f ? v : 0.0f;
            G2[b * 256 + o] = v;
            out[32 + b * 256 + o] = v;
        }
    }
    __syncthreads();
    if (o < 8) {
        int b = o;
        float r[4];
        #pragma unroll
        for (int c = 0; c < 4; ++c) {
            float acc = l3b[c];
            for (int k = 0; k < 256; ++k) acc += G2[b * 256 + k] * l3w[k * 4 + c];
            r[c] = acc > 0.0f ? acc : 0.0f;
        }
        float mx = fmaxf(fmaxf(r[0], r[1]), fmaxf(r[2], r[3]));
        float s = 0.0f;
        #pragma unroll
        for (int c = 0; c < 4; ++c) s += expf(r[c] - mx);
        float lse = mx + logf(s);
        #pragma unroll
        for (int c = 0; c < 4; ++c) out[b * 4 + c] = r[c] - lse;
    }
}

extern "C" void kernel_launch(void* const* d_in, const int* in_sizes, int n_in,
                              void* d_out, int out_size, void* d_ws, size_t ws_size,
                              hipStream_t stream) {
    const float* x      = (const float*)d_in[0];
    const int*   ei     = (const int*)d_in[1];
    const int*   batch  = (const int*)d_in[2];
    const float* pool_w = (const float*)d_in[3];
    const float* pool_b = (const float*)d_in[4];
    const float* c1_w0  = (const float*)d_in[5];
    const float* c1_w1  = (const float*)d_in[6];
    const float* c1_b   = (const float*)d_in[7];
    const float* c2_w0  = (const float*)d_in[8];
    const float* c2_w1  = (const float*)d_in[9];
    const float* c2_b   = (const float*)d_in[10];
    const float* bn1    = (const float*)d_in[11];
    const float* bn2    = (const float*)d_in[12];
    const float* bn3    = (const float*)d_in[13];
    const float* bn4    = (const float*)d_in[14];
    const float* l1w    = (const float*)d_in[15];
    const float* l1b    = (const float*)d_in[16];
    const float* l2w    = (const float*)d_in[17];
    const float* l2b    = (const float*)d_in[18];
    const float* l3w    = (const float*)d_in[19];
    const float* l3b    = (const float*)d_in[20];
    float* out = (float*)d_out;
    char* ws = (char*)d_ws;

    double* a_d   = (double*)(ws + WS_A_D);
    double* b_d   = (double*)(ws + WS_B_D);
    u32*    emax  = (u32*)(ws + WS_EMAX);
    double* ssum  = (double*)(ws + WS_SSUM);
    double* exd   = (double*)(ws + WS_EXD);
    u32*    cin   = (u32*)(ws + WS_CIN);
    u64*    key   = (u64*)(ws + WS_KEY);
    u64*    best  = (u64*)(ws + WS_BEST);
    u32*    used  = (u32*)(ws + WS_USED);
    int*    curp  = (int*)(ws + WS_CUR);
    int*    act0  = (int*)(ws + WS_ACT0);
    int*    act1  = (int*)(ws + WS_ACT1);
    unsigned short* bthi = (unsigned short*)(ws + WS_BTHI);
    float*  pxl   = (float*)(ws + WS_PXL);
    u32*    ht    = (u32*)(ws + WS_HT);
    float*  racc1 = (float*)(ws + WS_RACC1);
    float*  racc2 = (float*)(ws + WS_RACC2);
    float*  rg1   = (float*)(ws + WS_RG1);
    float*  score = (float*)(ws + WS_SCORE);
    int*    csr_a = (int*)(ws + WS_CSRA);
    int*    sel   = (int*)(ws + WS_SEL);
    float*  csr_c = (float*)(ws + WS_CSRC);
    int*    clus  = (int*)(ws + WS_CLUST);
    int*    other = (int*)(ws + WS_OTHER);
    float*  nsc   = (float*)(ws + WS_NSC);
    int*    ce_u  = (int*)(ws + WS_CEU);
    int*    ce_v  = (int*)(ws + WS_CEV);
    u32*    deg   = (u32*)(ws + WS_DEG);
    int*    off   = (int*)(ws + WS_OFF);
    float*  dis   = (float*)(ws + WS_DIS);
    int*    misc  = (int*)(ws + WS_MISC);
    u32*    gmaxb = (u32*)(ws + WS_GMAX);
    float*  gsum  = (float*)(ws + WS_GSUM);
    float*  gcnt  = (float*)(ws + WS_GCNT);
    float*  P     = (float*)(ws + WS_P);
    unsigned short* ax = (unsigned short*)(ws + WS_H);   // packed Ax bf16 (gemm1 A)
    unsigned short* hb = (unsigned short*)(ws + WS_H);   // packed Hb bf16 (gemm2 A)
    float*  H     = (float*)(ws + WS_H);                 // final H fp32

    // ---- phase A: scores, matching, coarse graph ----
    init_misc<<<NN / 256, 256, 0, stream>>>(emax, ssum, deg, misc, gmaxb, gsum, gcnt,
                                            best, used);
    node_dots<<<NN / 4, 256, 0, stream>>>(x, pool_w, a_d, b_d);
    edge_p1<<<NE / 256, 256, 0, stream>>>(ei, a_d, b_d, pool_b, exd, emax);
    edge_p2<<<NE / 256, 256, 0, stream>>>(ei, exd, emax, ssum);
    edge_p3<<<NE / 256, 256, 0, stream>>>(ei, exd, ssum, score, key, sel, act0, best);

    {
        static const int gr[9] = {512, 512, 256, 128, 64, 32, 16, 8, 8};
        int* acts[2] = {act0, act1};
        for (int r = 0; r < 8; ++r) {
            int c = r & 1, n = 1 - c;
            mk_sel<<<gr[r], 256, 0, stream>>>(key, ei, acts[c], &misc[1 + c],
                                              &misc[1 + n], best, used, sel);
            mk_compact<<<gr[r], 256, 0, stream>>>(ei, acts[c], &misc[1 + c],
                                                  acts[n], &misc[1 + n], best, used);
            mk_min<<<gr[r + 1], 256, 0, stream>>>(key, ei, acts[n], &misc[1 + n], best);
        }
        match_fin<<<1, 1024, 0, stream>>>(key, ei, sel, best, used,
                                          act0, act1, &misc[1]);
    }

    cluster_init<<<NN / 256, 256, 0, stream>>>(clus, other, nsc, cin);
    apply_sel<<<NE / 256, 256, 0, stream>>>(ei, sel, score, clus, other, nsc);
    init_ht<<<HTS / 256, 256, 0, stream>>>(ht);
    coarse_build<<<NE / 256, 256, 0, stream>>>(ei, clus, ht, misc, ce_u, ce_v, deg, cin);
    dis_kernel<<<NN / 256, 256, 0, stream>>>(deg, dis, racc1, racc2);
    scan_kernel<<<1, 1024, 0, stream>>>(cin, off, curp);
    csr_scatter<<<NE / 256, 256, 0, stream>>>(ce_u, ce_v, dis, misc, curp, csr_a, csr_c);

    // ---- phase B: ChebConv layers (packed-fragment MFMA + fused gather/BN/ReLU) ----
    conv_b<<<dim3(4, 128), 256, 0, stream>>>(c1_w0, c1_w1, bthi, 32);
    conv_a1<<<NN, 128, 0, stream>>>(x, clus, other, nsc, ax, pxl);
    gemm_pk<true><<<2048, 256, 0, stream>>>(ax, bthi, P, 32, pxl, c1_w0, c1_w1);
    cheb_fuse<true><<<NN / 4, 256, 0, stream>>>(P, off, csr_a, csr_c, misc, c1_b, bn1,
                                                nullptr, hb);

    conv_b<<<dim3(4, 64), 256, 0, stream>>>(c2_w0, c2_w1, bthi, 16);
    gemm_pk<false><<<2048, 256, 0, stream>>>(hb, bthi, P, 16, nullptr, nullptr, nullptr);
    cheb_fuse<false><<<NN / 4, 256, 0, stream>>>(P, off, csr_a, csr_c, misc, c2_b, bn2,
                                                 H, nullptr);

    pool_kernel<<<NN / 64, 256, 0, stream>>>(H, clus, batch, gmaxb, gsum, gcnt);

    // ---- parallel readout ----
    ro1<<<64, 512, 0, stream>>>(gmaxb, gsum, gcnt, l1w, racc1);
    ro2<<<1, 512, 0, stream>>>(racc1, l1b, bn3, rg1);
    ro3<<<32, 256, 0, stream>>>(rg1, l2w, racc2);
    ro4<<<1, 256, 0, stream>>>(racc2, l2b, bn4, l3w, l3b, out);
}

// Round 9
// 871.754 us; speedup vs baseline: 7.7126x; 1.0224x over previous
//
#include <hip/hip_runtime.h>
#include <hip/hip_bf16.h>
#include <cstdint>
#include <cmath>

typedef unsigned int u32;
typedef unsigned long long u64;
typedef float f32x4 __attribute__((ext_vector_type(4)));
typedef __bf16 bf16x8 __attribute__((ext_vector_type(8)));
typedef unsigned short us8 __attribute__((ext_vector_type(8)));
typedef unsigned short us4 __attribute__((ext_vector_type(4)));

#define NN 32768
#define NE 131072
#define FIN 1025
#define HTS 262144
#define HTM (HTS - 1)

// ---------------- workspace layout (byte offsets) ----------------
#define WS_A_D    0ul          // double[NN]
#define WS_B_D    262144ul     // double[NN]
#define WS_EMAX   524288ul     // u32[NN]
#define WS_SSUM   655360ul     // double[NN]
#define WS_EXD    917504ul     // double[NE]
#define WS_CIN    917504ul     // u32[NN]  overlays EXD head
#define WS_KEY    1966080ul    // u64[NE]
#define WS_BEST   3014656ul    // u64[NN]
#define WS_USED   3276800ul    // u32[NN]
#define WS_CUR    3276800ul    // int[NN]  overlays USED (dead after match_fin)
#define WS_ACT0   3407872ul    // int[NE]
#define WS_ACT1   3932160ul    // int[NE]   (zone ends 4456448)
#define WS_BTHI   0ul          // ushort[1024*1024] packed frag order (phase B)
#define WS_PXL    4194304ul    // float[NN]                            (phase B)
#define WS_HT     1966080ul    // u32[HTS] overlays KEY (dead after coarse_build)
// readout scratch (phase B, overlays dead HT tail):
#define WS_RACC1  2097152ul    // float[8*512]
#define WS_RACC2  2113536ul    // float[8*256]
#define WS_RG1    2121728ul    // float[8*512]
// persistent:
#define WS_SCORE  4456448ul    // float[NE]
#define WS_CSRA   4456448ul    // int[NE]  overlays SCORE (dead after apply_sel)
#define WS_SEL    4980736ul    // int[NE]
#define WS_CSRC   4980736ul    // float[NE] overlays SEL (dead after apply_sel)
#define WS_CLUST  5505024ul    // int[NN]
#define WS_OTHER  5636096ul    // int[NN]
#define WS_NSC    5767168ul    // float[NN]
#define WS_CEU    5898240ul    // int[NE]
#define WS_CEV    6422528ul    // int[NE]
#define WS_DEG    6946816ul    // u32[NN]
#define WS_OFF    6946816ul    // int[NN]  overlays DEG
#define WS_DIS    7077888ul    // float[NN]
#define WS_MISC   7208960ul    // int[64]
#define WS_GMAX   7209216ul    // u32[8*512]
#define WS_GSUM   7225600ul    // float[8*512]
#define WS_GCNT   7241984ul    // float[64]
#define WS_P      7242240ul    // float[NN*1024]
#define WS_H      141459968ul  // Ax/Hb bf16 packed -> H f32[NN*512]

__device__ __forceinline__ u32 enc_f(float f) {
    u32 b = __float_as_uint(f);
    return (b & 0x80000000u) ? ~b : (b | 0x80000000u);
}
__device__ __forceinline__ float dec_f(u32 m) {
    return (m & 0x80000000u) ? __uint_as_float(m ^ 0x80000000u) : __uint_as_float(~m);
}
__device__ __forceinline__ double wave_sum(double v) {
    #pragma unroll
    for (int off = 32; off > 0; off >>= 1) v += __shfl_down(v, off, 64);
    return v;
}
__device__ __forceinline__ unsigned short f2bf(float v) {   // RNE f32->bf16
    u32 b = __float_as_uint(v);
    u32 r = b + 0x7FFFu + ((b >> 16) & 1u);
    return (unsigned short)(r >> 16);
}
__device__ __forceinline__ bf16x8 ld_frag(const unsigned short* p) {
    union { us8 u; bf16x8 b; } t;
    t.u = *(const us8*)p;
    return t.b;
}
// async global->LDS, 16B/lane; lds base must be wave-uniform (lane lands at base+lane*16)
__device__ __forceinline__ void dma16(unsigned short* lds, const unsigned short* g) {
    __builtin_amdgcn_global_load_lds((const __attribute__((address_space(1))) u32*)g,
                                     (__attribute__((address_space(3))) u32*)lds, 16, 0, 0);
}

// ---------------- init ----------------
__global__ void init_misc(u32* emax, double* ssum, u32* deg,
                          int* misc, u32* gmaxb, float* gsum, float* gcnt,
                          u64* best, u32* used) {
    int i = blockIdx.x * 256 + threadIdx.x;
    if (i < NN) { emax[i] = 0u; ssum[i] = 0.0; deg[i] = 0u; best[i] = ~0ull; used[i] = 0u; }
    if (i < 4096) { gmaxb[i] = 0u; gsum[i] = 0.0f; }
    if (i < 64) { misc[i] = (i == 1) ? NE : 0; gcnt[i] = 0.0f; }
}
__global__ void init_ht(u32* ht) {
    int i = blockIdx.x * 256 + threadIdx.x;
    if (i < HTS) ht[i] = 0xFFFFFFFFu;
}

// ---------------- per-node dots with pool_w halves (double accum) ----------------
__global__ void node_dots(const float* __restrict__ x, const float* __restrict__ pw,
                          double* a_d, double* b_d) {
    int wave = (blockIdx.x * blockDim.x + threadIdx.x) >> 6;
    int lane = threadIdx.x & 63;
    if (wave >= NN) return;
    const float* xr = x + (size_t)wave * FIN;
    double s0 = 0.0, s1 = 0.0;
    for (int f = lane; f < FIN; f += 64) {
        double xv = (double)xr[f];
        s0 += xv * (double)pw[f];
        s1 += xv * (double)pw[FIN + f];
    }
    s0 = wave_sum(s0); s1 = wave_sum(s1);
    if (lane == 0) { a_d[wave] = s0; b_d[wave] = s1; }
}

// ---------------- edge score pipeline ----------------
__global__ void edge_p1(const int* __restrict__ ei, const double* __restrict__ a_d,
                        const double* __restrict__ b_d, const float* __restrict__ pb,
                        double* e_d, u32* emax) {
    int k = blockIdx.x * 256 + threadIdx.x;
    if (k >= NE) return;
    int u = ei[k], v = ei[NE + k];
    double e = a_d[u] + b_d[v] + (double)pb[0];
    e_d[k] = e;
    atomicMax(&emax[v], enc_f((float)e));
}
__global__ void edge_p2(const int* __restrict__ ei, double* e_d,
                        const u32* __restrict__ emax, double* ssum) {
    int k = blockIdx.x * 256 + threadIdx.x;
    if (k >= NE) return;
    int v = ei[NE + k];
    float mf = dec_f(emax[v]);
    double ex = exp(e_d[k] - (double)mf);
    e_d[k] = ex;
    unsafeAtomicAdd(&ssum[v], ex);
}
__global__ void edge_p3(const int* __restrict__ ei, const double* __restrict__ e_d,
                        const double* __restrict__ ssum, float* score, u64* key,
                        int* sel, int* act0, u64* best) {
    int k = blockIdx.x * 256 + threadIdx.x;
    if (k >= NE) return;
    int u = ei[k], v = ei[NE + k];
    float sc = (float)(e_d[k] / ssum[v] + 0.5);
    score[k] = sc;
    u32 m = enc_f(sc);
    u64 kk = ((u64)(m ^ 0xFFFFFFFFu) << 32) | (u32)k;  // low = high score, tie: low idx
    key[k] = kk;
    sel[k] = 0;
    act0[k] = k;
    atomicMin(&best[u], kk);
    atomicMin(&best[v], kk);
}

// ---------------- flattened dominant-edge peeling rounds ----------------
__global__ void mk_sel(const u64* __restrict__ key, const int* __restrict__ ei,
                       const int* __restrict__ act, const int* __restrict__ cntp,
                       int* ncntp, const u64* __restrict__ best,
                       u32* used, int* sel) {
    int cnt = cntp[0];
    int stride = gridDim.x * blockDim.x;
    int gid = blockIdx.x * blockDim.x + threadIdx.x;
    if (gid == 0) ncntp[0] = 0;
    for (int i = gid; i < cnt; i += stride) {
        int e = act[i];
        u64 k = key[e];
        int a = ei[e], b = ei[NE + e];
        if (best[a] == k && best[b] == k) { sel[e] = 1; used[a] = 1u; used[b] = 1u; }
    }
}
__global__ void mk_compact(const int* __restrict__ ei, const int* __restrict__ act,
                           const int* __restrict__ cntp, int* nxt, int* ncntp,
                           u64* best, const u32* __restrict__ used) {
    int cnt = cntp[0];
    int stride = gridDim.x * blockDim.x;
    for (int i = blockIdx.x * blockDim.x + threadIdx.x; i < cnt; i += stride) {
        int e = act[i];
        int a = ei[e], b = ei[NE + e];
        best[a] = ~0ull; best[b] = ~0ull;
        bool live = !(used[a] | used[b]);
        u64 mask = __ballot(live);
        if (mask) {
            int lane = threadIdx.x & 63;
            int leader = __ffsll((unsigned long long)mask) - 1;
            int base = 0;
            if (lane == leader) base = atomicAdd(ncntp, __popcll(mask));
            base = __shfl(base, leader, 64);
            if (live) nxt[base + __popcll(mask & ((1ull << lane) - 1ull))] = e;
        }
    }
}
__global__ void mk_min(const u64* __restrict__ key, const int* __restrict__ ei,
                       const int* __restrict__ act, const int* __restrict__ cntp,
                       u64* best) {
    int cnt = cntp[0];
    int stride = gridDim.x * blockDim.x;
    for (int i = blockIdx.x * blockDim.x + threadIdx.x; i < cnt; i += stride) {
        int e = act[i];
        u64 k = key[e];
        atomicMin(&best[ei[e]], k);
        atomicMin(&best[ei[NE + e]], k);
    }
}
__global__ void __launch_bounds__(1024) match_fin(
        const u64* __restrict__ key, const int* __restrict__ ei,
        int* sel, u64* best, u32* used,
        int* listA, int* listB, const int* __restrict__ cntp) {
    int tid = threadIdx.x;
    int cnt = cntp[0];
    int* cur = listA; int* nxt = listB;
    __shared__ int s_n;
    for (int round = 0; round < 4096 && cnt > 0; ++round) {
        for (int i = tid; i < cnt; i += 1024) {
            int e = cur[i]; u64 k = key[e];
            atomicMin(&best[ei[e]], k);
            atomicMin(&best[ei[NE + e]], k);
        }
        __syncthreads();
        for (int i = tid; i < cnt; i += 1024) {
            int e = cur[i]; u64 k = key[e];
            int a = ei[e], b = ei[NE + e];
            if (best[a] == k && best[b] == k) { sel[e] = 1; used[a] = 1u; used[b] = 1u; }
        }
        if (tid == 0) s_n = 0;
        __syncthreads();
        for (int i = tid; i < cnt; i += 1024) {
            int e = cur[i];
            int a = ei[e], b = ei[NE + e];
            best[a] = ~0ull; best[b] = ~0ull;
            if (!(used[a] | used[b])) {
                int idx = atomicAdd(&s_n, 1);
                nxt[idx] = e;
            }
        }
        __syncthreads();
        cnt = s_n;
        int* t = cur; cur = nxt; nxt = t;
        __syncthreads();
    }
}

__global__ void cluster_init(int* cluster, int* other, float* nscore, u32* cin) {
    int n = blockIdx.x * 256 + threadIdx.x;
    if (n >= NN) return;
    cluster[n] = n; other[n] = -1; nscore[n] = 1.0f; cin[n] = 0u;
}
__global__ void apply_sel(const int* __restrict__ ei, const int* __restrict__ sel,
                          const float* __restrict__ score,
                          int* cluster, int* other, float* nscore) {
    int e = blockIdx.x * 256 + threadIdx.x;
    if (e >= NE) return;
    if (sel[e] != 1) return;
    int u = ei[e], v = ei[NE + e];
    int rep = min(u, v);
    cluster[u] = rep; cluster[v] = rep;
    if (u != v) other[rep] = u + v - rep;
    nscore[rep] = score[e];
}

// ---------------- coarse graph: dedup (cu,cv) pairs via hash set ----------------
__global__ void coarse_build(const int* __restrict__ ei, const int* __restrict__ cluster,
                             u32* ht, int* misc, int* ce_u, int* ce_v, u32* deg,
                             u32* cin) {
    int e = blockIdx.x * 256 + threadIdx.x;
    if (e >= NE) return;
    int cu = cluster[ei[e]], cv = cluster[ei[NE + e]];
    if (cu == cv) return;
    u32 k = (u32)cu * 32768u + (u32)cv;
    u32 h = ((k * 2654435761u) >> 12) & HTM;
    while (true) {
        u32 old = atomicCAS(&ht[h], 0xFFFFFFFFu, k);
        if (old == 0xFFFFFFFFu) {
            int idx = atomicAdd(&misc[0], 1);
            ce_u[idx] = cu; ce_v[idx] = cv;
            atomicAdd(&deg[cu], 1u);
            atomicAdd(&cin[cv], 1u);
            break;
        }
        if (old == k) break;
        h = (h + 1) & HTM;
    }
}
// also zeroes readout partial-sum buffers (HT region dead by now)
__global__ void dis_kernel(const u32* __restrict__ deg, float* dis,
                           float* racc1, float* racc2) {
    int n = blockIdx.x * 256 + threadIdx.x;
    if (n >= NN) return;
    u32 d = deg[n];
    dis[n] = d ? (float)(1.0 / sqrt((double)d)) : 0.0f;
    if (n < 4096) racc1[n] = 0.0f;
    if (n < 2048) racc2[n] = 0.0f;
}

// ---------------- CSR build: exclusive scan of cin -> off, cur ----------------
__global__ void __launch_bounds__(1024) scan_kernel(const u32* __restrict__ cin,
                                                    int* off, int* cur) {
    __shared__ int part[1024];
    int t = threadIdx.x;
    int base = t << 5;
    int loc[32];
    int s = 0;
    #pragma unroll
    for (int i = 0; i < 32; ++i) { loc[i] = s; s += (int)cin[base + i]; }
    part[t] = s;
    __syncthreads();
    for (int d = 1; d < 1024; d <<= 1) {
        int v = (t >= d) ? part[t - d] : 0;
        __syncthreads();
        if (t >= d) part[t] += v;
        __syncthreads();
    }
    int pre = (t == 0) ? 0 : part[t - 1];
    #pragma unroll
    for (int i = 0; i < 32; ++i) {
        int v = pre + loc[i];
        off[base + i] = v;
        cur[base + i] = v;
    }
}
__global__ void csr_scatter(const int* __restrict__ ce_u, const int* __restrict__ ce_v,
                            const float* __restrict__ dis, const int* __restrict__ misc,
                            int* cur, int* csr_a, float* csr_c) {
    int e = blockIdx.x * 256 + threadIdx.x;
    if (e >= misc[0]) return;
    int a = ce_u[e], b = ce_v[e];
    int pos = atomicAdd(&cur[b], 1);
    csr_a[pos] = a;
    csr_c[pos] = -dis[a] * dis[b];
}

// ---- packed fragment index: row r, col k -> ushort offset ----
__device__ __forceinline__ size_t pk_idx(int r, int k, int KT) {
    return ((((size_t)(r >> 4) * KT + (k >> 5)) << 6) + (((k >> 3) & 3) << 4) + (r & 15)) << 3;
}

// ---------------- pre-gather px -> packed bf16 Ax, pxlast[NN] (col 1024) ----------------
// One block per 16-row tile: writes are contiguous 1024B per (tile,kt) per wave.
__global__ void __launch_bounds__(256) conv_a1(
        const float* __restrict__ x, const int* __restrict__ clus,
        const int* __restrict__ other, const float* __restrict__ nsc,
        unsigned short* __restrict__ Abf, float* __restrict__ pxl) {
    int tile = blockIdx.x;
    int t = threadIdx.x;
    int wave = t >> 6, lane = t & 63;
    int l16 = lane & 15, quad = lane >> 4;
    int row = (tile << 4) + l16;
    bool valid = (clus[row] == row);
    int o = other[row];
    float s = nsc[row];
    const float* xr = x + (size_t)row * FIN;
    const float* xo = x + (size_t)(o >= 0 ? o : row) * FIN;
    for (int kt = wave; kt < 32; kt += 4) {
        int c0 = (kt << 5) + (quad << 3);
        unsigned short h[8];
        #pragma unroll
        for (int j = 0; j < 8; ++j) {
            float v = 0.0f;
            if (valid) {
                v = xr[c0 + j];
                if (o >= 0) v += xo[c0 + j];
                v *= s;
            }
            h[j] = f2bf(v);
        }
        *(us8*)&Abf[((((size_t)tile << 5) + kt) << 9) + ((size_t)lane << 3)] = *(const us8*)h;
    }
    if (t < 16) {
        int r2 = (tile << 4) + t;
        bool v2 = (clus[r2] == r2);
        int o2 = other[r2];
        float v = 0.0f;
        if (v2) {
            v = x[(size_t)r2 * FIN + 1024];
            if (o2 >= 0) v += x[(size_t)o2 * FIN + 1024];
            v *= nsc[r2];
        }
        pxl[r2] = v;
    }
}

// ---------------- weight transpose -> packed bf16 Bt ----------------
__global__ void conv_b(const float* __restrict__ B0, const float* __restrict__ B1,
                       unsigned short* __restrict__ Bp, int KT) {
    int n = blockIdx.x * 256 + threadIdx.x;
    int k0 = blockIdx.y * 8;
    unsigned short h[8];
    #pragma unroll
    for (int j = 0; j < 8; ++j) {
        int k = k0 + j;
        float v = (n < 512) ? B0[(size_t)k * 512 + n] : B1[(size_t)k * 512 + (n - 512)];
        h[j] = f2bf(v);
    }
    *(us8*)&Bp[pk_idx(n, k0, KT)] = *(const us8*)h;
}

// ---------------- packed-fragment bf16 MFMA GEMM with LDS DMA double-buffer ----------------
// 128x128 tile, 4 waves. Per kt: 16 frags (8 A + 8 B) DMA'd via global_load_lds
// (each fetched ONCE per block), ds_read_b128 -> 16 MFMA per wave. m97-style pipeline.
template <bool R1>
__global__ void __launch_bounds__(256, 4) gemm_pk(
        const unsigned short* __restrict__ Ap, const unsigned short* __restrict__ Bp,
        float* __restrict__ P, int KT,
        const float* __restrict__ pxl, const float* __restrict__ w0,
        const float* __restrict__ w1) {
    __shared__ unsigned short L[2][8192];   // 16 frags x 512 ushorts per buffer
    int tid = threadIdx.x;
    int bid = blockIdx.x;
    int loc = bid >> 3;
    int bn = (loc & 7) << 7;
    int bm = ((((bid & 7) << 5) | (loc >> 3))) << 7;
    int wave = tid >> 6, lane = tid & 63, quad = lane >> 4, l16 = lane & 15;
    int moff = (wave >> 1) << 6, noff = (wave & 1) << 6;
    f32x4 acc[4][4];
    #pragma unroll
    for (int i = 0; i < 4; ++i)
        #pragma unroll
        for (int j = 0; j < 4; ++j) acc[i][j] = (f32x4){0.f, 0.f, 0.f, 0.f};

    // DMA: wave loads frags f = wave*4+q (f<8: A tile (bm>>4)+f; else B tile (bn>>4)+f-8)
    const unsigned short* src[4];
    unsigned short* dst[4];
    #pragma unroll
    for (int q = 0; q < 4; ++q) {
        int f = (wave << 2) + q;
        int tg = (f < 8) ? ((bm >> 4) + f) : ((bn >> 4) + (f - 8));
        src[q] = ((f < 8) ? Ap : Bp) + (((size_t)tg * KT) << 9) + ((size_t)lane << 3);
        dst[q] = &L[0][(size_t)f << 9];
    }
    const unsigned short* ra = &L[0][(size_t)(wave >> 1) << 11];
    const unsigned short* rb = &L[0][4096 + ((size_t)(wave & 1) << 11)];

    #pragma unroll
    for (int q = 0; q < 4; ++q) dma16(dst[q], src[q]);
    __syncthreads();

    int cur = 0;
    for (int kt = 0; kt < KT; ++kt) {
        if (kt + 1 < KT) {
            int nb = (cur ^ 1) * 8192;
            size_t go = ((size_t)(kt + 1)) << 9;
            #pragma unroll
            for (int q = 0; q < 4; ++q) dma16(dst[q] + nb, src[q] + go);
        }
        const unsigned short* la = ra + cur * 8192;
        const unsigned short* lb = rb + cur * 8192;
        bf16x8 af[4], bf[4];
        #pragma unroll
        for (int i = 0; i < 4; ++i) {
            af[i] = ld_frag(la + ((size_t)i << 9) + (lane << 3));
            bf[i] = ld_frag(lb + ((size_t)i << 9) + (lane << 3));
        }
        #pragma unroll
        for (int mi = 0; mi < 4; ++mi)
            #pragma unroll
            for (int ni = 0; ni < 4; ++ni)
                acc[mi][ni] = __builtin_amdgcn_mfma_f32_16x16x32_bf16(af[mi], bf[ni], acc[mi][ni], 0, 0, 0);
        __syncthreads();
        cur ^= 1;
    }
    // epilogue: C/D row=quad*4+r2, col=l16; optional rank-1 (column 1024 of A/B)
    #pragma unroll
    for (int mi = 0; mi < 4; ++mi)
        #pragma unroll
        for (int ni = 0; ni < 4; ++ni) {
            int col = bn + noff + (ni << 4) + l16;
            float wl = 0.0f;
            if (R1) wl = (col < 512) ? w0[524288 + col] : w1[524288 + col - 512];
            #pragma unroll
            for (int r2 = 0; r2 < 4; ++r2) {
                int row = bm + moff + (mi << 4) + (quad << 2) + r2;
                float v = acc[mi][ni][r2];
                if (R1) v += pxl[row] * wl;
                P[(size_t)row * 1024 + col] = v;
            }
        }
}

// ---------------- fused gather + BN + ReLU: one wave per destination row ----------------
template <bool BF16OUT>
__global__ void __launch_bounds__(256) cheb_fuse(
        const float* __restrict__ P, const int* __restrict__ off,
        const int* __restrict__ csr_a, const float* __restrict__ csr_c,
        const int* __restrict__ misc, const float* __restrict__ bias,
        const float* __restrict__ bn, float* __restrict__ Hf,
        unsigned short* __restrict__ Hb) {
    int b = (blockIdx.x * 256 + threadIdx.x) >> 6;
    int lane = threadIdx.x & 63;
    if (b >= NN) return;
    int s = off[b];
    int e = (b < NN - 1) ? off[b + 1] : misc[0];
    int c0 = lane << 3;
    float a0[4], a1[4];
    {
        float4 t0 = *(const float4*)&P[(size_t)b * 1024 + c0];
        float4 t1 = *(const float4*)&P[(size_t)b * 1024 + c0 + 4];
        a0[0] = t0.x; a0[1] = t0.y; a0[2] = t0.z; a0[3] = t0.w;
        a1[0] = t1.x; a1[1] = t1.y; a1[2] = t1.z; a1[3] = t1.w;
    }
    for (int j = s; j < e; ++j) {
        int a = csr_a[j];
        float cf = csr_c[j];
        float4 p0 = *(const float4*)&P[(size_t)a * 1024 + 512 + c0];
        float4 p1 = *(const float4*)&P[(size_t)a * 1024 + 512 + c0 + 4];
        a0[0] = fmaf(cf, p0.x, a0[0]); a0[1] = fmaf(cf, p0.y, a0[1]);
        a0[2] = fmaf(cf, p0.z, a0[2]); a0[3] = fmaf(cf, p0.w, a0[3]);
        a1[0] = fmaf(cf, p1.x, a1[0]); a1[1] = fmaf(cf, p1.y, a1[1]);
        a1[2] = fmaf(cf, p1.z, a1[2]); a1[3] = fmaf(cf, p1.w, a1[3]);
    }
    float o[8];
    #pragma unroll
    for (int i = 0; i < 8; ++i) {
        int j = c0 + i;
        float acc = (i < 4) ? a0[i] : a1[i - 4];
        float ga = bn[j], be = bn[512 + j], mn = bn[1024 + j], vr = bn[1536 + j];
        float sc = (float)(1.0 / sqrt((double)vr + 1e-5));
        float v = (acc + bias[j] - mn) * sc * ga + be;
        o[i] = v > 0.0f ? v : 0.0f;
    }
    if (BF16OUT) {
        unsigned short h[8];
        #pragma unroll
        for (int i = 0; i < 8; ++i) h[i] = f2bf(o[i]);
        *(us8*)&Hb[pk_idx(b, c0, 16)] = *(const us8*)h;   // packed for layer-2 GEMM
    } else {
        *(float4*)&Hf[(size_t)b * 512 + c0] = make_float4(o[0], o[1], o[2], o[3]);
        *(float4*)&Hf[(size_t)b * 512 + c0 + 4] = make_float4(o[4], o[5], o[6], o[7]);
    }
}

// ---------------- global max+mean pool over valid nodes per graph ----------------
__global__ void __launch_bounds__(256) pool_kernel(
        const float* __restrict__ H, const int* __restrict__ cluster,
        const int* __restrict__ batch, u32* gmaxb, float* gsum, float* gcnt) {
    int t = threadIdx.x;
    int n0 = blockIdx.x * 64;
    float m0 = 0.0f, m1 = 0.0f, s0 = 0.0f, s1 = 0.0f;
    int cntl = 0;
    int cur = batch[n0];
    for (int i = 0; i < 64; ++i) {
        int n = n0 + i;
        int bt = batch[n];
        if (bt != cur) {
            atomicMax(&gmaxb[cur * 512 + t], __float_as_uint(m0));
            atomicMax(&gmaxb[cur * 512 + t + 256], __float_as_uint(m1));
            unsafeAtomicAdd(&gsum[cur * 512 + t], s0);
            unsafeAtomicAdd(&gsum[cur * 512 + t + 256], s1);
            if (t == 0) unsafeAtomicAdd(&gcnt[cur], (float)cntl);
            m0 = m1 = s0 = s1 = 0.0f; cntl = 0; cur = bt;
        }
        if (cluster[n] == n) {
            float h0 = H[(size_t)n * 512 + t];
            float h1 = H[(size_t)n * 512 + t + 256];
            m0 = fmaxf(m0, h0); m1 = fmaxf(m1, h1);
            s0 += h0; s1 += h1;
            ++cntl;
        }
    }
    atomicMax(&gmaxb[cur * 512 + t], __float_as_uint(m0));
    atomicMax(&gmaxb[cur * 512 + t + 256], __float_as_uint(m1));
    unsafeAtomicAdd(&gsum[cur * 512 + t], s0);
    unsafeAtomicAdd(&gsum[cur * 512 + t + 256], s1);
    if (t == 0) unsafeAtomicAdd(&gcnt[cur], (float)cntl);
}

// ---------------- parallel readout MLP ----------------
__global__ void __launch_bounds__(512) ro1(
        const u32* __restrict__ gmaxb, const float* __restrict__ gsum,
        const float* __restrict__ gcnt, const float* __restrict__ l1w,
        float* __restrict__ racc1) {
    int o = threadIdx.x;
    int k0 = blockIdx.x << 4;
    float acc[8] = {0, 0, 0, 0, 0, 0, 0, 0};
    float inv[8];
    #pragma unroll
    for (int b = 0; b < 8; ++b) inv[b] = 1.0f / fmaxf(gcnt[b], 1.0f);
    for (int kk = 0; kk < 16; ++kk) {
        int k = k0 + kk;
        float w = l1w[(size_t)k * 512 + o];
        #pragma unroll
        for (int b = 0; b < 8; ++b) {
            float g = (k < 512) ? __uint_as_float(gmaxb[b * 512 + k])
                                : gsum[b * 512 + (k - 512)] * inv[b];
            acc[b] = fmaf(g, w, acc[b]);
        }
    }
    #pragma unroll
    for (int b = 0; b < 8; ++b) unsafeAtomicAdd(&racc1[b * 512 + o], acc[b]);
}
__global__ void __launch_bounds__(512) ro2(
        const float* __restrict__ racc1, const float* __restrict__ l1b,
        const float* __restrict__ bn3, float* __restrict__ rg1) {
    int o = threadIdx.x;
    float ga = bn3[o], be = bn3[512 + o], mn = bn3[1024 + o], vr = bn3[1536 + o];
    float sc = (float)(1.0 / sqrt((double)vr + 1e-5));
    float bi = l1b[o];
    #pragma unroll
    for (int b = 0; b < 8; ++b) {
        float v = (racc1[b * 512 + o] + bi - mn) * sc * ga + be;
        rg1[b * 512 + o] = v > 0.0f ? v : 0.0f;
    }
}
__global__ void __launch_bounds__(256) ro3(
        const float* __restrict__ rg1, const float* __restrict__ l2w,
        float* __restrict__ racc2) {
    int o = threadIdx.x;
    int k0 = blockIdx.x << 4;
    float acc[8] = {0, 0, 0, 0, 0, 0, 0, 0};
    for (int kk = 0; kk < 16; ++kk) {
        int k = k0 + kk;
        float w = l2w[(size_t)k * 256 + o];
        #pragma unroll
        for (int b = 0; b < 8; ++b) acc[b] = fmaf(rg1[b * 512 + k], w, acc[b]);
    }
    #pragma unroll
    for (int b = 0; b < 8; ++b) unsafeAtomicAdd(&racc2[b * 256 + o], acc[b]);
}
__global__ void __launch_bounds__(256) ro4(
        const float* __restrict__ racc2, const float* __restrict__ l2b,
        const float* __restrict__ bn4, const float* __restrict__ l3w,
        const float* __restrict__ l3b, float* __restrict__ out) {
    __shared__ float G2[8 * 256];
    int o = threadIdx.x;
    {
        float ga = bn4[o], be = bn4[256 + o], mn = bn4[512 + o], vr = bn4[768 + o];
        float sc = (float)(1.0 / sqrt((double)vr + 1e-5));
        float bi = l2b[o];
        #pragma unroll
        for (int b = 0; b < 8; ++b) {
            float v = (racc2[b * 256 + o] + bi - mn) * sc * ga + be;
            v = v > 0.0f ? v : 0.0f;
            G2[b * 256 + o] = v;
            out[32 + b * 256 + o] = v;
        }
    }
    __syncthreads();
    if (o < 8) {
        int b = o;
        float r[4];
        #pragma unroll
        for (int c = 0; c < 4; ++c) {
            float acc = l3b[c];
            for (int k = 0; k < 256; ++k) acc += G2[b * 256 + k] * l3w[k * 4 + c];
            r[c] = acc > 0.0f ? acc : 0.0f;
        }
        float mx = fmaxf(fmaxf(r[0], r[1]), fmaxf(r[2], r[3]));
        float s = 0.0f;
        #pragma unroll
        for (int c = 0; c < 4; ++c) s += expf(r[c] - mx);
        float lse = mx + logf(s);
        #pragma unroll
        for (int c = 0; c < 4; ++c) out[b * 4 + c] = r[c] - lse;
    }
}

extern "C" void kernel_launch(void* const* d_in, const int* in_sizes, int n_in,
                              void* d_out, int out_size, void* d_ws, size_t ws_size,
                              hipStream_t stream) {
    const float* x      = (const float*)d_in[0];
    const int*   ei     = (const int*)d_in[1];
    const int*   batch  = (const int*)d_in[2];
    const float* pool_w = (const float*)d_in[3];
    const float* pool_b = (const float*)d_in[4];
    const float* c1_w0  = (const float*)d_in[5];
    const float* c1_w1  = (const float*)d_in[6];
    const float* c1_b   = (const float*)d_in[7];
    const float* c2_w0  = (const float*)d_in[8];
    const float* c2_w1  = (const float*)d_in[9];
    const float* c2_b   = (const float*)d_in[10];
    const float* bn1    = (const float*)d_in[11];
    const float* bn2    = (const float*)d_in[12];
    const float* bn3    = (const float*)d_in[13];
    const float* bn4    = (const float*)d_in[14];
    const float* l1w    = (const float*)d_in[15];
    const float* l1b    = (const float*)d_in[16];
    const float* l2w    = (const float*)d_in[17];
    const float* l2b    = (const float*)d_in[18];
    const float* l3w    = (const float*)d_in[19];
    const float* l3b    = (const float*)d_in[20];
    float* out = (float*)d_out;
    char* ws = (char*)d_ws;

    double* a_d   = (double*)(ws + WS_A_D);
    double* b_d   = (double*)(ws + WS_B_D);
    u32*    emax  = (u32*)(ws + WS_EMAX);
    double* ssum  = (double*)(ws + WS_SSUM);
    double* exd   = (double*)(ws + WS_EXD);
    u32*    cin   = (u32*)(ws + WS_CIN);
    u64*    key   = (u64*)(ws + WS_KEY);
    u64*    best  = (u64*)(ws + WS_BEST);
    u32*    used  = (u32*)(ws + WS_USED);
    int*    curp  = (int*)(ws + WS_CUR);
    int*    act0  = (int*)(ws + WS_ACT0);
    int*    act1  = (int*)(ws + WS_ACT1);
    unsigned short* bthi = (unsigned short*)(ws + WS_BTHI);
    float*  pxl   = (float*)(ws + WS_PXL);
    u32*    ht    = (u32*)(ws + WS_HT);
    float*  racc1 = (float*)(ws + WS_RACC1);
    float*  racc2 = (float*)(ws + WS_RACC2);
    float*  rg1   = (float*)(ws + WS_RG1);
    float*  score = (float*)(ws + WS_SCORE);
    int*    csr_a = (int*)(ws + WS_CSRA);
    int*    sel   = (int*)(ws + WS_SEL);
    float*  csr_c = (float*)(ws + WS_CSRC);
    int*    clus  = (int*)(ws + WS_CLUST);
    int*    other = (int*)(ws + WS_OTHER);
    float*  nsc   = (float*)(ws + WS_NSC);
    int*    ce_u  = (int*)(ws + WS_CEU);
    int*    ce_v  = (int*)(ws + WS_CEV);
    u32*    deg   = (u32*)(ws + WS_DEG);
    int*    off   = (int*)(ws + WS_OFF);
    float*  dis   = (float*)(ws + WS_DIS);
    int*    misc  = (int*)(ws + WS_MISC);
    u32*    gmaxb = (u32*)(ws + WS_GMAX);
    float*  gsum  = (float*)(ws + WS_GSUM);
    float*  gcnt  = (float*)(ws + WS_GCNT);
    float*  P     = (float*)(ws + WS_P);
    unsigned short* ax = (unsigned short*)(ws + WS_H);   // packed Ax bf16 (gemm1 A)
    unsigned short* hb = (unsigned short*)(ws + WS_H);   // packed Hb bf16 (gemm2 A)
    float*  H     = (float*)(ws + WS_H);                 // final H fp32

    // ---- phase A: scores, matching, coarse graph ----
    init_misc<<<NN / 256, 256, 0, stream>>>(emax, ssum, deg, misc, gmaxb, gsum, gcnt,
                                            best, used);
    node_dots<<<NN / 4, 256, 0, stream>>>(x, pool_w, a_d, b_d);
    edge_p1<<<NE / 256, 256, 0, stream>>>(ei, a_d, b_d, pool_b, exd, emax);
    edge_p2<<<NE / 256, 256, 0, stream>>>(ei, exd, emax, ssum);
    edge_p3<<<NE / 256, 256, 0, stream>>>(ei, exd, ssum, score, key, sel, act0, best);

    {
        static const int gr[9] = {512, 512, 256, 128, 64, 32, 16, 8, 8};
        int* acts[2] = {act0, act1};
        for (int r = 0; r < 8; ++r) {
            int c = r & 1, n = 1 - c;
            mk_sel<<<gr[r], 256, 0, stream>>>(key, ei, acts[c], &misc[1 + c],
                                              &misc[1 + n], best, used, sel);
            mk_compact<<<gr[r], 256, 0, stream>>>(ei, acts[c], &misc[1 + c],
                                                  acts[n], &misc[1 + n], best, used);
            mk_min<<<gr[r + 1], 256, 0, stream>>>(key, ei, acts[n], &misc[1 + n], best);
        }
        match_fin<<<1, 1024, 0, stream>>>(key, ei, sel, best, used,
                                          act0, act1, &misc[1]);
    }

    cluster_init<<<NN / 256, 256, 0, stream>>>(clus, other, nsc, cin);
    apply_sel<<<NE / 256, 256, 0, stream>>>(ei, sel, score, clus, other, nsc);
    init_ht<<<HTS / 256, 256, 0, stream>>>(ht);
    coarse_build<<<NE / 256, 256, 0, stream>>>(ei, clus, ht, misc, ce_u, ce_v, deg, cin);
    dis_kernel<<<NN / 256, 256, 0, stream>>>(deg, dis, racc1, racc2);
    scan_kernel<<<1, 1024, 0, stream>>>(cin, off, curp);
    csr_scatter<<<NE / 256, 256, 0, stream>>>(ce_u, ce_v, dis, misc, curp, csr_a, csr_c);

    // ---- phase B: ChebConv layers (packed-fragment MFMA + fused gather/BN/ReLU) ----
    conv_b<<<dim3(4, 128), 256, 0, stream>>>(c1_w0, c1_w1, bthi, 32);
    conv_a1<<<NN / 16, 256, 0, stream>>>(x, clus, other, nsc, ax, pxl);
    gemm_pk<true><<<2048, 256, 0, stream>>>(ax, bthi, P, 32, pxl, c1_w0, c1_w1);
    cheb_fuse<true><<<NN / 4, 256, 0, stream>>>(P, off, csr_a, csr_c, misc, c1_b, bn1,
                                                nullptr, hb);

    conv_b<<<dim3(4, 64), 256, 0, stream>>>(c2_w0, c2_w1, bthi, 16);
    gemm_pk<false><<<2048, 256, 0, stream>>>(hb, bthi, P, 16, nullptr, nullptr, nullptr);
    cheb_fuse<false><<<NN / 4, 256, 0, stream>>>(P, off, csr_a, csr_c, misc, c2_b, bn2,
                                                 H, nullptr);

    pool_kernel<<<NN / 64, 256, 0, stream>>>(H, clus, batch, gmaxb, gsum, gcnt);

    // ---- parallel readout ----
    ro1<<<64, 512, 0, stream>>>(gmaxb, gsum, gcnt, l1w, racc1);
    ro2<<<1, 512, 0, stream>>>(racc1, l1b, bn3, rg1);
    ro3<<<32, 256, 0, stream>>>(rg1, l2w, racc2);
    ro4<<<1, 256, 0, stream>>>(racc2, l2b, bn4, l3w, l3b, out);
}

// Round 10
// 841.427 us; speedup vs baseline: 7.9906x; 1.0360x over previous
//
#include <hip/hip_runtime.h>
#include <hip/hip_bf16.h>
#include <cstdint>
#include <cmath>

typedef unsigned int u32;
typedef unsigned long long u64;
typedef float f32x4 __attribute__((ext_vector_type(4)));
typedef __bf16 bf16x8 __attribute__((ext_vector_type(8)));
typedef unsigned short us8 __attribute__((ext_vector_type(8)));
typedef unsigned short us4 __attribute__((ext_vector_type(4)));

#define NN 32768
#define NE 131072
#define FIN 1025
#define HTS 262144
#define HTM (HTS - 1)

// ---------------- workspace layout (byte offsets) ----------------
#define WS_A_D    0ul          // double[NN]
#define WS_B_D    262144ul     // double[NN]
#define WS_EMAX   524288ul     // u32[NN]
#define WS_SSUM   655360ul     // double[NN]
#define WS_EXD    917504ul     // double[NE]
#define WS_CIN    917504ul     // u32[NN]  overlays EXD head (zeroed in apply_sel)
#define WS_KEY    1966080ul    // u64[NE]
#define WS_BEST   3014656ul    // u64[NN]
#define WS_USED   3276800ul    // u32[NN]
#define WS_CUR    3276800ul    // int[NN]  overlays USED (dead after match_fin)
#define WS_ACT0   3407872ul    // int[NE]
#define WS_ACT1   3932160ul    // int[NE]   (zone ends 4456448)
#define WS_BTHI   0ul          // ushort[1024*1024] packed L1 weights (phase B)
#define WS_BT2    3407872ul    // ushort[1024*512] packed L2 weights (overlays ACT0/1)
#define WS_HT     1966080ul    // u32[HTS] overlays KEY (init in apply_sel)
// readout scratch (phase B, overlays dead KEY tail):
#define WS_RACC1  2097152ul    // float[8*512]
#define WS_RACC2  2113536ul    // float[8*256]
// persistent:
#define WS_SCORE  4456448ul    // float[NE]
#define WS_CSRA   4456448ul    // int[NE]  overlays SCORE (dead after apply_sel)
#define WS_SEL    4980736ul    // int[NE]
#define WS_CSRC   4980736ul    // float[NE] overlays SEL (dead after apply_sel)
#define WS_CLUST  5505024ul    // int[NN]
#define WS_OTHER  5636096ul    // int[NN]
#define WS_NSC    5767168ul    // float[NN]
#define WS_CEU    5898240ul    // int[NE]
#define WS_CEV    6422528ul    // int[NE]
#define WS_DEG    6946816ul    // u32[NN]
#define WS_OFF    6946816ul    // int[NN]  overlays DEG
#define WS_DIS    7077888ul    // float[NN]
#define WS_PXL    7077888ul    // float[NN] overlays DIS (dis dead after csr_scatter)
#define WS_MISC   7208960ul    // int[64]
#define WS_GMAX   7209216ul    // u32[8*512]
#define WS_GSUM   7225600ul    // float[8*512]
#define WS_GCNT   7241984ul    // float[64]
#define WS_P      7242240ul    // float[NN*512] P0 fp32
#define WS_PB     74351104ul   // ushort[NN*512] P1 bf16 (=WS_P+67108864)
#define WS_H      141459968ul  // Ax/Hb bf16 packed -> H f32[NN*512]

__device__ __forceinline__ u32 enc_f(float f) {
    u32 b = __float_as_uint(f);
    return (b & 0x80000000u) ? ~b : (b | 0x80000000u);
}
__device__ __forceinline__ float dec_f(u32 m) {
    return (m & 0x80000000u) ? __uint_as_float(m ^ 0x80000000u) : __uint_as_float(~m);
}
__device__ __forceinline__ double wave_sum(double v) {
    #pragma unroll
    for (int off = 32; off > 0; off >>= 1) v += __shfl_down(v, off, 64);
    return v;
}
__device__ __forceinline__ unsigned short f2bf(float v) {   // RNE f32->bf16
    u32 b = __float_as_uint(v);
    u32 r = b + 0x7FFFu + ((b >> 16) & 1u);
    return (unsigned short)(r >> 16);
}
__device__ __forceinline__ float bf2f(unsigned short h) {
    return __uint_as_float(((u32)h) << 16);
}
__device__ __forceinline__ bf16x8 ld_frag(const unsigned short* p) {
    union { us8 u; bf16x8 b; } t;
    t.u = *(const us8*)p;
    return t.b;
}
// async global->LDS, 16B/lane; lds base must be wave-uniform
__device__ __forceinline__ void dma16(unsigned short* lds, const unsigned short* g) {
    __builtin_amdgcn_global_load_lds((const __attribute__((address_space(1))) u32*)g,
                                     (__attribute__((address_space(3))) u32*)lds, 16, 0, 0);
}

// ---------------- per-node dots + all phase-A init fused ----------------
__global__ void node_dots(const float* __restrict__ x, const float* __restrict__ pw,
                          double* a_d, double* b_d,
                          u32* emax, double* ssum, u32* deg, int* misc,
                          u32* gmaxb, float* gsum, float* gcnt,
                          u64* best, u32* used, int* clus, int* other, float* nsc) {
    int gid = blockIdx.x * blockDim.x + threadIdx.x;
    if (gid < NN) {
        emax[gid] = 0u; ssum[gid] = 0.0; deg[gid] = 0u;
        best[gid] = ~0ull; used[gid] = 0u;
        clus[gid] = gid; other[gid] = -1; nsc[gid] = 1.0f;
    }
    if (gid < 4096) { gmaxb[gid] = 0u; gsum[gid] = 0.0f; }
    if (gid < 64) { misc[gid] = (gid == 1) ? NE : 0; gcnt[gid] = 0.0f; }

    int wave = gid >> 6;
    int lane = threadIdx.x & 63;
    if (wave >= NN) return;
    const float* xr = x + (size_t)wave * FIN;
    double s0 = 0.0, s1 = 0.0;
    for (int f = lane; f < FIN; f += 64) {
        double xv = (double)xr[f];
        s0 += xv * (double)pw[f];
        s1 += xv * (double)pw[FIN + f];
    }
    s0 = wave_sum(s0); s1 = wave_sum(s1);
    if (lane == 0) { a_d[wave] = s0; b_d[wave] = s1; }
}

// ---------------- edge score pipeline ----------------
__global__ void edge_p1(const int* __restrict__ ei, const double* __restrict__ a_d,
                        const double* __restrict__ b_d, const float* __restrict__ pb,
                        double* e_d, u32* emax) {
    int k = blockIdx.x * 256 + threadIdx.x;
    if (k >= NE) return;
    int u = ei[k], v = ei[NE + k];
    double e = a_d[u] + b_d[v] + (double)pb[0];
    e_d[k] = e;
    atomicMax(&emax[v], enc_f((float)e));
}
__global__ void edge_p2(const int* __restrict__ ei, double* e_d,
                        const u32* __restrict__ emax, double* ssum) {
    int k = blockIdx.x * 256 + threadIdx.x;
    if (k >= NE) return;
    int v = ei[NE + k];
    float mf = dec_f(emax[v]);
    double ex = exp(e_d[k] - (double)mf);
    e_d[k] = ex;
    unsafeAtomicAdd(&ssum[v], ex);
}
__global__ void edge_p3(const int* __restrict__ ei, const double* __restrict__ e_d,
                        const double* __restrict__ ssum, float* score, u64* key,
                        int* sel, int* act0, u64* best) {
    int k = blockIdx.x * 256 + threadIdx.x;
    if (k >= NE) return;
    int u = ei[k], v = ei[NE + k];
    float sc = (float)(e_d[k] / ssum[v] + 0.5);
    score[k] = sc;
    u32 m = enc_f(sc);
    u64 kk = ((u64)(m ^ 0xFFFFFFFFu) << 32) | (u32)k;  // low = high score, tie: low idx
    key[k] = kk;
    sel[k] = 0;
    act0[k] = k;
    atomicMin(&best[u], kk);
    atomicMin(&best[v], kk);
}

// ---------------- flattened dominant-edge peeling rounds ----------------
__global__ void mk_sel(const u64* __restrict__ key, const int* __restrict__ ei,
                       const int* __restrict__ act, const int* __restrict__ cntp,
                       int* ncntp, const u64* __restrict__ best,
                       u32* used, int* sel) {
    int cnt = cntp[0];
    int stride = gridDim.x * blockDim.x;
    int gid = blockIdx.x * blockDim.x + threadIdx.x;
    if (gid == 0) ncntp[0] = 0;
    for (int i = gid; i < cnt; i += stride) {
        int e = act[i];
        u64 k = key[e];
        int a = ei[e], b = ei[NE + e];
        if (best[a] == k && best[b] == k) { sel[e] = 1; used[a] = 1u; used[b] = 1u; }
    }
}
__global__ void mk_compact(const int* __restrict__ ei, const int* __restrict__ act,
                           const int* __restrict__ cntp, int* nxt, int* ncntp,
                           u64* best, const u32* __restrict__ used) {
    int cnt = cntp[0];
    int stride = gridDim.x * blockDim.x;
    for (int i = blockIdx.x * blockDim.x + threadIdx.x; i < cnt; i += stride) {
        int e = act[i];
        int a = ei[e], b = ei[NE + e];
        best[a] = ~0ull; best[b] = ~0ull;
        bool live = !(used[a] | used[b]);
        u64 mask = __ballot(live);
        if (mask) {
            int lane = threadIdx.x & 63;
            int leader = __ffsll((unsigned long long)mask) - 1;
            int base = 0;
            if (lane == leader) base = atomicAdd(ncntp, __popcll(mask));
            base = __shfl(base, leader, 64);
            if (live) nxt[base + __popcll(mask & ((1ull << lane) - 1ull))] = e;
        }
    }
}
__global__ void mk_min(const u64* __restrict__ key, const int* __restrict__ ei,
                       const int* __restrict__ act, const int* __restrict__ cntp,
                       u64* best) {
    int cnt = cntp[0];
    int stride = gridDim.x * blockDim.x;
    for (int i = blockIdx.x * blockDim.x + threadIdx.x; i < cnt; i += stride) {
        int e = act[i];
        u64 k = key[e];
        atomicMin(&best[ei[e]], k);
        atomicMin(&best[ei[NE + e]], k);
    }
}
__global__ void __launch_bounds__(1024) match_fin(
        const u64* __restrict__ key, const int* __restrict__ ei,
        int* sel, u64* best, u32* used,
        int* listA, int* listB, const int* __restrict__ cntp) {
    int tid = threadIdx.x;
    int cnt = cntp[0];
    int* cur = listA; int* nxt = listB;
    __shared__ int s_n;
    for (int round = 0; round < 4096 && cnt > 0; ++round) {
        for (int i = tid; i < cnt; i += 1024) {
            int e = cur[i]; u64 k = key[e];
            atomicMin(&best[ei[e]], k);
            atomicMin(&best[ei[NE + e]], k);
        }
        __syncthreads();
        for (int i = tid; i < cnt; i += 1024) {
            int e = cur[i]; u64 k = key[e];
            int a = ei[e], b = ei[NE + e];
            if (best[a] == k && best[b] == k) { sel[e] = 1; used[a] = 1u; used[b] = 1u; }
        }
        if (tid == 0) s_n = 0;
        __syncthreads();
        for (int i = tid; i < cnt; i += 1024) {
            int e = cur[i];
            int a = ei[e], b = ei[NE + e];
            best[a] = ~0ull; best[b] = ~0ull;
            if (!(used[a] | used[b])) {
                int idx = atomicAdd(&s_n, 1);
                nxt[idx] = e;
            }
        }
        __syncthreads();
        cnt = s_n;
        int* t = cur; cur = nxt; nxt = t;
        __syncthreads();
    }
}

// apply_sel + ht init + cin zero (grid = NE/256; KEY dead here)
__global__ void apply_sel(const int* __restrict__ ei, const int* __restrict__ sel,
                          const float* __restrict__ score,
                          int* cluster, int* other, float* nscore,
                          u32* ht, u32* cin) {
    int e = blockIdx.x * 256 + threadIdx.x;
    ht[e << 1] = 0xFFFFFFFFu;
    ht[(e << 1) + 1] = 0xFFFFFFFFu;
    if (e < NN) cin[e] = 0u;
    if (sel[e] != 1) return;
    int u = ei[e], v = ei[NE + e];
    int rep = min(u, v);
    cluster[u] = rep; cluster[v] = rep;
    if (u != v) other[rep] = u + v - rep;
    nscore[rep] = score[e];
}

// ---------------- coarse graph: dedup (cu,cv) pairs via hash set ----------------
__global__ void coarse_build(const int* __restrict__ ei, const int* __restrict__ cluster,
                             u32* ht, int* misc, int* ce_u, int* ce_v, u32* deg,
                             u32* cin) {
    int e = blockIdx.x * 256 + threadIdx.x;
    if (e >= NE) return;
    int cu = cluster[ei[e]], cv = cluster[ei[NE + e]];
    if (cu == cv) return;
    u32 k = (u32)cu * 32768u + (u32)cv;
    u32 h = ((k * 2654435761u) >> 12) & HTM;
    while (true) {
        u32 old = atomicCAS(&ht[h], 0xFFFFFFFFu, k);
        if (old == 0xFFFFFFFFu) {
            int idx = atomicAdd(&misc[0], 1);
            ce_u[idx] = cu; ce_v[idx] = cv;
            atomicAdd(&deg[cu], 1u);
            atomicAdd(&cin[cv], 1u);
            break;
        }
        if (old == k) break;
        h = (h + 1) & HTM;
    }
}
// dis + readout-scratch zero + gcnt (per-wave ballot reduction; batch sorted)
__global__ void dis_kernel(const u32* __restrict__ deg, float* dis,
                           float* racc1, float* racc2,
                           const int* __restrict__ clus, const int* __restrict__ batch,
                           float* gcnt) {
    int n = blockIdx.x * 256 + threadIdx.x;
    if (n >= NN) return;
    u32 d = deg[n];
    dis[n] = d ? (float)(1.0 / sqrt((double)d)) : 0.0f;
    if (n < 4096) racc1[n] = 0.0f;
    if (n < 2048) racc2[n] = 0.0f;
    bool val = (clus[n] == n);
    int bt = batch[n];
    int lane = threadIdx.x & 63;
    #pragma unroll
    for (int g = 0; g < 8; ++g) {
        u64 m = __ballot(val && bt == g);
        if (m && lane == (__ffsll((unsigned long long)m) - 1))
            unsafeAtomicAdd(&gcnt[g], (float)__popcll(m));
    }
}

// ---------------- CSR build: exclusive scan of cin -> off, cur ----------------
__global__ void __launch_bounds__(1024) scan_kernel(const u32* __restrict__ cin,
                                                    int* off, int* cur) {
    __shared__ int part[1024];
    int t = threadIdx.x;
    int base = t << 5;
    int loc[32];
    int s = 0;
    #pragma unroll
    for (int i = 0; i < 32; ++i) { loc[i] = s; s += (int)cin[base + i]; }
    part[t] = s;
    __syncthreads();
    for (int d = 1; d < 1024; d <<= 1) {
        int v = (t >= d) ? part[t - d] : 0;
        __syncthreads();
        if (t >= d) part[t] += v;
        __syncthreads();
    }
    int pre = (t == 0) ? 0 : part[t - 1];
    #pragma unroll
    for (int i = 0; i < 32; ++i) {
        int v = pre + loc[i];
        off[base + i] = v;
        cur[base + i] = v;
    }
}
__global__ void csr_scatter(const int* __restrict__ ce_u, const int* __restrict__ ce_v,
                            const float* __restrict__ dis, const int* __restrict__ misc,
                            int* cur, int* csr_a, float* csr_c) {
    int e = blockIdx.x * 256 + threadIdx.x;
    if (e >= misc[0]) return;
    int a = ce_u[e], b = ce_v[e];
    int pos = atomicAdd(&cur[b], 1);
    csr_a[pos] = a;
    csr_c[pos] = -dis[a] * dis[b];
}

// ---- packed fragment index: row r, col k -> ushort offset ----
__device__ __forceinline__ size_t pk_idx(int r, int k, int KT) {
    return ((((size_t)(r >> 4) * KT + (k >> 5)) << 6) + (((k >> 3) & 3) << 4) + (r & 15)) << 3;
}

// ---------------- fused: packed Ax gather + pxl + BOTH weight transposes ----------------
__global__ void __launch_bounds__(256) conv_all(
        const float* __restrict__ x, const int* __restrict__ clus,
        const int* __restrict__ other, const float* __restrict__ nsc,
        unsigned short* __restrict__ Abf, float* __restrict__ pxl,
        const float* __restrict__ B10, const float* __restrict__ B11,
        unsigned short* __restrict__ Bp1,
        const float* __restrict__ B20, const float* __restrict__ B21,
        unsigned short* __restrict__ Bp2) {
    int bid = blockIdx.x;
    int t = threadIdx.x;
    if (bid < 2048) {   // A-tile gather (16 rows, packed writes contiguous per wave)
        int tile = bid;
        int wave = t >> 6, lane = t & 63;
        int l16 = lane & 15, quad = lane >> 4;
        int row = (tile << 4) + l16;
        bool valid = (clus[row] == row);
        int o = other[row];
        float s = nsc[row];
        const float* xr = x + (size_t)row * FIN;
        const float* xo = x + (size_t)(o >= 0 ? o : row) * FIN;
        for (int kt = wave; kt < 32; kt += 4) {
            int c0 = (kt << 5) + (quad << 3);
            unsigned short h[8];
            #pragma unroll
            for (int j = 0; j < 8; ++j) {
                float v = 0.0f;
                if (valid) {
                    v = xr[c0 + j];
                    if (o >= 0) v += xo[c0 + j];
                    v *= s;
                }
                h[j] = f2bf(v);
            }
            *(us8*)&Abf[((((size_t)tile << 5) + kt) << 9) + ((size_t)lane << 3)] = *(const us8*)h;
        }
        if (t < 16) {
            int r2 = (tile << 4) + t;
            bool v2 = (clus[r2] == r2);
            int o2 = other[r2];
            float v = 0.0f;
            if (v2) {
                v = x[(size_t)r2 * FIN + 1024];
                if (o2 >= 0) v += x[(size_t)o2 * FIN + 1024];
                v *= nsc[r2];
            }
            pxl[r2] = v;
        }
    } else if (bid < 2560) {   // L1 weight transpose, KT=32
        int j = bid - 2048;
        int n = ((j & 3) << 8) + t;
        int k0 = (j >> 2) << 3;
        unsigned short h[8];
        #pragma unroll
        for (int jj = 0; jj < 8; ++jj) {
            int k = k0 + jj;
            float v = (n < 512) ? B10[(size_t)k * 512 + n] : B11[(size_t)k * 512 + (n - 512)];
            h[jj] = f2bf(v);
        }
        *(us8*)&Bp1[pk_idx(n, k0, 32)] = *(const us8*)h;
    } else {                   // L2 weight transpose, KT=16
        int j = bid - 2560;
        int n = ((j & 3) << 8) + t;
        int k0 = (j >> 2) << 3;
        unsigned short h[8];
        #pragma unroll
        for (int jj = 0; jj < 8; ++jj) {
            int k = k0 + jj;
            float v = (n < 512) ? B20[(size_t)k * 512 + n] : B21[(size_t)k * 512 + (n - 512)];
            h[jj] = f2bf(v);
        }
        *(us8*)&Bp2[pk_idx(n, k0, 16)] = *(const us8*)h;
    }
}

// ---------------- packed-fragment bf16 MFMA GEMM with LDS DMA double-buffer ----------------
// P0 (cols<512) fp32; P1 (cols>=512) stored bf16 in Pb.
template <bool R1>
__global__ void __launch_bounds__(256, 4) gemm_pk(
        const unsigned short* __restrict__ Ap, const unsigned short* __restrict__ Bp,
        float* __restrict__ P, unsigned short* __restrict__ Pb, int KT,
        const float* __restrict__ pxl, const float* __restrict__ w0,
        const float* __restrict__ w1) {
    __shared__ unsigned short L[2][8192];
    int tid = threadIdx.x;
    int bid = blockIdx.x;
    int loc = bid >> 3;
    int bn = (loc & 7) << 7;
    int bm = ((((bid & 7) << 5) | (loc >> 3))) << 7;
    int wave = tid >> 6, lane = tid & 63, quad = lane >> 4, l16 = lane & 15;
    int moff = (wave >> 1) << 6, noff = (wave & 1) << 6;
    f32x4 acc[4][4];
    #pragma unroll
    for (int i = 0; i < 4; ++i)
        #pragma unroll
        for (int j = 0; j < 4; ++j) acc[i][j] = (f32x4){0.f, 0.f, 0.f, 0.f};

    const unsigned short* src[4];
    unsigned short* dst[4];
    #pragma unroll
    for (int q = 0; q < 4; ++q) {
        int f = (wave << 2) + q;
        int tg = (f < 8) ? ((bm >> 4) + f) : ((bn >> 4) + (f - 8));
        src[q] = ((f < 8) ? Ap : Bp) + (((size_t)tg * KT) << 9) + ((size_t)lane << 3);
        dst[q] = &L[0][(size_t)f << 9];
    }
    const unsigned short* ra = &L[0][(size_t)(wave >> 1) << 11];
    const unsigned short* rb = &L[0][4096 + ((size_t)(wave & 1) << 11)];

    #pragma unroll
    for (int q = 0; q < 4; ++q) dma16(dst[q], src[q]);
    __syncthreads();

    int cur = 0;
    for (int kt = 0; kt < KT; ++kt) {
        if (kt + 1 < KT) {
            int nb = (cur ^ 1) * 8192;
            size_t go = ((size_t)(kt + 1)) << 9;
            #pragma unroll
            for (int q = 0; q < 4; ++q) dma16(dst[q] + nb, src[q] + go);
        }
        const unsigned short* la = ra + cur * 8192;
        const unsigned short* lb = rb + cur * 8192;
        bf16x8 af[4], bf[4];
        #pragma unroll
        for (int i = 0; i < 4; ++i) {
            af[i] = ld_frag(la + ((size_t)i << 9) + (lane << 3));
            bf[i] = ld_frag(lb + ((size_t)i << 9) + (lane << 3));
        }
        #pragma unroll
        for (int mi = 0; mi < 4; ++mi)
            #pragma unroll
            for (int ni = 0; ni < 4; ++ni)
                acc[mi][ni] = __builtin_amdgcn_mfma_f32_16x16x32_bf16(af[mi], bf[ni], acc[mi][ni], 0, 0, 0);
        __syncthreads();
        cur ^= 1;
    }
    // epilogue: C/D row=quad*4+r2, col=l16; rank-1; split fp32/bf16 store
    #pragma unroll
    for (int mi = 0; mi < 4; ++mi)
        #pragma unroll
        for (int ni = 0; ni < 4; ++ni) {
            int col = bn + noff + (ni << 4) + l16;
            float wl = 0.0f;
            if (R1) wl = (col < 512) ? w0[524288 + col] : w1[524288 + col - 512];
            #pragma unroll
            for (int r2 = 0; r2 < 4; ++r2) {
                int row = bm + moff + (mi << 4) + (quad << 2) + r2;
                float v = acc[mi][ni][r2];
                if (R1) v += pxl[row] * wl;
                if (col < 512) P[(size_t)row * 512 + col] = v;
                else Pb[(size_t)row * 512 + (col - 512)] = f2bf(v);
            }
        }
}

// ---------------- fused gather + BN + ReLU: one wave per destination row ----------------
template <bool BF16OUT>
__global__ void __launch_bounds__(256) cheb_fuse(
        const float* __restrict__ P, const unsigned short* __restrict__ Pb,
        const int* __restrict__ off,
        const int* __restrict__ csr_a, const float* __restrict__ csr_c,
        const int* __restrict__ misc, const float* __restrict__ bias,
        const float* __restrict__ bn, float* __restrict__ Hf,
        unsigned short* __restrict__ Hb) {
    int b = (blockIdx.x * 256 + threadIdx.x) >> 6;
    int lane = threadIdx.x & 63;
    if (b >= NN) return;
    int s = off[b];
    int e = (b < NN - 1) ? off[b + 1] : misc[0];
    int c0 = lane << 3;
    float a0[4], a1[4];
    {
        float4 t0 = *(const float4*)&P[(size_t)b * 512 + c0];
        float4 t1 = *(const float4*)&P[(size_t)b * 512 + c0 + 4];
        a0[0] = t0.x; a0[1] = t0.y; a0[2] = t0.z; a0[3] = t0.w;
        a1[0] = t1.x; a1[1] = t1.y; a1[2] = t1.z; a1[3] = t1.w;
    }
    for (int j = s; j < e; ++j) {
        int a = csr_a[j];
        float cf = csr_c[j];
        us8 raw = *(const us8*)&Pb[(size_t)a * 512 + c0];
        a0[0] = fmaf(cf, bf2f(raw[0]), a0[0]); a0[1] = fmaf(cf, bf2f(raw[1]), a0[1]);
        a0[2] = fmaf(cf, bf2f(raw[2]), a0[2]); a0[3] = fmaf(cf, bf2f(raw[3]), a0[3]);
        a1[0] = fmaf(cf, bf2f(raw[4]), a1[0]); a1[1] = fmaf(cf, bf2f(raw[5]), a1[1]);
        a1[2] = fmaf(cf, bf2f(raw[6]), a1[2]); a1[3] = fmaf(cf, bf2f(raw[7]), a1[3]);
    }
    float o[8];
    #pragma unroll
    for (int i = 0; i < 8; ++i) {
        int j = c0 + i;
        float acc = (i < 4) ? a0[i] : a1[i - 4];
        float ga = bn[j], be = bn[512 + j], mn = bn[1024 + j], vr = bn[1536 + j];
        float sc = (float)(1.0 / sqrt((double)vr + 1e-5));
        float v = (acc + bias[j] - mn) * sc * ga + be;
        o[i] = v > 0.0f ? v : 0.0f;
    }
    if (BF16OUT) {
        unsigned short h[8];
        #pragma unroll
        for (int i = 0; i < 8; ++i) h[i] = f2bf(o[i]);
        *(us8*)&Hb[pk_idx(b, c0, 16)] = *(const us8*)h;   // packed for layer-2 GEMM
    } else {
        *(float4*)&Hf[(size_t)b * 512 + c0] = make_float4(o[0], o[1], o[2], o[3]);
        *(float4*)&Hf[(size_t)b * 512 + c0 + 4] = make_float4(o[4], o[5], o[6], o[7]);
    }
}

// ---------------- global max+mean pool over valid nodes per graph ----------------
__global__ void __launch_bounds__(256) pool_kernel(
        const float* __restrict__ H, const int* __restrict__ cluster,
        const int* __restrict__ batch, u32* gmaxb, float* gsum) {
    int t = threadIdx.x;
    int n0 = blockIdx.x * 64;
    float m0 = 0.0f, m1 = 0.0f, s0 = 0.0f, s1 = 0.0f;
    int cur = batch[n0];
    for (int i = 0; i < 64; ++i) {
        int n = n0 + i;
        int bt = batch[n];
        if (bt != cur) {
            atomicMax(&gmaxb[cur * 512 + t], __float_as_uint(m0));
            atomicMax(&gmaxb[cur * 512 + t + 256], __float_as_uint(m1));
            unsafeAtomicAdd(&gsum[cur * 512 + t], s0);
            unsafeAtomicAdd(&gsum[cur * 512 + t + 256], s1);
            m0 = m1 = s0 = s1 = 0.0f; cur = bt;
        }
        if (cluster[n] == n) {
            float h0 = H[(size_t)n * 512 + t];
            float h1 = H[(size_t)n * 512 + t + 256];
            m0 = fmaxf(m0, h0); m1 = fmaxf(m1, h1);
            s0 += h0; s1 += h1;
        }
    }
    atomicMax(&gmaxb[cur * 512 + t], __float_as_uint(m0));
    atomicMax(&gmaxb[cur * 512 + t + 256], __float_as_uint(m1));
    unsafeAtomicAdd(&gsum[cur * 512 + t], s0);
    unsafeAtomicAdd(&gsum[cur * 512 + t + 256], s1);
}

// ---------------- parallel readout MLP (3 kernels) ----------------
__global__ void __launch_bounds__(512) ro1(
        const u32* __restrict__ gmaxb, const float* __restrict__ gsum,
        const float* __restrict__ gcnt, const float* __restrict__ l1w,
        float* __restrict__ racc1) {
    int o = threadIdx.x;
    int k0 = blockIdx.x << 4;
    float acc[8] = {0, 0, 0, 0, 0, 0, 0, 0};
    float inv[8];
    #pragma unroll
    for (int b = 0; b < 8; ++b) inv[b] = 1.0f / fmaxf(gcnt[b], 1.0f);
    for (int kk = 0; kk < 16; ++kk) {
        int k = k0 + kk;
        float w = l1w[(size_t)k * 512 + o];
        #pragma unroll
        for (int b = 0; b < 8; ++b) {
            float g = (k < 512) ? __uint_as_float(gmaxb[b * 512 + k])
                                : gsum[b * 512 + (k - 512)] * inv[b];
            acc[b] = fmaf(g, w, acc[b]);
        }
    }
    #pragma unroll
    for (int b = 0; b < 8; ++b) unsafeAtomicAdd(&racc1[b * 512 + o], acc[b]);
}
// ro3: layer-2 partials with ro2's BN inlined (recomputed per k-slice)
__global__ void __launch_bounds__(256) ro3(
        const float* __restrict__ racc1, const float* __restrict__ l1b,
        const float* __restrict__ bn3, const float* __restrict__ l2w,
        float* __restrict__ racc2) {
    int o = threadIdx.x;
    int k0 = blockIdx.x << 4;
    float acc[8] = {0, 0, 0, 0, 0, 0, 0, 0};
    for (int kk = 0; kk < 16; ++kk) {
        int k = k0 + kk;
        float ga = bn3[k], be = bn3[512 + k], mn = bn3[1024 + k], vr = bn3[1536 + k];
        float sc = (float)(1.0 / sqrt((double)vr + 1e-5));
        float bi = l1b[k];
        float w = l2w[(size_t)k * 256 + o];
        #pragma unroll
        for (int b = 0; b < 8; ++b) {
            float g1 = (racc1[b * 512 + k] + bi - mn) * sc * ga + be;
            g1 = g1 > 0.0f ? g1 : 0.0f;
            acc[b] = fmaf(g1, w, acc[b]);
        }
    }
    #pragma unroll
    for (int b = 0; b < 8; ++b) unsafeAtomicAdd(&racc2[b * 256 + o], acc[b]);
}
__global__ void __launch_bounds__(256) ro4(
        const float* __restrict__ racc2, const float* __restrict__ l2b,
        const float* __restrict__ bn4, const float* __restrict__ l3w,
        const float* __restrict__ l3b, float* __restrict__ out) {
    __shared__ float G2[8 * 256];
    int o = threadIdx.x;
    {
        float ga = bn4[o], be = bn4[256 + o], mn = bn4[512 + o], vr = bn4[768 + o];
        float sc = (float)(1.0 / sqrt((double)vr + 1e-5));
        float bi = l2b[o];
        #pragma unroll
        for (int b = 0; b < 8; ++b) {
            float v = (racc2[b * 256 + o] + bi - mn) * sc * ga + be;
            v = v > 0.0f ? v : 0.0f;
            G2[b * 256 + o] = v;
            out[32 + b * 256 + o] = v;
        }
    }
    __syncthreads();
    if (o < 8) {
        int b = o;
        float r[4];
        #pragma unroll
        for (int c = 0; c < 4; ++c) {
            float acc = l3b[c];
            for (int k = 0; k < 256; ++k) acc += G2[b * 256 + k] * l3w[k * 4 + c];
            r[c] = acc > 0.0f ? acc : 0.0f;
        }
        float mx = fmaxf(fmaxf(r[0], r[1]), fmaxf(r[2], r[3]));
        float s = 0.0f;
        #pragma unroll
        for (int c = 0; c < 4; ++c) s += expf(r[c] - mx);
        float lse = mx + logf(s);
        #pragma unroll
        for (int c = 0; c < 4; ++c) out[b * 4 + c] = r[c] - lse;
    }
}

extern "C" void kernel_launch(void* const* d_in, const int* in_sizes, int n_in,
                              void* d_out, int out_size, void* d_ws, size_t ws_size,
                              hipStream_t stream) {
    const float* x      = (const float*)d_in[0];
    const int*   ei     = (const int*)d_in[1];
    const int*   batch  = (const int*)d_in[2];
    const float* pool_w = (const float*)d_in[3];
    const float* pool_b = (const float*)d_in[4];
    const float* c1_w0  = (const float*)d_in[5];
    const float* c1_w1  = (const float*)d_in[6];
    const float* c1_b   = (const float*)d_in[7];
    const float* c2_w0  = (const float*)d_in[8];
    const float* c2_w1  = (const float*)d_in[9];
    const float* c2_b   = (const float*)d_in[10];
    const float* bn1    = (const float*)d_in[11];
    const float* bn2    = (const float*)d_in[12];
    const float* bn3    = (const float*)d_in[13];
    const float* bn4    = (const float*)d_in[14];
    const float* l1w    = (const float*)d_in[15];
    const float* l1b    = (const float*)d_in[16];
    const float* l2w    = (const float*)d_in[17];
    const float* l2b    = (const float*)d_in[18];
    const float* l3w    = (const float*)d_in[19];
    const float* l3b    = (const float*)d_in[20];
    float* out = (float*)d_out;
    char* ws = (char*)d_ws;

    double* a_d   = (double*)(ws + WS_A_D);
    double* b_d   = (double*)(ws + WS_B_D);
    u32*    emax  = (u32*)(ws + WS_EMAX);
    double* ssum  = (double*)(ws + WS_SSUM);
    double* exd   = (double*)(ws + WS_EXD);
    u32*    cin   = (u32*)(ws + WS_CIN);
    u64*    key   = (u64*)(ws + WS_KEY);
    u64*    best  = (u64*)(ws + WS_BEST);
    u32*    used  = (u32*)(ws + WS_USED);
    int*    curp  = (int*)(ws + WS_CUR);
    int*    act0  = (int*)(ws + WS_ACT0);
    int*    act1  = (int*)(ws + WS_ACT1);
    unsigned short* bthi = (unsigned short*)(ws + WS_BTHI);
    unsigned short* bt2  = (unsigned short*)(ws + WS_BT2);
    float*  pxl   = (float*)(ws + WS_PXL);
    u32*    ht    = (u32*)(ws + WS_HT);
    float*  racc1 = (float*)(ws + WS_RACC1);
    float*  racc2 = (float*)(ws + WS_RACC2);
    float*  score = (float*)(ws + WS_SCORE);
    int*    csr_a = (int*)(ws + WS_CSRA);
    int*    sel   = (int*)(ws + WS_SEL);
    float*  csr_c = (float*)(ws + WS_CSRC);
    int*    clus  = (int*)(ws + WS_CLUST);
    int*    other = (int*)(ws + WS_OTHER);
    float*  nsc   = (float*)(ws + WS_NSC);
    int*    ce_u  = (int*)(ws + WS_CEU);
    int*    ce_v  = (int*)(ws + WS_CEV);
    u32*    deg   = (u32*)(ws + WS_DEG);
    int*    off   = (int*)(ws + WS_OFF);
    float*  dis   = (float*)(ws + WS_DIS);
    int*    misc  = (int*)(ws + WS_MISC);
    u32*    gmaxb = (u32*)(ws + WS_GMAX);
    float*  gsum  = (float*)(ws + WS_GSUM);
    float*  gcnt  = (float*)(ws + WS_GCNT);
    float*  P     = (float*)(ws + WS_P);
    unsigned short* Pb = (unsigned short*)(ws + WS_PB);
    unsigned short* ax = (unsigned short*)(ws + WS_H);   // packed Ax bf16 (gemm1 A)
    unsigned short* hb = (unsigned short*)(ws + WS_H);   // packed Hb bf16 (gemm2 A)
    float*  H     = (float*)(ws + WS_H);                 // final H fp32

    // ---- phase A: scores, matching, coarse graph ----
    node_dots<<<NN / 4, 256, 0, stream>>>(x, pool_w, a_d, b_d,
                                          emax, ssum, deg, misc, gmaxb, gsum, gcnt,
                                          best, used, clus, other, nsc);
    edge_p1<<<NE / 256, 256, 0, stream>>>(ei, a_d, b_d, pool_b, exd, emax);
    edge_p2<<<NE / 256, 256, 0, stream>>>(ei, exd, emax, ssum);
    edge_p3<<<NE / 256, 256, 0, stream>>>(ei, exd, ssum, score, key, sel, act0, best);

    {
        static const int gr[9] = {512, 512, 256, 128, 64, 32, 16, 8, 8};
        int* acts[2] = {act0, act1};
        for (int r = 0; r < 8; ++r) {
            int c = r & 1, n = 1 - c;
            mk_sel<<<gr[r], 256, 0, stream>>>(key, ei, acts[c], &misc[1 + c],
                                              &misc[1 + n], best, used, sel);
            mk_compact<<<gr[r], 256, 0, stream>>>(ei, acts[c], &misc[1 + c],
                                                  acts[n], &misc[1 + n], best, used);
            mk_min<<<gr[r + 1], 256, 0, stream>>>(key, ei, acts[n], &misc[1 + n], best);
        }
        match_fin<<<1, 1024, 0, stream>>>(key, ei, sel, best, used,
                                          act0, act1, &misc[1]);
    }

    apply_sel<<<NE / 256, 256, 0, stream>>>(ei, sel, score, clus, other, nsc, ht, cin);
    coarse_build<<<NE / 256, 256, 0, stream>>>(ei, clus, ht, misc, ce_u, ce_v, deg, cin);
    dis_kernel<<<NN / 256, 256, 0, stream>>>(deg, dis, racc1, racc2, clus, batch, gcnt);
    scan_kernel<<<1, 1024, 0, stream>>>(cin, off, curp);
    csr_scatter<<<NE / 256, 256, 0, stream>>>(ce_u, ce_v, dis, misc, curp, csr_a, csr_c);

    // ---- phase B: ChebConv layers ----
    conv_all<<<2816, 256, 0, stream>>>(x, clus, other, nsc, ax, pxl,
                                       c1_w0, c1_w1, bthi, c2_w0, c2_w1, bt2);
    gemm_pk<true><<<2048, 256, 0, stream>>>(ax, bthi, P, Pb, 32, pxl, c1_w0, c1_w1);
    cheb_fuse<true><<<NN / 4, 256, 0, stream>>>(P, Pb, off, csr_a, csr_c, misc, c1_b, bn1,
                                                nullptr, hb);

    gemm_pk<false><<<2048, 256, 0, stream>>>(hb, bt2, P, Pb, 16, nullptr, nullptr, nullptr);
    cheb_fuse<false><<<NN / 4, 256, 0, stream>>>(P, Pb, off, csr_a, csr_c, misc, c2_b, bn2,
                                                 H, nullptr);

    pool_kernel<<<NN / 64, 256, 0, stream>>>(H, clus, batch, gmaxb, gsum);

    // ---- parallel readout ----
    ro1<<<64, 512, 0, stream>>>(gmaxb, gsum, gcnt, l1w, racc1);
    ro3<<<32, 256, 0, stream>>>(racc1, l1b, bn3, l2w, racc2);
    ro4<<<1, 256, 0, stream>>>(racc2, l2b, bn4, l3w, l3b, out);
}